// Round 3
// baseline (345.572 us; speedup 1.0000x reference)
//
#include <hip/hip_runtime.h>

// ---------------------------------------------------------------------------
// Mamba2 hybrid block. GEMMs: bf16 MFMA 16x16x32, f32 accumulate, m97-style
// global_load_lds(16B) staging, BK=64 (R15: single-buffered K-loop is ~53%
// barrier drain at 2-3 blocks/CU; 64-wide K tiles halve barrier count.
// 3-bit XOR chunk swizzle keeps frag reads 2-way/free). Small-N GEMMs use
// split-K x4 into SEPARATE partial buffers; partials summed in the
// downstream residual_rms kernel. MLP gu-GEMMs fuse SwiGLU (128x64 act tile;
// R14: acc must stay <=16 f32x4 or VGPR cliff). Scan: MFMA chunked.
// R16: scan_mfma1 was latency-bound (Occ 13.8%, all pipes <17%): now 4 heads
// per 256-thread block sharing B/C staging (LDS 60.5KB -> 2 blk/CU, 8 w/CU);
// scan_combine widened to 4 waves + float4. (-14.1 us, 355.5 -> 341.4)
// R17: scan_mfma2 same treatment: 4 heads/block, raw C staged ONCE shared
// (dacl[t] is a per-OUTPUT-ROW scale in the C*Sinit MFMA -> folded into f32
// epilogue, so staged C is head-independent). LDS 5.6 KB -> 32 waves/CU.
// scan_combine: hoist Ptot loads + full unroll so Sc loads prefetch past
// the serial carry chain.
// R18: identical resubmit of R17 (round 2 bench was an infra failure:
// "MI355X container failed twice" — no measurement was taken).
// ---------------------------------------------------------------------------

#define BB 4
#define LL 1024
#define DMODEL 512
#define DINNER 1024
#define NHEADS 16
#define HEADDIM 64
#define DSTATE 64
#define CONVDIM 1152        // DINNER + 2*DSTATE
#define NPROJ 2192          // D_IN_PROJ
#define NPROJ_PAD 2304      // padded to multiple of 128
#define INTER_T 2816
#define INTER_M 1536
#define NCHUNK 32
#define CHUNK 32

typedef __bf16 bf16x8 __attribute__((ext_vector_type(8)));
typedef float  f32x4  __attribute__((ext_vector_type(4)));
typedef unsigned short u16;
typedef unsigned int   u32;

__device__ __forceinline__ u16 f2bf(float x) {
    union { float f; u32 u; } v; v.f = x;
    u32 u = v.u;
    return (u16)((u + 0x7fffu + ((u >> 16) & 1u)) >> 16);
}
__device__ __forceinline__ float silu_f(float x) {
    return x / (1.f + __expf(-x));
}
__device__ __forceinline__ float bf2f(u16 w) {
    union { u32 u; float f; } a; a.u = ((u32)w) << 16; return a.f;
}

// async global->LDS, 16B per lane; LDS dest is wave-uniform base + lane*16
__device__ __forceinline__ void gld_lds16(const u16* g, u16* l) {
    __builtin_amdgcn_global_load_lds(
        (const __attribute__((address_space(1))) unsigned int*)g,
        (__attribute__((address_space(3))) unsigned int*)l, 16, 0, 0);
}

// --------------------------- block-wide sum --------------------------------
__device__ __forceinline__ float block_sum(float v) {
    #pragma unroll
    for (int off = 32; off > 0; off >>= 1) v += __shfl_xor(v, off, 64);
    __shared__ float red[4];
    int w = threadIdx.x >> 6;
    int nwv = blockDim.x >> 6;
    if ((threadIdx.x & 63) == 0) red[w] = v;
    __syncthreads();
    float tot = red[0];
    for (int i = 1; i < nwv; i++) tot += red[i];
    return tot;
}

// --------------------- f32 -> bf16 convert (all weights + hidden) ----------
#define HID_E      2097152LL   // 4096*512
#define INPROJ_P_E 1179648LL   // 2304*512
#define INPROJ_S_E 1122304LL   // 2192*512
#define OUTPROJ_E   524288LL   // 512*1024
#define GUT_E      5767168LL   // 5632*1024
#define DOWNT_E    2883584LL   // 1024*2816
#define GUM_E      1572864LL   // 3072*512
#define DOWNM_E     786432LL   // 512*1536
#define CONV_TOT_E 14811136LL

__global__ __launch_bounds__(256) void convert_all_kernel(
    const float* __restrict__ s_hid, const float* __restrict__ s_inproj,
    const float* __restrict__ s_outproj, const float* __restrict__ s_gut,
    const float* __restrict__ s_downt, const float* __restrict__ s_gum,
    const float* __restrict__ s_downm, u16* __restrict__ dst)
{
    long long idx = (long long)blockIdx.x * 256 + threadIdx.x;
    long long e = idx * 4;
    if (e >= CONV_TOT_E) return;
    const float* src; long long off, nsrc;
    long long c0 = HID_E;
    long long c1 = c0 + INPROJ_P_E;
    long long c2 = c1 + OUTPROJ_E;
    long long c3 = c2 + GUT_E;
    long long c4 = c3 + DOWNT_E;
    long long c5 = c4 + GUM_E;
    if      (e < c0) { src = s_hid;     off = e;      nsrc = HID_E; }
    else if (e < c1) { src = s_inproj;  off = e - c0; nsrc = INPROJ_S_E; }
    else if (e < c2) { src = s_outproj; off = e - c1; nsrc = OUTPROJ_E; }
    else if (e < c3) { src = s_gut;     off = e - c2; nsrc = GUT_E; }
    else if (e < c4) { src = s_downt;   off = e - c3; nsrc = DOWNT_E; }
    else if (e < c5) { src = s_gum;     off = e - c4; nsrc = GUM_E; }
    else             { src = s_downm;   off = e - c5; nsrc = DOWNM_E; }
    ushort4 r;
    if (off < nsrc) {
        float4 v = *reinterpret_cast<const float4*>(src + off);
        r.x = f2bf(v.x); r.y = f2bf(v.y); r.z = f2bf(v.z); r.w = f2bf(v.w);
    } else {
        r.x = 0; r.y = 0; r.z = 0; r.w = 0;
    }
    *reinterpret_cast<ushort4*>(dst + e) = r;
}

// ----------------------------- bf16 MFMA GEMM (BK=64) ----------------------
// C[M,N] = A[M,K] * W[N,K]^T. 128x128 tile, 4 waves of 64x64 (4x4 MFMAs).
// LDS rows are 64 u16 (128 B); staging: 8 rows x 8 chunks of 16B per inst,
// global chunk = cL ^ rL (3-bit XOR). Frag chunk = (ks*4+kq) ^ (lrow&7).
template<bool SK>
__device__ __forceinline__ void gemm_bt_body(
    const u16* __restrict__ A, const u16* __restrict__ W,
    float* __restrict__ C, int M, int N, int K, int kLen)
{
    __shared__ u16 As[128 * 64];   // 16 KB
    __shared__ u16 Bs[128 * 64];   // 16 KB
    int tid = threadIdx.x;
    int m0 = blockIdx.y * 128, n0 = blockIdx.x * 128;
    int kBase = SK ? blockIdx.z * kLen : 0;
    float* Cw = SK ? C + (size_t)blockIdx.z * M * N : C;
    int wave = tid >> 6, lane = tid & 63;
    int wm = (wave >> 1) * 64, wn = (wave & 1) * 64;
    int lrow = lane & 15;
    int kq = lane >> 4;
    int kx = lrow & 7;

    int rL = lane >> 3, cL = lane & 7;
    int cG = cL ^ rL;
    const u16* gA[4]; const u16* gB[4];
    u16 *lA[4], *lB[4];
    #pragma unroll
    for (int i = 0; i < 4; i++) {
        int r = wave * 32 + i * 8;
        gA[i] = A + (size_t)(m0 + r + rL) * K + kBase + cG * 8;
        gB[i] = W + (size_t)(n0 + r + rL) * K + kBase + cG * 8;
        lA[i] = &As[r * 64];
        lB[i] = &Bs[r * 64];
    }

    f32x4 acc[4][4];
    #pragma unroll
    for (int i = 0; i < 4; i++)
        #pragma unroll
        for (int j = 0; j < 4; j++) {
            acc[i][j][0] = 0.f; acc[i][j][1] = 0.f;
            acc[i][j][2] = 0.f; acc[i][j][3] = 0.f;
        }

    for (int kt = 0; kt < kLen; kt += 64) {
        __syncthreads();
        #pragma unroll
        for (int i = 0; i < 4; i++) {
            gld_lds16(gA[i] + kt, lA[i]);
            gld_lds16(gB[i] + kt, lB[i]);
        }
        __syncthreads();
        #pragma unroll
        for (int ks = 0; ks < 2; ks++) {
            int ko = (((ks * 4 + kq) ^ kx) * 8);
            bf16x8 af[4], bfr[4];
            #pragma unroll
            for (int i = 0; i < 4; i++) {
                af[i]  = *reinterpret_cast<const bf16x8*>(&As[(wm + i * 16 + lrow) * 64 + ko]);
                bfr[i] = *reinterpret_cast<const bf16x8*>(&Bs[(wn + i * 16 + lrow) * 64 + ko]);
            }
            #pragma unroll
            for (int i = 0; i < 4; i++)
                #pragma unroll
                for (int j = 0; j < 4; j++)
                    acc[i][j] = __builtin_amdgcn_mfma_f32_16x16x32_bf16(af[i], bfr[j], acc[i][j], 0, 0, 0);
        }
    }

    // C/D layout: col = lane&15, row = (lane>>4)*4 + reg
    int rbase = m0 + wm + kq * 4;
    int cbase = n0 + wn + lrow;
    #pragma unroll
    for (int i = 0; i < 4; i++)
        #pragma unroll
        for (int j = 0; j < 4; j++)
            #pragma unroll
            for (int r = 0; r < 4; r++)
                Cw[(size_t)(rbase + i * 16 + r) * N + cbase + j * 16] = acc[i][j][r];
}

__global__ __launch_bounds__(256) void gemm_bt(
    const u16* __restrict__ A, const u16* __restrict__ W,
    float* __restrict__ C, int M, int N, int K)
{
    gemm_bt_body<false>(A, W, C, M, N, K, K);
}

__global__ __launch_bounds__(256) void gemm_bt_sk(
    const u16* __restrict__ A, const u16* __restrict__ W,
    float* __restrict__ C, int M, int N, int K, int kLen)
{
    gemm_bt_body<true>(A, W, C, M, N, K, kLen);
}

// --------------- fused gate/up GEMM + SwiGLU (128x64, BK=64) ---------------
// act[M,inter] = silu(A·Wg^T) * (A·Wu^T). Bs rows 0..63 = gate, 64..127 = up.
__global__ __launch_bounds__(256) void gemm_swiglu(
    const u16* __restrict__ A, const u16* __restrict__ W,
    u16* __restrict__ act, int M, int inter, int K)
{
    __shared__ u16 As[128 * 64];   // 16 KB
    __shared__ u16 Bs[128 * 64];   // 16 KB
    int tid = threadIdx.x;
    int m0 = blockIdx.y * 128, n0 = blockIdx.x * 64;
    int wave = tid >> 6, lane = tid & 63;
    int wm = (wave >> 1) * 64, wn = (wave & 1) * 32;
    int lrow = lane & 15;
    int kq = lane >> 4;
    int kx = lrow & 7;

    int rL = lane >> 3, cL = lane & 7;
    int cG = cL ^ rL;
    const u16* gA[4]; const u16* gB[4];
    u16 *lA[4], *lB[4];
    #pragma unroll
    for (int i = 0; i < 4; i++) {
        int r = wave * 32 + i * 8;
        gA[i] = A + (size_t)(m0 + r + rL) * K + cG * 8;
        lA[i] = &As[r * 64];
        int rB = r;   // combined index: 0..63 gate, 64..127 up (per wave 32)
        int grow = (rB < 64) ? (n0 + rB + rL)
                             : (inter + n0 + rB - 64 + rL);
        gB[i] = W + (size_t)grow * K + cG * 8;
        lB[i] = &Bs[rB * 64];
    }

    f32x4 accg[4][2], accu[4][2];
    #pragma unroll
    for (int i = 0; i < 4; i++)
        #pragma unroll
        for (int j = 0; j < 2; j++) {
            accg[i][j][0]=0.f; accg[i][j][1]=0.f; accg[i][j][2]=0.f; accg[i][j][3]=0.f;
            accu[i][j][0]=0.f; accu[i][j][1]=0.f; accu[i][j][2]=0.f; accu[i][j][3]=0.f;
        }

    for (int kt = 0; kt < K; kt += 64) {
        __syncthreads();
        #pragma unroll
        for (int i = 0; i < 4; i++) {
            gld_lds16(gA[i] + kt, lA[i]);
            gld_lds16(gB[i] + kt, lB[i]);
        }
        __syncthreads();
        #pragma unroll
        for (int ks = 0; ks < 2; ks++) {
            int ko = (((ks * 4 + kq) ^ kx) * 8);
            bf16x8 af[4], bg[2], bu[2];
            #pragma unroll
            for (int i = 0; i < 4; i++)
                af[i] = *reinterpret_cast<const bf16x8*>(&As[(wm + i * 16 + lrow) * 64 + ko]);
            #pragma unroll
            for (int j = 0; j < 2; j++) {
                bg[j] = *reinterpret_cast<const bf16x8*>(&Bs[(wn + j * 16 + lrow) * 64 + ko]);
                bu[j] = *reinterpret_cast<const bf16x8*>(&Bs[(64 + wn + j * 16 + lrow) * 64 + ko]);
            }
            #pragma unroll
            for (int i = 0; i < 4; i++)
                #pragma unroll
                for (int j = 0; j < 2; j++) {
                    accg[i][j] = __builtin_amdgcn_mfma_f32_16x16x32_bf16(af[i], bg[j], accg[i][j], 0, 0, 0);
                    accu[i][j] = __builtin_amdgcn_mfma_f32_16x16x32_bf16(af[i], bu[j], accu[i][j], 0, 0, 0);
                }
        }
    }

    int rbase = m0 + wm + kq * 4;
    int cbase = n0 + wn + lrow;
    #pragma unroll
    for (int i = 0; i < 4; i++)
        #pragma unroll
        for (int j = 0; j < 2; j++)
            #pragma unroll
            for (int r = 0; r < 4; r++) {
                float g = accg[i][j][r], u = accu[i][j][r];
                act[(size_t)(rbase + i * 16 + r) * inter + cbase + j * 16] =
                    f2bf(silu_f(g) * u);
            }
}

// ----------------- conv (depthwise, causal, width 4) + dt ------------------
__global__ __launch_bounds__(256) void conv_dt_kernel(
    const float* __restrict__ zx, const float* __restrict__ conv_w,
    const float* __restrict__ conv_b, const float* __restrict__ dt_bias,
    float* __restrict__ convout, float* __restrict__ dtbuf)
{
    int idx = blockIdx.x * 256 + threadIdx.x;   // over 4096*1168
    int bl = idx / 1168;
    int c  = idx - bl * 1168;
    int l  = bl & (LL - 1);
    if (c < CONVDIM) {
        const float* col = zx + (size_t)bl * NPROJ_PAD + DINNER + c;
        float acc = conv_b[c];
        #pragma unroll
        for (int i = 0; i < 4; i++) {
            int lt = l - 3 + i;
            float v = (lt >= 0) ? col[(long long)(lt - l) * NPROJ_PAD] : 0.f;
            acc = fmaf(v, conv_w[c * 4 + i], acc);
        }
        convout[(size_t)bl * CONVDIM + c] = silu_f(acc);
    } else {
        int h = c - CONVDIM;
        float v = zx[(size_t)bl * NPROJ_PAD + 2176 + h] + dt_bias[h];
        float sp = (v > 20.f) ? v : log1pf(__expf(v));
        dtbuf[(size_t)bl * NHEADS + h] = sp;
    }
}

// -------------------- MFMA chunk scan: pass 1 ------------------------------
// R16: 4 heads per block (4 waves). B/C tiles staged ONCE per (b,c,hquad)
// block (was once per head = 16x redundant); per-head arrays are per-wave
// private. Barrier placement identical to the 1-wave version (3 barriers);
// waves do symmetric work so barrier skew is negligible. LDS 60.5 KB ->
// 2 blocks/CU = 8 waves/CU (was ~4.4).
__global__ __launch_bounds__(256) void scan_mfma1(
    const float* __restrict__ convout, const float* __restrict__ dtbuf,
    const float* __restrict__ A_log, float* __restrict__ Sc,
    float* __restrict__ Ptot, float* __restrict__ yp0)
{
    __shared__ u16 Blds[32 * 72];        // raw B bf16 [t][n] (shared)
    __shared__ u16 Clds[32 * 72];        // raw C bf16 [t][n] (shared)
    __shared__ u16 Xt[4][64 * 40];       // x^T bf16 [p][t] (per head)
    __shared__ u16 Bht[4][64 * 40];      // (w_t*dt_t*B)^T bf16 [n][t]
    __shared__ u16 Wlds[4][32 * 40];     // W bf16 [t][t']
    __shared__ float dtl[4][32], cuml[4][32], warr[4][32];

    int blk = blockIdx.x;                // 512 = (b*4 + hq)*32 + c
    int c   = blk & 31;
    int bg  = blk >> 5;
    int b   = bg >> 2;
    int hq  = bg & 3;
    int tid = threadIdx.x;
    int w    = tid >> 6;                 // wave = head within quad
    int lane = tid & 63;
    int h   = hq * 4 + w;
    int bh  = b * 16 + h;
    int lrow = lane & 15, kq = lane >> 4;
    size_t base = ((size_t)b * LL + (size_t)c * CHUNK) * CONVDIM;
    float Ah = -__expf(A_log[h]);

    if (lane < 32)
        dtl[w][lane] = dtbuf[((size_t)b * LL + (size_t)c * CHUNK + lane) * NHEADS + h];
    // shared B/C staging: 256 threads cover 32 t x 32 float4 in 4 iters
    #pragma unroll
    for (int it = 0; it < 4; ++it) {
        int idx = it * 256 + tid;
        int t = idx >> 5, q = idx & 31;
        float4 v = *reinterpret_cast<const float4*>(
            &convout[base + (size_t)t * CONVDIM + DINNER + q * 4]);
        ushort4 r4; r4.x = f2bf(v.x); r4.y = f2bf(v.y); r4.z = f2bf(v.z); r4.w = f2bf(v.w);
        if (q < 16) *reinterpret_cast<ushort4*>(&Blds[t * 72 + q * 4]) = r4;
        else        *reinterpret_cast<ushort4*>(&Clds[t * 72 + (q - 16) * 4]) = r4;
    }
    #pragma unroll
    for (int t = 0; t < 32; ++t) {
        float v = convout[base + (size_t)t * CONVDIM + h * HEADDIM + lane];
        Xt[w][lane * 40 + t] = f2bf(v);
    }
    __syncthreads();

    float s_inc = 0.f, s_all = 0.f;
    #pragma unroll
    for (int j = 0; j < 32; ++j) {
        float v = dtl[w][j];
        s_all += v;
        if (j <= lane) s_inc += v;
    }
    if (lane < 32) {
        cuml[w][lane] = s_inc;
        warr[w][lane] = __expf(Ah * (s_all - s_inc)) * dtl[w][lane];
    }
    float cumTot = s_all;
    __syncthreads();

    #pragma unroll
    for (int t = 0; t < 32; ++t)
        Bht[w][lane * 40 + t] = f2bf(warr[w][t] * bf2f(Blds[t * 72 + lane]));

    f32x4 accG[2][2];
    #pragma unroll
    for (int i = 0; i < 2; i++)
        #pragma unroll
        for (int j = 0; j < 2; j++) {
            accG[i][j][0]=0.f; accG[i][j][1]=0.f; accG[i][j][2]=0.f; accG[i][j][3]=0.f;
        }
    #pragma unroll
    for (int ks = 0; ks < 2; ++ks) {
        bf16x8 af[2], bfr[2];
        #pragma unroll
        for (int i = 0; i < 2; i++) {
            af[i]  = *reinterpret_cast<const bf16x8*>(&Clds[(16*i + lrow) * 72 + ks*32 + kq*8]);
            bfr[i] = *reinterpret_cast<const bf16x8*>(&Blds[(16*i + lrow) * 72 + ks*32 + kq*8]);
        }
        #pragma unroll
        for (int i = 0; i < 2; i++)
            #pragma unroll
            for (int j = 0; j < 2; j++)
                accG[i][j] = __builtin_amdgcn_mfma_f32_16x16x32_bf16(af[i], bfr[j], accG[i][j], 0, 0, 0);
    }

    float ctp0 = cuml[w][lrow],      dtp0 = dtl[w][lrow];
    float ctp1 = cuml[w][16 + lrow], dtp1 = dtl[w][16 + lrow];
    #pragma unroll
    for (int i = 0; i < 2; i++)
        #pragma unroll
        for (int r = 0; r < 4; r++) {
            int t = 16*i + kq*4 + r;
            float ct = cuml[w][t];
            #pragma unroll
            for (int j = 0; j < 2; j++) {
                int tp = 16*j + lrow;
                float ctp = j ? ctp1 : ctp0;
                float dtp = j ? dtp1 : dtp0;
                float g = accG[i][j][r];
                float wv = (tp <= t) ? __expf(Ah * (ct - ctp)) * dtp * g : 0.f;
                Wlds[w][t * 40 + tp] = f2bf(wv);
            }
        }
    __syncthreads();

    bf16x8 xf[4];
    #pragma unroll
    for (int j = 0; j < 4; j++)
        xf[j] = *reinterpret_cast<const bf16x8*>(&Xt[w][(16*j + lrow) * 40 + kq*8]);
    f32x4 accY[2][4];
    #pragma unroll
    for (int i = 0; i < 2; i++) {
        bf16x8 wf = *reinterpret_cast<const bf16x8*>(&Wlds[w][(16*i + lrow) * 40 + kq*8]);
        #pragma unroll
        for (int j = 0; j < 4; j++) {
            accY[i][j][0]=0.f; accY[i][j][1]=0.f; accY[i][j][2]=0.f; accY[i][j][3]=0.f;
            accY[i][j] = __builtin_amdgcn_mfma_f32_16x16x32_bf16(wf, xf[j], accY[i][j], 0, 0, 0);
        }
    }

    f32x4 accS[4][4];
    #pragma unroll
    for (int j = 0; j < 4; j++) {
        bf16x8 bb = *reinterpret_cast<const bf16x8*>(&Bht[w][(16*j + lrow) * 40 + kq*8]);
        #pragma unroll
        for (int i = 0; i < 4; i++) {
            accS[i][j][0]=0.f; accS[i][j][1]=0.f; accS[i][j][2]=0.f; accS[i][j][3]=0.f;
            accS[i][j] = __builtin_amdgcn_mfma_f32_16x16x32_bf16(xf[i], bb, accS[i][j], 0, 0, 0);
        }
    }

    float* yb = yp0 + ((size_t)b * LL + (size_t)c * CHUNK) * DINNER + h * HEADDIM;
    #pragma unroll
    for (int i = 0; i < 2; i++)
        #pragma unroll
        for (int r = 0; r < 4; r++) {
            int t = 16*i + kq*4 + r;
            #pragma unroll
            for (int j = 0; j < 4; j++)
                yb[(size_t)t * DINNER + 16*j + lrow] = accY[i][j][r];
        }
    #pragma unroll
    for (int i = 0; i < 4; i++)
        #pragma unroll
        for (int r = 0; r < 4; r++) {
            int p = 16*i + kq*4 + r;
            #pragma unroll
            for (int j = 0; j < 4; j++)
                Sc[((size_t)(bh * 4 + j) * NCHUNK + c) * 1024 + p * 16 + lrow] = accS[i][j][r];
        }
    if (lane == 0) Ptot[bh * NCHUNK + c] = __expf(Ah * cumTot);
}

// ----------------------- chunked SSM scan: combine -------------------------
// R16: 256 threads/block (4 waves) + float4. R17: Ptot hoisted to registers,
// chunk loop fully unrolled so the 32 independent Sc loads can issue ahead
// of the serial carry-FMA chain.
__global__ __launch_bounds__(256) void scan_combine(
    const float* __restrict__ Sc, const float* __restrict__ Ptot,
    float* __restrict__ Sinit)
{
    int blk = blockIdx.x;             // 256 = bh*4 + n-quarter
    int bh = blk >> 2;
    int tid = threadIdx.x;
    int p = tid >> 2;                 // 0..63
    int ncol = (tid & 3) * 4;         // 4 floats of the 16-wide n slice
    float Pv[NCHUNK];
    #pragma unroll
    for (int c = 0; c < NCHUNK; ++c) Pv[c] = Ptot[bh * NCHUNK + c];
    float4 carry; carry.x = 0.f; carry.y = 0.f; carry.z = 0.f; carry.w = 0.f;
    size_t rowbase = (size_t)blk * NCHUNK * 1024 + p * 16 + ncol;
    #pragma unroll
    for (int c = 0; c < NCHUNK; ++c) {
        size_t row = rowbase + (size_t)c * 1024;
        *reinterpret_cast<float4*>(Sinit + row) = carry;
        float4 si = *reinterpret_cast<const float4*>(Sc + row);
        carry.x = fmaf(carry.x, Pv[c], si.x);
        carry.y = fmaf(carry.y, Pv[c], si.y);
        carry.z = fmaf(carry.z, Pv[c], si.z);
        carry.w = fmaf(carry.w, Pv[c], si.w);
    }
}

// -------------------- MFMA chunk scan: pass 2 ------------------------------
// R17: 4 heads per 256-thread block (grid 2048 -> 512). Raw C is staged ONCE
// per block (head-independent); the dacl[t] factor is a per-OUTPUT-ROW scale
// in the C*Sinit MFMA (t = A-row = output row), so it moves to the f32
// epilogue. LDS 5.6 KB -> occupancy 8 blocks/CU (32 waves/CU, was ~8).
__global__ __launch_bounds__(256) void scan_mfma2(
    const float* __restrict__ convout, const float* __restrict__ dtbuf,
    const float* __restrict__ A_log, const float* __restrict__ Sinit,
    float* __restrict__ yp1)
{
    __shared__ u16 Clds2[32 * 72];       // raw C bf16 [t][n] (shared)
    __shared__ float dtl[4][32], dacl[4][32];
    int blk = blockIdx.x;                // 512 = (b*4 + hq)*32 + c
    int c   = blk & 31;
    int bg  = blk >> 5;
    int b   = bg >> 2;
    int hq  = bg & 3;
    int tid = threadIdx.x;
    int w    = tid >> 6;                 // wave = head within quad
    int lane = tid & 63;
    int h   = hq * 4 + w;
    int bh  = b * 16 + h;
    int lrow = lane & 15, kq = lane >> 4;
    size_t base = ((size_t)b * LL + (size_t)c * CHUNK) * CONVDIM;
    float Ah = -__expf(A_log[h]);

    if (lane < 32)
        dtl[w][lane] = dtbuf[((size_t)b * LL + (size_t)c * CHUNK + lane) * NHEADS + h];
    // shared raw-C staging: 32 t x 16 float4 = 512 float4 over 256 thr, 2 it
    #pragma unroll
    for (int it = 0; it < 2; ++it) {
        int idx = it * 256 + tid;
        int t = idx >> 4, q = idx & 15;
        float4 v = *reinterpret_cast<const float4*>(
            &convout[base + (size_t)t * CONVDIM + DINNER + DSTATE + q * 4]);
        ushort4 r4;
        r4.x = f2bf(v.x); r4.y = f2bf(v.y);
        r4.z = f2bf(v.z); r4.w = f2bf(v.w);
        *reinterpret_cast<ushort4*>(&Clds2[t * 72 + q * 4]) = r4;
    }
    __syncthreads();

    float s_inc = 0.f;
    #pragma unroll
    for (int j = 0; j < 32; ++j) {
        float v = dtl[w][j];
        if (j <= lane) s_inc += v;
    }
    if (lane < 32) dacl[w][lane] = __expf(Ah * s_inc);

    f32x4 accI[2][4];
    #pragma unroll
    for (int i = 0; i < 2; i++)
        #pragma unroll
        for (int j = 0; j < 4; j++) {
            accI[i][j][0]=0.f; accI[i][j][1]=0.f; accI[i][j][2]=0.f; accI[i][j][3]=0.f;
        }
    #pragma unroll
    for (int ks = 0; ks < 2; ++ks) {
        bf16x8 ca[2];
        #pragma unroll
        for (int i = 0; i < 2; i++)
            ca[i] = *reinterpret_cast<const bf16x8*>(&Clds2[(16*i + lrow) * 72 + ks*32 + kq*8]);
        int nq = ks * 2 + (kq >> 1);
        int off = (kq & 1) * 8;
        #pragma unroll
        for (int j = 0; j < 4; j++) {
            int p = 16*j + lrow;
            const float* sp = Sinit + ((size_t)(bh * 4 + nq) * NCHUNK + c) * 1024 + p * 16 + off;
            float4 a = *reinterpret_cast<const float4*>(sp);
            float4 b4 = *reinterpret_cast<const float4*>(sp + 4);
            union { u16 us[8]; bf16x8 v; } fr;
            fr.us[0] = f2bf(a.x);  fr.us[1] = f2bf(a.y);
            fr.us[2] = f2bf(a.z);  fr.us[3] = f2bf(a.w);
            fr.us[4] = f2bf(b4.x); fr.us[5] = f2bf(b4.y);
            fr.us[6] = f2bf(b4.z); fr.us[7] = f2bf(b4.w);
            #pragma unroll
            for (int i = 0; i < 2; i++)
                accI[i][j] = __builtin_amdgcn_mfma_f32_16x16x32_bf16(ca[i], fr.v, accI[i][j], 0, 0, 0);
        }
    }

    float* yb = yp1 + ((size_t)b * LL + (size_t)c * CHUNK) * DINNER + h * HEADDIM;
    #pragma unroll
    for (int i = 0; i < 2; i++)
        #pragma unroll
        for (int r = 0; r < 4; r++) {
            int t = 16*i + kq*4 + r;
            float sct = dacl[w][t];
            #pragma unroll
            for (int j = 0; j < 4; j++)
                yb[(size_t)t * DINNER + 16*j + lrow] = accI[i][j][r] * sct;
        }
}

// ------------- gated RMSNorm (yp0+yp1+xD)*silu(z), bf16 out ----------------
__global__ __launch_bounds__(256) void gated_rms_kernel(
    const float* __restrict__ yp0, const float* __restrict__ yp1,
    const float* __restrict__ convout, const float* __restrict__ zx,
    const float* __restrict__ Dv, const float* __restrict__ norm_w,
    u16* __restrict__ gout)
{
    int bl = blockIdx.x;
    int c = threadIdx.x * 4;
    float4 y0 = *reinterpret_cast<const float4*>(yp0 + (size_t)bl * DINNER + c);
    float4 y1 = *reinterpret_cast<const float4*>(yp1 + (size_t)bl * DINNER + c);
    float4 xv = *reinterpret_cast<const float4*>(convout + (size_t)bl * CONVDIM + c);
    float4 zv = *reinterpret_cast<const float4*>(zx + (size_t)bl * NPROJ_PAD + c);
    float Dh = Dv[c >> 6];
    float g0 = (y0.x + y1.x + xv.x * Dh) * silu_f(zv.x);
    float g1 = (y0.y + y1.y + xv.y * Dh) * silu_f(zv.y);
    float g2 = (y0.z + y1.z + xv.z * Dh) * silu_f(zv.z);
    float g3 = (y0.w + y1.w + xv.w * Dh) * silu_f(zv.w);
    float tot = block_sum(g0 * g0 + g1 * g1 + g2 * g2 + g3 * g3);
    float sc = rsqrtf(tot * (1.f / DINNER) + 1e-5f);
    float4 nw = *reinterpret_cast<const float4*>(norm_w + c);
    ushort4 o;
    o.x = f2bf(g0 * sc * nw.x); o.y = f2bf(g1 * sc * nw.y);
    o.z = f2bf(g2 * sc * nw.z); o.w = f2bf(g3 * sc * nw.w);
    *reinterpret_cast<ushort4*>(gout + (size_t)bl * DINNER + c) = o;
}

// ---- residual + 4 split-K partials + RMSNorm (no weight), f32 out ---------
__global__ void residual_rms_sk_kernel(
    const float* __restrict__ a, const float* __restrict__ pbuf,
    float* __restrict__ outf, int ncols, int rows)
{
    int row = blockIdx.x;
    int c = threadIdx.x * 4;
    size_t slice = (size_t)rows * ncols;
    size_t off = (size_t)row * ncols + c;
    float4 va = *reinterpret_cast<const float4*>(a + off);
    float4 p0 = *reinterpret_cast<const float4*>(pbuf + off);
    float4 p1 = *reinterpret_cast<const float4*>(pbuf + slice + off);
    float4 p2 = *reinterpret_cast<const float4*>(pbuf + 2 * slice + off);
    float4 p3 = *reinterpret_cast<const float4*>(pbuf + 3 * slice + off);
    float v0 = va.x + ((p0.x + p1.x) + (p2.x + p3.x));
    float v1 = va.y + ((p0.y + p1.y) + (p2.y + p3.y));
    float v2 = va.z + ((p0.z + p1.z) + (p2.z + p3.z));
    float v3 = va.w + ((p0.w + p1.w) + (p2.w + p3.w));
    float tot = block_sum(v0 * v0 + v1 * v1 + v2 * v2 + v3 * v3);
    float sc = rsqrtf(tot / (float)ncols + 1e-5f);
    float4 o; o.x = v0 * sc; o.y = v1 * sc; o.z = v2 * sc; o.w = v3 * sc;
    *reinterpret_cast<float4*>(outf + off) = o;
}

// ------------- transpose per batch: in (R,C) -> out (C,R), dual write ------
__global__ __launch_bounds__(256) void transpose_dual_kernel(
    const float* __restrict__ in, u16* __restrict__ outb,
    float* __restrict__ outf, int R, int C)
{
    __shared__ float tile[32][33];
    int b = blockIdx.z;
    int c0 = blockIdx.x * 32, r0 = blockIdx.y * 32;
    const float* ip = in + (size_t)b * R * C;
    for (int i = threadIdx.y; i < 32; i += 8)
        tile[i][threadIdx.x] = ip[(size_t)(r0 + i) * C + c0 + threadIdx.x];
    __syncthreads();
    size_t ob = (size_t)b * R * C;
    for (int i = threadIdx.y; i < 32; i += 8) {
        float v = tile[threadIdx.x][i];
        size_t oi = ob + (size_t)(c0 + i) * R + r0 + threadIdx.x;
        outf[oi] = v;
        outb[oi] = f2bf(v);
    }
}

// ---------------------------------------------------------------------------
extern "C" void kernel_launch(void* const* d_in, const int* in_sizes, int n_in,
                              void* d_out, int out_size, void* d_ws, size_t ws_size,
                              hipStream_t stream)
{
    const float* hid      = (const float*)d_in[0];
    const float* in_proj  = (const float*)d_in[1];
    const float* conv_w   = (const float*)d_in[2];
    const float* conv_b   = (const float*)d_in[3];
    const float* dt_bias  = (const float*)d_in[4];
    const float* A_log    = (const float*)d_in[5];
    const float* Dv       = (const float*)d_in[6];
    const float* norm_w   = (const float*)d_in[7];
    const float* out_proj = (const float*)d_in[8];
    const float* gu_t     = (const float*)d_in[9];
    const float* down_t   = (const float*)d_in[10];
    const float* gu_m     = (const float*)d_in[11];
    const float* down_m   = (const float*)d_in[12];
    float* outp = (float*)d_out;

    char* ws = (char*)d_ws;
    u16* bf        = (u16*)ws;
    u16* hid_bf    = bf;
    u16* w_inproj  = bf + HID_E;
    u16* w_outproj = w_inproj + INPROJ_P_E;
    u16* w_gut     = w_outproj + OUTPROJ_E;
    u16* w_downt   = w_gut + GUT_E;
    u16* w_gum     = w_downt + DOWNT_E;
    u16* w_downm   = w_gum + GUM_E;
    size_t o = (size_t)(CONV_TOT_E * 2);
    auto alloc = [&](size_t bytes) { size_t r = o; o = (o + bytes + 255) & ~(size_t)255; return r; };
    size_t dt_off  = alloc(4096 * 16 * 4);
    size_t g_off   = alloc((size_t)4096 * 1024 * 2);
    size_t h1_off  = alloc((size_t)4096 * 512 * 4);
    size_t Pt_off  = alloc(2048 * 4);
    // ---- MLP region (live step 8+); Sc/Sinit OVERLAY it (live steps 4-5).
    size_t xtb_off = alloc((size_t)2048 * 1024 * 2);
    size_t xtf_off = alloc((size_t)2048 * 1024 * 4);
    size_t act1_off= alloc((size_t)2048 * 2816 * 2);
    size_t x2_off  = alloc((size_t)2048 * 1024 * 4);
    size_t h2b_off = alloc((size_t)4096 * 512 * 2);
    size_t h2f_off = alloc((size_t)4096 * 512 * 4);
    size_t act2_off= alloc((size_t)4096 * 1536 * 2);
    size_t pad_off = alloc((size_t)10 * 1024 * 1024);
    size_t Sc_off  = xtb_off;                          // 33.55 MB
    size_t Si_off  = xtb_off + (size_t)8192 * 1024 * 4;// 33.55 MB
    (void)pad_off;
    size_t R_off   = o;
    size_t zx_off  = R_off;
    size_t cv_off  = zx_off + (size_t)4096 * NPROJ_PAD * 4;
    size_t y_off   = cv_off + (size_t)4096 * CONVDIM * 4;
    size_t sk_off  = R_off;

    float* zx      = (float*)(ws + zx_off);
    float* convout = (float*)(ws + cv_off);
    float* ybuf    = (float*)(ws + y_off);           // yp0
    float* dtbuf   = (float*)(ws + dt_off);
    u16*   g_bf    = (u16*)(ws + g_off);
    float* h1      = (float*)(ws + h1_off);
    u16*   xt_bf   = (u16*)(ws + xtb_off);
    float* xt_f    = (float*)(ws + xtf_off);
    u16*   act1    = (u16*)(ws + act1_off);
    float* x2      = (float*)(ws + x2_off);
    u16*   h2_bf   = (u16*)(ws + h2b_off);
    float* h2_f    = (float*)(ws + h2f_off);
    u16*   act2    = (u16*)(ws + act2_off);
    float* skbuf   = (float*)(ws + sk_off);
    float* Sc      = (float*)(ws + Sc_off);          // yp1 after scan_combine
    float* Sinit   = (float*)(ws + Si_off);
    float* Ptot    = (float*)(ws + Pt_off);

    // 1) convert weights + hidden to bf16
    convert_all_kernel<<<14464, 256, 0, stream>>>(
        hid, in_proj, out_proj, gu_t, down_t, gu_m, down_m, bf);

    // 2) zxbcdt = hidden @ in_proj^T
    gemm_bt<<<dim3(NPROJ_PAD / 128, 4096 / 128), 256, 0, stream>>>(
        hid_bf, w_inproj, zx, 4096, NPROJ_PAD, 512);

    // 3) conv + dt
    conv_dt_kernel<<<18688, 256, 0, stream>>>(zx, conv_w, conv_b, dt_bias, convout, dtbuf);

    // 4) MFMA chunk scan (R17: both passes 4 heads/block)
    scan_mfma1<<<512, 256, 0, stream>>>(convout, dtbuf, A_log, Sc, Ptot, ybuf);
    scan_combine<<<256, 256, 0, stream>>>(Sc, Ptot, Sinit);
    scan_mfma2<<<512, 256, 0, stream>>>(convout, dtbuf, A_log, Sinit, Sc);

    // 5) gated RMSNorm -> bf16
    gated_rms_kernel<<<4096, 256, 0, stream>>>(ybuf, Sc, convout, zx, Dv, norm_w, g_bf);

    // 6) out_proj GEMM, split-K x4 -> partials in skbuf
    gemm_bt_sk<<<dim3(512 / 128, 4096 / 128, 4), 256, 0, stream>>>(
        g_bf, w_outproj, skbuf, 4096, 512, 1024, 256);

    // 7) h1 = rms(hidden + sum partials)
    residual_rms_sk_kernel<<<4096, 128, 0, stream>>>(hid, skbuf, h1, 512, 4096);

    // 8) transpose (B,1024,512) -> (B,512,1024)
    transpose_dual_kernel<<<dim3(16, 32, 4), dim3(32, 8), 0, stream>>>(h1, xt_bf, xt_f, 1024, 512);

    // 9) token MLP fused: act1 = swiglu(xt @ gu_t^T)  (704 blocks, 128x64)
    gemm_swiglu<<<dim3(INTER_T / 64, 2048 / 128), 256, 0, stream>>>(
        xt_bf, w_gut, act1, 2048, INTER_T, 1024);

    // 10) down_t GEMM, split-K x4 -> partials in skbuf
    gemm_bt_sk<<<dim3(1024 / 128, 2048 / 128, 4), 256, 0, stream>>>(
        act1, w_downt, skbuf, 2048, 1024, 2816, 704);

    // 11) x2 = rms(xt_f + sum partials)
    residual_rms_sk_kernel<<<2048, 256, 0, stream>>>(xt_f, skbuf, x2, 1024, 2048);

    // 12) transpose back (B,512,1024) -> (B,1024,512)
    transpose_dual_kernel<<<dim3(32, 16, 4), dim3(32, 8), 0, stream>>>(x2, h2_bf, h2_f, 512, 1024);

    // 13) channel MLP fused: act2 = swiglu(h2 @ gu_m^T)  (768 blocks, 128x64)
    gemm_swiglu<<<dim3(INTER_M / 64, 4096 / 128), 256, 0, stream>>>(
        h2_bf, w_gum, act2, 4096, INTER_M, 512);

    // 14) down_m GEMM, split-K x4 -> partials in skbuf
    gemm_bt_sk<<<dim3(512 / 128, 4096 / 128, 4), 256, 0, stream>>>(
        act2, w_downm, skbuf, 4096, 512, 1536, 384);

    // 15) out = rms(h2_f + sum partials)
    residual_rms_sk_kernel<<<4096, 128, 0, stream>>>(h2_f, skbuf, outp, 512, 4096);
}

// Round 4
// 328.230 us; speedup vs baseline: 1.0528x; 1.0528x over previous
//
#include <hip/hip_runtime.h>

// ---------------------------------------------------------------------------
// Mamba2 hybrid block. GEMMs: bf16 MFMA 16x16x32, f32 accumulate, m97-style
// global_load_lds(16B) staging, BK=64 (R15: single-buffered K-loop is ~53%
// barrier drain at 2-3 blocks/CU; 64-wide K tiles halve barrier count.
// 3-bit XOR chunk swizzle keeps frag reads 2-way/free). Small-N GEMMs use
// split-K x4 into SEPARATE partial buffers; partials summed in the
// downstream residual_rms kernel. MLP gu-GEMMs fuse SwiGLU (128x64 act tile;
// R14: acc must stay <=16 f32x4 or VGPR cliff). Scan: MFMA chunked.
// R16: scan_mfma1 4 heads/block shared B/C staging (-14.1 us, 355.5->341.4).
// R17/R18: scan_mfma2 4 heads/block, dacl folded to epilogue; scan_combine
// unrolled. Measured NEUTRAL (345.6 +/- noise) -> scan tail was smaller than
// modeled; top-5 now saturated by harness fills (all our kernels <40 us).
// R19: bf16 scan state. Sinit was ALREADY rounded to bf16 at its only use
// (f2bf in scan_mfma2's fragment build) -> storing bf16 is numerically
// IDENTICAL, and the fragment build becomes one b128 load. Sc / yp0 / yp1
// also bf16 (one extra 2^-9 rounding each, small vs existing MFMA error).
// Cuts ~100 MB HBM round-trip (~16 us) + VALU convert chains.
// ---------------------------------------------------------------------------

#define BB 4
#define LL 1024
#define DMODEL 512
#define DINNER 1024
#define NHEADS 16
#define HEADDIM 64
#define DSTATE 64
#define CONVDIM 1152        // DINNER + 2*DSTATE
#define NPROJ 2192          // D_IN_PROJ
#define NPROJ_PAD 2304      // padded to multiple of 128
#define INTER_T 2816
#define INTER_M 1536
#define NCHUNK 32
#define CHUNK 32

typedef __bf16 bf16x8 __attribute__((ext_vector_type(8)));
typedef float  f32x4  __attribute__((ext_vector_type(4)));
typedef unsigned short u16;
typedef unsigned int   u32;

__device__ __forceinline__ u16 f2bf(float x) {
    union { float f; u32 u; } v; v.f = x;
    u32 u = v.u;
    return (u16)((u + 0x7fffu + ((u >> 16) & 1u)) >> 16);
}
__device__ __forceinline__ float silu_f(float x) {
    return x / (1.f + __expf(-x));
}
__device__ __forceinline__ float bf2f(u16 w) {
    union { u32 u; float f; } a; a.u = ((u32)w) << 16; return a.f;
}

// async global->LDS, 16B per lane; LDS dest is wave-uniform base + lane*16
__device__ __forceinline__ void gld_lds16(const u16* g, u16* l) {
    __builtin_amdgcn_global_load_lds(
        (const __attribute__((address_space(1))) unsigned int*)g,
        (__attribute__((address_space(3))) unsigned int*)l, 16, 0, 0);
}

// --------------------------- block-wide sum --------------------------------
__device__ __forceinline__ float block_sum(float v) {
    #pragma unroll
    for (int off = 32; off > 0; off >>= 1) v += __shfl_xor(v, off, 64);
    __shared__ float red[4];
    int w = threadIdx.x >> 6;
    int nwv = blockDim.x >> 6;
    if ((threadIdx.x & 63) == 0) red[w] = v;
    __syncthreads();
    float tot = red[0];
    for (int i = 1; i < nwv; i++) tot += red[i];
    return tot;
}

// --------------------- f32 -> bf16 convert (all weights + hidden) ----------
#define HID_E      2097152LL   // 4096*512
#define INPROJ_P_E 1179648LL   // 2304*512
#define INPROJ_S_E 1122304LL   // 2192*512
#define OUTPROJ_E   524288LL   // 512*1024
#define GUT_E      5767168LL   // 5632*1024
#define DOWNT_E    2883584LL   // 1024*2816
#define GUM_E      1572864LL   // 3072*512
#define DOWNM_E     786432LL   // 512*1536
#define CONV_TOT_E 14811136LL

__global__ __launch_bounds__(256) void convert_all_kernel(
    const float* __restrict__ s_hid, const float* __restrict__ s_inproj,
    const float* __restrict__ s_outproj, const float* __restrict__ s_gut,
    const float* __restrict__ s_downt, const float* __restrict__ s_gum,
    const float* __restrict__ s_downm, u16* __restrict__ dst)
{
    long long idx = (long long)blockIdx.x * 256 + threadIdx.x;
    long long e = idx * 4;
    if (e >= CONV_TOT_E) return;
    const float* src; long long off, nsrc;
    long long c0 = HID_E;
    long long c1 = c0 + INPROJ_P_E;
    long long c2 = c1 + OUTPROJ_E;
    long long c3 = c2 + GUT_E;
    long long c4 = c3 + DOWNT_E;
    long long c5 = c4 + GUM_E;
    if      (e < c0) { src = s_hid;     off = e;      nsrc = HID_E; }
    else if (e < c1) { src = s_inproj;  off = e - c0; nsrc = INPROJ_S_E; }
    else if (e < c2) { src = s_outproj; off = e - c1; nsrc = OUTPROJ_E; }
    else if (e < c3) { src = s_gut;     off = e - c2; nsrc = GUT_E; }
    else if (e < c4) { src = s_downt;   off = e - c3; nsrc = DOWNT_E; }
    else if (e < c5) { src = s_gum;     off = e - c4; nsrc = GUM_E; }
    else             { src = s_downm;   off = e - c5; nsrc = DOWNM_E; }
    ushort4 r;
    if (off < nsrc) {
        float4 v = *reinterpret_cast<const float4*>(src + off);
        r.x = f2bf(v.x); r.y = f2bf(v.y); r.z = f2bf(v.z); r.w = f2bf(v.w);
    } else {
        r.x = 0; r.y = 0; r.z = 0; r.w = 0;
    }
    *reinterpret_cast<ushort4*>(dst + e) = r;
}

// ----------------------------- bf16 MFMA GEMM (BK=64) ----------------------
// C[M,N] = A[M,K] * W[N,K]^T. 128x128 tile, 4 waves of 64x64 (4x4 MFMAs).
// LDS rows are 64 u16 (128 B); staging: 8 rows x 8 chunks of 16B per inst,
// global chunk = cL ^ rL (3-bit XOR). Frag chunk = (ks*4+kq) ^ (lrow&7).
template<bool SK>
__device__ __forceinline__ void gemm_bt_body(
    const u16* __restrict__ A, const u16* __restrict__ W,
    float* __restrict__ C, int M, int N, int K, int kLen)
{
    __shared__ u16 As[128 * 64];   // 16 KB
    __shared__ u16 Bs[128 * 64];   // 16 KB
    int tid = threadIdx.x;
    int m0 = blockIdx.y * 128, n0 = blockIdx.x * 128;
    int kBase = SK ? blockIdx.z * kLen : 0;
    float* Cw = SK ? C + (size_t)blockIdx.z * M * N : C;
    int wave = tid >> 6, lane = tid & 63;
    int wm = (wave >> 1) * 64, wn = (wave & 1) * 64;
    int lrow = lane & 15;
    int kq = lane >> 4;
    int kx = lrow & 7;

    int rL = lane >> 3, cL = lane & 7;
    int cG = cL ^ rL;
    const u16* gA[4]; const u16* gB[4];
    u16 *lA[4], *lB[4];
    #pragma unroll
    for (int i = 0; i < 4; i++) {
        int r = wave * 32 + i * 8;
        gA[i] = A + (size_t)(m0 + r + rL) * K + kBase + cG * 8;
        gB[i] = W + (size_t)(n0 + r + rL) * K + kBase + cG * 8;
        lA[i] = &As[r * 64];
        lB[i] = &Bs[r * 64];
    }

    f32x4 acc[4][4];
    #pragma unroll
    for (int i = 0; i < 4; i++)
        #pragma unroll
        for (int j = 0; j < 4; j++) {
            acc[i][j][0] = 0.f; acc[i][j][1] = 0.f;
            acc[i][j][2] = 0.f; acc[i][j][3] = 0.f;
        }

    for (int kt = 0; kt < kLen; kt += 64) {
        __syncthreads();
        #pragma unroll
        for (int i = 0; i < 4; i++) {
            gld_lds16(gA[i] + kt, lA[i]);
            gld_lds16(gB[i] + kt, lB[i]);
        }
        __syncthreads();
        #pragma unroll
        for (int ks = 0; ks < 2; ks++) {
            int ko = (((ks * 4 + kq) ^ kx) * 8);
            bf16x8 af[4], bfr[4];
            #pragma unroll
            for (int i = 0; i < 4; i++) {
                af[i]  = *reinterpret_cast<const bf16x8*>(&As[(wm + i * 16 + lrow) * 64 + ko]);
                bfr[i] = *reinterpret_cast<const bf16x8*>(&Bs[(wn + i * 16 + lrow) * 64 + ko]);
            }
            #pragma unroll
            for (int i = 0; i < 4; i++)
                #pragma unroll
                for (int j = 0; j < 4; j++)
                    acc[i][j] = __builtin_amdgcn_mfma_f32_16x16x32_bf16(af[i], bfr[j], acc[i][j], 0, 0, 0);
        }
    }

    // C/D layout: col = lane&15, row = (lane>>4)*4 + reg
    int rbase = m0 + wm + kq * 4;
    int cbase = n0 + wn + lrow;
    #pragma unroll
    for (int i = 0; i < 4; i++)
        #pragma unroll
        for (int j = 0; j < 4; j++)
            #pragma unroll
            for (int r = 0; r < 4; r++)
                Cw[(size_t)(rbase + i * 16 + r) * N + cbase + j * 16] = acc[i][j][r];
}

__global__ __launch_bounds__(256) void gemm_bt(
    const u16* __restrict__ A, const u16* __restrict__ W,
    float* __restrict__ C, int M, int N, int K)
{
    gemm_bt_body<false>(A, W, C, M, N, K, K);
}

__global__ __launch_bounds__(256) void gemm_bt_sk(
    const u16* __restrict__ A, const u16* __restrict__ W,
    float* __restrict__ C, int M, int N, int K, int kLen)
{
    gemm_bt_body<true>(A, W, C, M, N, K, kLen);
}

// --------------- fused gate/up GEMM + SwiGLU (128x64, BK=64) ---------------
// act[M,inter] = silu(A·Wg^T) * (A·Wu^T). Bs rows 0..63 = gate, 64..127 = up.
__global__ __launch_bounds__(256) void gemm_swiglu(
    const u16* __restrict__ A, const u16* __restrict__ W,
    u16* __restrict__ act, int M, int inter, int K)
{
    __shared__ u16 As[128 * 64];   // 16 KB
    __shared__ u16 Bs[128 * 64];   // 16 KB
    int tid = threadIdx.x;
    int m0 = blockIdx.y * 128, n0 = blockIdx.x * 64;
    int wave = tid >> 6, lane = tid & 63;
    int wm = (wave >> 1) * 64, wn = (wave & 1) * 32;
    int lrow = lane & 15;
    int kq = lane >> 4;
    int kx = lrow & 7;

    int rL = lane >> 3, cL = lane & 7;
    int cG = cL ^ rL;
    const u16* gA[4]; const u16* gB[4];
    u16 *lA[4], *lB[4];
    #pragma unroll
    for (int i = 0; i < 4; i++) {
        int r = wave * 32 + i * 8;
        gA[i] = A + (size_t)(m0 + r + rL) * K + cG * 8;
        lA[i] = &As[r * 64];
        int rB = r;   // combined index: 0..63 gate, 64..127 up (per wave 32)
        int grow = (rB < 64) ? (n0 + rB + rL)
                             : (inter + n0 + rB - 64 + rL);
        gB[i] = W + (size_t)grow * K + cG * 8;
        lB[i] = &Bs[rB * 64];
    }

    f32x4 accg[4][2], accu[4][2];
    #pragma unroll
    for (int i = 0; i < 4; i++)
        #pragma unroll
        for (int j = 0; j < 2; j++) {
            accg[i][j][0]=0.f; accg[i][j][1]=0.f; accg[i][j][2]=0.f; accg[i][j][3]=0.f;
            accu[i][j][0]=0.f; accu[i][j][1]=0.f; accu[i][j][2]=0.f; accu[i][j][3]=0.f;
        }

    for (int kt = 0; kt < K; kt += 64) {
        __syncthreads();
        #pragma unroll
        for (int i = 0; i < 4; i++) {
            gld_lds16(gA[i] + kt, lA[i]);
            gld_lds16(gB[i] + kt, lB[i]);
        }
        __syncthreads();
        #pragma unroll
        for (int ks = 0; ks < 2; ks++) {
            int ko = (((ks * 4 + kq) ^ kx) * 8);
            bf16x8 af[4], bg[2], bu[2];
            #pragma unroll
            for (int i = 0; i < 4; i++)
                af[i] = *reinterpret_cast<const bf16x8*>(&As[(wm + i * 16 + lrow) * 64 + ko]);
            #pragma unroll
            for (int j = 0; j < 2; j++) {
                bg[j] = *reinterpret_cast<const bf16x8*>(&Bs[(wn + j * 16 + lrow) * 64 + ko]);
                bu[j] = *reinterpret_cast<const bf16x8*>(&Bs[(64 + wn + j * 16 + lrow) * 64 + ko]);
            }
            #pragma unroll
            for (int i = 0; i < 4; i++)
                #pragma unroll
                for (int j = 0; j < 2; j++) {
                    accg[i][j] = __builtin_amdgcn_mfma_f32_16x16x32_bf16(af[i], bg[j], accg[i][j], 0, 0, 0);
                    accu[i][j] = __builtin_amdgcn_mfma_f32_16x16x32_bf16(af[i], bu[j], accu[i][j], 0, 0, 0);
                }
        }
    }

    int rbase = m0 + wm + kq * 4;
    int cbase = n0 + wn + lrow;
    #pragma unroll
    for (int i = 0; i < 4; i++)
        #pragma unroll
        for (int j = 0; j < 2; j++)
            #pragma unroll
            for (int r = 0; r < 4; r++) {
                float g = accg[i][j][r], u = accu[i][j][r];
                act[(size_t)(rbase + i * 16 + r) * inter + cbase + j * 16] =
                    f2bf(silu_f(g) * u);
            }
}

// ----------------- conv (depthwise, causal, width 4) + dt ------------------
__global__ __launch_bounds__(256) void conv_dt_kernel(
    const float* __restrict__ zx, const float* __restrict__ conv_w,
    const float* __restrict__ conv_b, const float* __restrict__ dt_bias,
    float* __restrict__ convout, float* __restrict__ dtbuf)
{
    int idx = blockIdx.x * 256 + threadIdx.x;   // over 4096*1168
    int bl = idx / 1168;
    int c  = idx - bl * 1168;
    int l  = bl & (LL - 1);
    if (c < CONVDIM) {
        const float* col = zx + (size_t)bl * NPROJ_PAD + DINNER + c;
        float acc = conv_b[c];
        #pragma unroll
        for (int i = 0; i < 4; i++) {
            int lt = l - 3 + i;
            float v = (lt >= 0) ? col[(long long)(lt - l) * NPROJ_PAD] : 0.f;
            acc = fmaf(v, conv_w[c * 4 + i], acc);
        }
        convout[(size_t)bl * CONVDIM + c] = silu_f(acc);
    } else {
        int h = c - CONVDIM;
        float v = zx[(size_t)bl * NPROJ_PAD + 2176 + h] + dt_bias[h];
        float sp = (v > 20.f) ? v : log1pf(__expf(v));
        dtbuf[(size_t)bl * NHEADS + h] = sp;
    }
}

// -------------------- MFMA chunk scan: pass 1 ------------------------------
// R16: 4 heads per block (4 waves), shared B/C staging.
// R19: Sc and yp0 outputs are bf16 (halves the scan-state HBM round-trip).
__global__ __launch_bounds__(256) void scan_mfma1(
    const float* __restrict__ convout, const float* __restrict__ dtbuf,
    const float* __restrict__ A_log, u16* __restrict__ Sc,
    float* __restrict__ Ptot, u16* __restrict__ yp0)
{
    __shared__ u16 Blds[32 * 72];        // raw B bf16 [t][n] (shared)
    __shared__ u16 Clds[32 * 72];        // raw C bf16 [t][n] (shared)
    __shared__ u16 Xt[4][64 * 40];       // x^T bf16 [p][t] (per head)
    __shared__ u16 Bht[4][64 * 40];      // (w_t*dt_t*B)^T bf16 [n][t]
    __shared__ u16 Wlds[4][32 * 40];     // W bf16 [t][t']
    __shared__ float dtl[4][32], cuml[4][32], warr[4][32];

    int blk = blockIdx.x;                // 512 = (b*4 + hq)*32 + c
    int c   = blk & 31;
    int bg  = blk >> 5;
    int b   = bg >> 2;
    int hq  = bg & 3;
    int tid = threadIdx.x;
    int w    = tid >> 6;                 // wave = head within quad
    int lane = tid & 63;
    int h   = hq * 4 + w;
    int bh  = b * 16 + h;
    int lrow = lane & 15, kq = lane >> 4;
    size_t base = ((size_t)b * LL + (size_t)c * CHUNK) * CONVDIM;
    float Ah = -__expf(A_log[h]);

    if (lane < 32)
        dtl[w][lane] = dtbuf[((size_t)b * LL + (size_t)c * CHUNK + lane) * NHEADS + h];
    // shared B/C staging: 256 threads cover 32 t x 32 float4 in 4 iters
    #pragma unroll
    for (int it = 0; it < 4; ++it) {
        int idx = it * 256 + tid;
        int t = idx >> 5, q = idx & 31;
        float4 v = *reinterpret_cast<const float4*>(
            &convout[base + (size_t)t * CONVDIM + DINNER + q * 4]);
        ushort4 r4; r4.x = f2bf(v.x); r4.y = f2bf(v.y); r4.z = f2bf(v.z); r4.w = f2bf(v.w);
        if (q < 16) *reinterpret_cast<ushort4*>(&Blds[t * 72 + q * 4]) = r4;
        else        *reinterpret_cast<ushort4*>(&Clds[t * 72 + (q - 16) * 4]) = r4;
    }
    #pragma unroll
    for (int t = 0; t < 32; ++t) {
        float v = convout[base + (size_t)t * CONVDIM + h * HEADDIM + lane];
        Xt[w][lane * 40 + t] = f2bf(v);
    }
    __syncthreads();

    float s_inc = 0.f, s_all = 0.f;
    #pragma unroll
    for (int j = 0; j < 32; ++j) {
        float v = dtl[w][j];
        s_all += v;
        if (j <= lane) s_inc += v;
    }
    if (lane < 32) {
        cuml[w][lane] = s_inc;
        warr[w][lane] = __expf(Ah * (s_all - s_inc)) * dtl[w][lane];
    }
    float cumTot = s_all;
    __syncthreads();

    #pragma unroll
    for (int t = 0; t < 32; ++t)
        Bht[w][lane * 40 + t] = f2bf(warr[w][t] * bf2f(Blds[t * 72 + lane]));

    f32x4 accG[2][2];
    #pragma unroll
    for (int i = 0; i < 2; i++)
        #pragma unroll
        for (int j = 0; j < 2; j++) {
            accG[i][j][0]=0.f; accG[i][j][1]=0.f; accG[i][j][2]=0.f; accG[i][j][3]=0.f;
        }
    #pragma unroll
    for (int ks = 0; ks < 2; ++ks) {
        bf16x8 af[2], bfr[2];
        #pragma unroll
        for (int i = 0; i < 2; i++) {
            af[i]  = *reinterpret_cast<const bf16x8*>(&Clds[(16*i + lrow) * 72 + ks*32 + kq*8]);
            bfr[i] = *reinterpret_cast<const bf16x8*>(&Blds[(16*i + lrow) * 72 + ks*32 + kq*8]);
        }
        #pragma unroll
        for (int i = 0; i < 2; i++)
            #pragma unroll
            for (int j = 0; j < 2; j++)
                accG[i][j] = __builtin_amdgcn_mfma_f32_16x16x32_bf16(af[i], bfr[j], accG[i][j], 0, 0, 0);
    }

    float ctp0 = cuml[w][lrow],      dtp0 = dtl[w][lrow];
    float ctp1 = cuml[w][16 + lrow], dtp1 = dtl[w][16 + lrow];
    #pragma unroll
    for (int i = 0; i < 2; i++)
        #pragma unroll
        for (int r = 0; r < 4; r++) {
            int t = 16*i + kq*4 + r;
            float ct = cuml[w][t];
            #pragma unroll
            for (int j = 0; j < 2; j++) {
                int tp = 16*j + lrow;
                float ctp = j ? ctp1 : ctp0;
                float dtp = j ? dtp1 : dtp0;
                float g = accG[i][j][r];
                float wv = (tp <= t) ? __expf(Ah * (ct - ctp)) * dtp * g : 0.f;
                Wlds[w][t * 40 + tp] = f2bf(wv);
            }
        }
    __syncthreads();

    bf16x8 xf[4];
    #pragma unroll
    for (int j = 0; j < 4; j++)
        xf[j] = *reinterpret_cast<const bf16x8*>(&Xt[w][(16*j + lrow) * 40 + kq*8]);
    f32x4 accY[2][4];
    #pragma unroll
    for (int i = 0; i < 2; i++) {
        bf16x8 wf = *reinterpret_cast<const bf16x8*>(&Wlds[w][(16*i + lrow) * 40 + kq*8]);
        #pragma unroll
        for (int j = 0; j < 4; j++) {
            accY[i][j][0]=0.f; accY[i][j][1]=0.f; accY[i][j][2]=0.f; accY[i][j][3]=0.f;
            accY[i][j] = __builtin_amdgcn_mfma_f32_16x16x32_bf16(wf, xf[j], accY[i][j], 0, 0, 0);
        }
    }

    f32x4 accS[4][4];
    #pragma unroll
    for (int j = 0; j < 4; j++) {
        bf16x8 bb = *reinterpret_cast<const bf16x8*>(&Bht[w][(16*j + lrow) * 40 + kq*8]);
        #pragma unroll
        for (int i = 0; i < 4; i++) {
            accS[i][j][0]=0.f; accS[i][j][1]=0.f; accS[i][j][2]=0.f; accS[i][j][3]=0.f;
            accS[i][j] = __builtin_amdgcn_mfma_f32_16x16x32_bf16(xf[i], bb, accS[i][j], 0, 0, 0);
        }
    }

    u16* yb = yp0 + ((size_t)b * LL + (size_t)c * CHUNK) * DINNER + h * HEADDIM;
    #pragma unroll
    for (int i = 0; i < 2; i++)
        #pragma unroll
        for (int r = 0; r < 4; r++) {
            int t = 16*i + kq*4 + r;
            #pragma unroll
            for (int j = 0; j < 4; j++)
                yb[(size_t)t * DINNER + 16*j + lrow] = f2bf(accY[i][j][r]);
        }
    #pragma unroll
    for (int i = 0; i < 4; i++)
        #pragma unroll
        for (int r = 0; r < 4; r++) {
            int p = 16*i + kq*4 + r;
            #pragma unroll
            for (int j = 0; j < 4; j++)
                Sc[((size_t)(bh * 4 + j) * NCHUNK + c) * 1024 + p * 16 + lrow] = f2bf(accS[i][j][r]);
        }
    if (lane == 0) Ptot[bh * NCHUNK + c] = __expf(Ah * cumTot);
}

// ----------------------- chunked SSM scan: combine -------------------------
// R16: 4 waves + vectorized. R17: Ptot in regs, full unroll. R19: Sc/Sinit
// bf16 (carry stays f32 in-register; stored Sinit rounding is IDENTICAL to
// the f2bf that scan_mfma2 previously applied at read time).
__global__ __launch_bounds__(256) void scan_combine(
    const u16* __restrict__ Sc, const float* __restrict__ Ptot,
    u16* __restrict__ Sinit)
{
    int blk = blockIdx.x;             // 256 = bh*4 + n-quarter
    int bh = blk >> 2;
    int tid = threadIdx.x;
    int p = tid >> 2;                 // 0..63
    int ncol = (tid & 3) * 4;         // 4 elems of the 16-wide n slice
    float Pv[NCHUNK];
    #pragma unroll
    for (int c = 0; c < NCHUNK; ++c) Pv[c] = Ptot[bh * NCHUNK + c];
    float4 carry; carry.x = 0.f; carry.y = 0.f; carry.z = 0.f; carry.w = 0.f;
    size_t rowbase = (size_t)blk * NCHUNK * 1024 + p * 16 + ncol;
    #pragma unroll
    for (int c = 0; c < NCHUNK; ++c) {
        size_t row = rowbase + (size_t)c * 1024;
        ushort4 o;
        o.x = f2bf(carry.x); o.y = f2bf(carry.y);
        o.z = f2bf(carry.z); o.w = f2bf(carry.w);
        *reinterpret_cast<ushort4*>(Sinit + row) = o;
        ushort4 si = *reinterpret_cast<const ushort4*>(Sc + row);
        carry.x = fmaf(carry.x, Pv[c], bf2f(si.x));
        carry.y = fmaf(carry.y, Pv[c], bf2f(si.y));
        carry.z = fmaf(carry.z, Pv[c], bf2f(si.z));
        carry.w = fmaf(carry.w, Pv[c], bf2f(si.w));
    }
}

// -------------------- MFMA chunk scan: pass 2 ------------------------------
// R17: 4 heads/block, shared raw-C staging, dacl in f32 epilogue.
// R19: Sinit is bf16 -> the B-fragment is ONE b128 load (was 2x float4 +
// 8x f2bf); yp1 stored bf16.
__global__ __launch_bounds__(256) void scan_mfma2(
    const float* __restrict__ convout, const float* __restrict__ dtbuf,
    const float* __restrict__ A_log, const u16* __restrict__ Sinit,
    u16* __restrict__ yp1)
{
    __shared__ u16 Clds2[32 * 72];       // raw C bf16 [t][n] (shared)
    __shared__ float dtl[4][32], dacl[4][32];
    int blk = blockIdx.x;                // 512 = (b*4 + hq)*32 + c
    int c   = blk & 31;
    int bg  = blk >> 5;
    int b   = bg >> 2;
    int hq  = bg & 3;
    int tid = threadIdx.x;
    int w    = tid >> 6;                 // wave = head within quad
    int lane = tid & 63;
    int h   = hq * 4 + w;
    int bh  = b * 16 + h;
    int lrow = lane & 15, kq = lane >> 4;
    size_t base = ((size_t)b * LL + (size_t)c * CHUNK) * CONVDIM;
    float Ah = -__expf(A_log[h]);

    if (lane < 32)
        dtl[w][lane] = dtbuf[((size_t)b * LL + (size_t)c * CHUNK + lane) * NHEADS + h];
    // shared raw-C staging: 32 t x 16 float4 = 512 float4 over 256 thr, 2 it
    #pragma unroll
    for (int it = 0; it < 2; ++it) {
        int idx = it * 256 + tid;
        int t = idx >> 4, q = idx & 15;
        float4 v = *reinterpret_cast<const float4*>(
            &convout[base + (size_t)t * CONVDIM + DINNER + DSTATE + q * 4]);
        ushort4 r4;
        r4.x = f2bf(v.x); r4.y = f2bf(v.y);
        r4.z = f2bf(v.z); r4.w = f2bf(v.w);
        *reinterpret_cast<ushort4*>(&Clds2[t * 72 + q * 4]) = r4;
    }
    __syncthreads();

    float s_inc = 0.f;
    #pragma unroll
    for (int j = 0; j < 32; ++j) {
        float v = dtl[w][j];
        if (j <= lane) s_inc += v;
    }
    if (lane < 32) dacl[w][lane] = __expf(Ah * s_inc);

    f32x4 accI[2][4];
    #pragma unroll
    for (int i = 0; i < 2; i++)
        #pragma unroll
        for (int j = 0; j < 4; j++) {
            accI[i][j][0]=0.f; accI[i][j][1]=0.f; accI[i][j][2]=0.f; accI[i][j][3]=0.f;
        }
    #pragma unroll
    for (int ks = 0; ks < 2; ++ks) {
        bf16x8 ca[2];
        #pragma unroll
        for (int i = 0; i < 2; i++)
            ca[i] = *reinterpret_cast<const bf16x8*>(&Clds2[(16*i + lrow) * 72 + ks*32 + kq*8]);
        int nq = ks * 2 + (kq >> 1);
        int off = (kq & 1) * 8;
        #pragma unroll
        for (int j = 0; j < 4; j++) {
            int p = 16*j + lrow;
            const u16* sp = Sinit + ((size_t)(bh * 4 + nq) * NCHUNK + c) * 1024 + p * 16 + off;
            bf16x8 fr = *reinterpret_cast<const bf16x8*>(sp);
            #pragma unroll
            for (int i = 0; i < 2; i++)
                accI[i][j] = __builtin_amdgcn_mfma_f32_16x16x32_bf16(ca[i], fr, accI[i][j], 0, 0, 0);
        }
    }

    u16* yb = yp1 + ((size_t)b * LL + (size_t)c * CHUNK) * DINNER + h * HEADDIM;
    #pragma unroll
    for (int i = 0; i < 2; i++)
        #pragma unroll
        for (int r = 0; r < 4; r++) {
            int t = 16*i + kq*4 + r;
            float sct = dacl[w][t];
            #pragma unroll
            for (int j = 0; j < 4; j++)
                yb[(size_t)t * DINNER + 16*j + lrow] = f2bf(accI[i][j][r] * sct);
        }
}

// ------------- gated RMSNorm (yp0+yp1+xD)*silu(z), bf16 out ----------------
// R19: yp0/yp1 are bf16 inputs.
__global__ __launch_bounds__(256) void gated_rms_kernel(
    const u16* __restrict__ yp0, const u16* __restrict__ yp1,
    const float* __restrict__ convout, const float* __restrict__ zx,
    const float* __restrict__ Dv, const float* __restrict__ norm_w,
    u16* __restrict__ gout)
{
    int bl = blockIdx.x;
    int c = threadIdx.x * 4;
    ushort4 y0 = *reinterpret_cast<const ushort4*>(yp0 + (size_t)bl * DINNER + c);
    ushort4 y1 = *reinterpret_cast<const ushort4*>(yp1 + (size_t)bl * DINNER + c);
    float4 xv = *reinterpret_cast<const float4*>(convout + (size_t)bl * CONVDIM + c);
    float4 zv = *reinterpret_cast<const float4*>(zx + (size_t)bl * NPROJ_PAD + c);
    float Dh = Dv[c >> 6];
    float g0 = (bf2f(y0.x) + bf2f(y1.x) + xv.x * Dh) * silu_f(zv.x);
    float g1 = (bf2f(y0.y) + bf2f(y1.y) + xv.y * Dh) * silu_f(zv.y);
    float g2 = (bf2f(y0.z) + bf2f(y1.z) + xv.z * Dh) * silu_f(zv.z);
    float g3 = (bf2f(y0.w) + bf2f(y1.w) + xv.w * Dh) * silu_f(zv.w);
    float tot = block_sum(g0 * g0 + g1 * g1 + g2 * g2 + g3 * g3);
    float sc = rsqrtf(tot * (1.f / DINNER) + 1e-5f);
    float4 nw = *reinterpret_cast<const float4*>(norm_w + c);
    ushort4 o;
    o.x = f2bf(g0 * sc * nw.x); o.y = f2bf(g1 * sc * nw.y);
    o.z = f2bf(g2 * sc * nw.z); o.w = f2bf(g3 * sc * nw.w);
    *reinterpret_cast<ushort4*>(gout + (size_t)bl * DINNER + c) = o;
}

// ---- residual + 4 split-K partials + RMSNorm (no weight), f32 out ---------
__global__ void residual_rms_sk_kernel(
    const float* __restrict__ a, const float* __restrict__ pbuf,
    float* __restrict__ outf, int ncols, int rows)
{
    int row = blockIdx.x;
    int c = threadIdx.x * 4;
    size_t slice = (size_t)rows * ncols;
    size_t off = (size_t)row * ncols + c;
    float4 va = *reinterpret_cast<const float4*>(a + off);
    float4 p0 = *reinterpret_cast<const float4*>(pbuf + off);
    float4 p1 = *reinterpret_cast<const float4*>(pbuf + slice + off);
    float4 p2 = *reinterpret_cast<const float4*>(pbuf + 2 * slice + off);
    float4 p3 = *reinterpret_cast<const float4*>(pbuf + 3 * slice + off);
    float v0 = va.x + ((p0.x + p1.x) + (p2.x + p3.x));
    float v1 = va.y + ((p0.y + p1.y) + (p2.y + p3.y));
    float v2 = va.z + ((p0.z + p1.z) + (p2.z + p3.z));
    float v3 = va.w + ((p0.w + p1.w) + (p2.w + p3.w));
    float tot = block_sum(v0 * v0 + v1 * v1 + v2 * v2 + v3 * v3);
    float sc = rsqrtf(tot / (float)ncols + 1e-5f);
    float4 o; o.x = v0 * sc; o.y = v1 * sc; o.z = v2 * sc; o.w = v3 * sc;
    *reinterpret_cast<float4*>(outf + off) = o;
}

// ------------- transpose per batch: in (R,C) -> out (C,R), dual write ------
__global__ __launch_bounds__(256) void transpose_dual_kernel(
    const float* __restrict__ in, u16* __restrict__ outb,
    float* __restrict__ outf, int R, int C)
{
    __shared__ float tile[32][33];
    int b = blockIdx.z;
    int c0 = blockIdx.x * 32, r0 = blockIdx.y * 32;
    const float* ip = in + (size_t)b * R * C;
    for (int i = threadIdx.y; i < 32; i += 8)
        tile[i][threadIdx.x] = ip[(size_t)(r0 + i) * C + c0 + threadIdx.x];
    __syncthreads();
    size_t ob = (size_t)b * R * C;
    for (int i = threadIdx.y; i < 32; i += 8) {
        float v = tile[threadIdx.x][i];
        size_t oi = ob + (size_t)(c0 + i) * R + r0 + threadIdx.x;
        outf[oi] = v;
        outb[oi] = f2bf(v);
    }
}

// ---------------------------------------------------------------------------
extern "C" void kernel_launch(void* const* d_in, const int* in_sizes, int n_in,
                              void* d_out, int out_size, void* d_ws, size_t ws_size,
                              hipStream_t stream)
{
    const float* hid      = (const float*)d_in[0];
    const float* in_proj  = (const float*)d_in[1];
    const float* conv_w   = (const float*)d_in[2];
    const float* conv_b   = (const float*)d_in[3];
    const float* dt_bias  = (const float*)d_in[4];
    const float* A_log    = (const float*)d_in[5];
    const float* Dv       = (const float*)d_in[6];
    const float* norm_w   = (const float*)d_in[7];
    const float* out_proj = (const float*)d_in[8];
    const float* gu_t     = (const float*)d_in[9];
    const float* down_t   = (const float*)d_in[10];
    const float* gu_m     = (const float*)d_in[11];
    const float* down_m   = (const float*)d_in[12];
    float* outp = (float*)d_out;

    char* ws = (char*)d_ws;
    u16* bf        = (u16*)ws;
    u16* hid_bf    = bf;
    u16* w_inproj  = bf + HID_E;
    u16* w_outproj = w_inproj + INPROJ_P_E;
    u16* w_gut     = w_outproj + OUTPROJ_E;
    u16* w_downt   = w_gut + GUT_E;
    u16* w_gum     = w_downt + DOWNT_E;
    u16* w_downm   = w_gum + GUM_E;
    size_t o = (size_t)(CONV_TOT_E * 2);
    auto alloc = [&](size_t bytes) { size_t r = o; o = (o + bytes + 255) & ~(size_t)255; return r; };
    size_t dt_off  = alloc(4096 * 16 * 4);
    size_t g_off   = alloc((size_t)4096 * 1024 * 2);
    size_t h1_off  = alloc((size_t)4096 * 512 * 4);
    size_t Pt_off  = alloc(2048 * 4);
    // ---- MLP region (live step 8+); Sc/Sinit OVERLAY it (live steps 4-5).
    size_t xtb_off = alloc((size_t)2048 * 1024 * 2);
    size_t xtf_off = alloc((size_t)2048 * 1024 * 4);
    size_t act1_off= alloc((size_t)2048 * 2816 * 2);
    size_t x2_off  = alloc((size_t)2048 * 1024 * 4);
    size_t h2b_off = alloc((size_t)4096 * 512 * 2);
    size_t h2f_off = alloc((size_t)4096 * 512 * 4);
    size_t act2_off= alloc((size_t)4096 * 1536 * 2);
    size_t pad_off = alloc((size_t)10 * 1024 * 1024);
    size_t Sc_off  = xtb_off;                          // bf16: 16.78 MB
    size_t Si_off  = xtb_off + (size_t)8192 * 1024 * 4;// bf16: 16.78 MB
    (void)pad_off;
    size_t R_off   = o;
    size_t zx_off  = R_off;
    size_t cv_off  = zx_off + (size_t)4096 * NPROJ_PAD * 4;
    size_t y_off   = cv_off + (size_t)4096 * CONVDIM * 4;
    size_t sk_off  = R_off;

    float* zx      = (float*)(ws + zx_off);
    float* convout = (float*)(ws + cv_off);
    u16*   ybuf    = (u16*)(ws + y_off);             // yp0 (bf16, R19)
    float* dtbuf   = (float*)(ws + dt_off);
    u16*   g_bf    = (u16*)(ws + g_off);
    float* h1      = (float*)(ws + h1_off);
    u16*   xt_bf   = (u16*)(ws + xtb_off);
    float* xt_f    = (float*)(ws + xtf_off);
    u16*   act1    = (u16*)(ws + act1_off);
    float* x2      = (float*)(ws + x2_off);
    u16*   h2_bf   = (u16*)(ws + h2b_off);
    float* h2_f    = (float*)(ws + h2f_off);
    u16*   act2    = (u16*)(ws + act2_off);
    float* skbuf   = (float*)(ws + sk_off);
    u16*   Sc      = (u16*)(ws + Sc_off);            // bf16; yp1 after combine
    u16*   Sinit   = (u16*)(ws + Si_off);            // bf16
    float* Ptot    = (float*)(ws + Pt_off);

    // 1) convert weights + hidden to bf16
    convert_all_kernel<<<14464, 256, 0, stream>>>(
        hid, in_proj, out_proj, gu_t, down_t, gu_m, down_m, bf);

    // 2) zxbcdt = hidden @ in_proj^T
    gemm_bt<<<dim3(NPROJ_PAD / 128, 4096 / 128), 256, 0, stream>>>(
        hid_bf, w_inproj, zx, 4096, NPROJ_PAD, 512);

    // 3) conv + dt
    conv_dt_kernel<<<18688, 256, 0, stream>>>(zx, conv_w, conv_b, dt_bias, convout, dtbuf);

    // 4) MFMA chunk scan (R19: all state bf16)
    scan_mfma1<<<512, 256, 0, stream>>>(convout, dtbuf, A_log, Sc, Ptot, ybuf);
    scan_combine<<<256, 256, 0, stream>>>(Sc, Ptot, Sinit);
    scan_mfma2<<<512, 256, 0, stream>>>(convout, dtbuf, A_log, Sinit, Sc);

    // 5) gated RMSNorm -> bf16
    gated_rms_kernel<<<4096, 256, 0, stream>>>(ybuf, Sc, convout, zx, Dv, norm_w, g_bf);

    // 6) out_proj GEMM, split-K x4 -> partials in skbuf
    gemm_bt_sk<<<dim3(512 / 128, 4096 / 128, 4), 256, 0, stream>>>(
        g_bf, w_outproj, skbuf, 4096, 512, 1024, 256);

    // 7) h1 = rms(hidden + sum partials)
    residual_rms_sk_kernel<<<4096, 128, 0, stream>>>(hid, skbuf, h1, 512, 4096);

    // 8) transpose (B,1024,512) -> (B,512,1024)
    transpose_dual_kernel<<<dim3(16, 32, 4), dim3(32, 8), 0, stream>>>(h1, xt_bf, xt_f, 1024, 512);

    // 9) token MLP fused: act1 = swiglu(xt @ gu_t^T)  (704 blocks, 128x64)
    gemm_swiglu<<<dim3(INTER_T / 64, 2048 / 128), 256, 0, stream>>>(
        xt_bf, w_gut, act1, 2048, INTER_T, 1024);

    // 10) down_t GEMM, split-K x4 -> partials in skbuf
    gemm_bt_sk<<<dim3(1024 / 128, 2048 / 128, 4), 256, 0, stream>>>(
        act1, w_downt, skbuf, 2048, 1024, 2816, 704);

    // 11) x2 = rms(xt_f + sum partials)
    residual_rms_sk_kernel<<<2048, 256, 0, stream>>>(xt_f, skbuf, x2, 1024, 2048);

    // 12) transpose back (B,512,1024) -> (B,1024,512)
    transpose_dual_kernel<<<dim3(32, 16, 4), dim3(32, 8), 0, stream>>>(x2, h2_bf, h2_f, 512, 1024);

    // 13) channel MLP fused: act2 = swiglu(h2 @ gu_m^T)  (768 blocks, 128x64)
    gemm_swiglu<<<dim3(INTER_M / 64, 4096 / 128), 256, 0, stream>>>(
        h2_bf, w_gum, act2, 4096, INTER_M, 512);

    // 14) down_m GEMM, split-K x4 -> partials in skbuf
    gemm_bt_sk<<<dim3(512 / 128, 4096 / 128, 4), 256, 0, stream>>>(
        act2, w_downm, skbuf, 4096, 512, 1536, 384);

    // 15) out = rms(h2_f + sum partials)
    residual_rms_sk_kernel<<<4096, 128, 0, stream>>>(h2_f, skbuf, outp, 512, 4096);
}

// Round 5
// 319.634 us; speedup vs baseline: 1.0812x; 1.0269x over previous
//
#include <hip/hip_runtime.h>

// ---------------------------------------------------------------------------
// Mamba2 hybrid block. GEMMs: bf16 MFMA 16x16x32, f32 accumulate, m97-style
// global_load_lds(16B) staging, BK=64 (R15: single-buffered K-loop is ~53%
// barrier drain at 2-3 blocks/CU; 64-wide K tiles halve barrier count.
// 3-bit XOR chunk swizzle keeps frag reads 2-way/free). Small-N GEMMs use
// split-K x4 into SEPARATE partial buffers; partials summed in the
// downstream residual_rms kernel. MLP gu-GEMMs fuse SwiGLU (128x64 act tile;
// R14: acc must stay <=16 f32x4 or VGPR cliff). Scan: MFMA chunked.
// R16: scan_mfma1 4 heads/block shared B/C staging (-14.1 us, 355.5->341.4).
// R17/R18: scan_mfma2 4 heads/block + scan_combine unroll: NEUTRAL.
// R19: bf16 scan state (Sc/Sinit/yp0/yp1): -17.4 us (345.6->328.2, absmax
// unchanged 0.03125) — ~100 MB HBM round-trip removed as predicted.
// R20: bf16 split-K partials. The 3 SK GEMMs wrote 4x f32 partial slices
// (201 MB total round-trip with the residual_rms re-read). Partials are
// K/4-length bf16-input dot products; bf16-rounding them (2^-9 rel) before
// the f32 re-sum is far below the existing MFMA noise floor. Saves ~100 MB.
// ---------------------------------------------------------------------------

#define BB 4
#define LL 1024
#define DMODEL 512
#define DINNER 1024
#define NHEADS 16
#define HEADDIM 64
#define DSTATE 64
#define CONVDIM 1152        // DINNER + 2*DSTATE
#define NPROJ 2192          // D_IN_PROJ
#define NPROJ_PAD 2304      // padded to multiple of 128
#define INTER_T 2816
#define INTER_M 1536
#define NCHUNK 32
#define CHUNK 32

typedef __bf16 bf16x8 __attribute__((ext_vector_type(8)));
typedef float  f32x4  __attribute__((ext_vector_type(4)));
typedef unsigned short u16;
typedef unsigned int   u32;

__device__ __forceinline__ u16 f2bf(float x) {
    union { float f; u32 u; } v; v.f = x;
    u32 u = v.u;
    return (u16)((u + 0x7fffu + ((u >> 16) & 1u)) >> 16);
}
__device__ __forceinline__ float silu_f(float x) {
    return x / (1.f + __expf(-x));
}
__device__ __forceinline__ float bf2f(u16 w) {
    union { u32 u; float f; } a; a.u = ((u32)w) << 16; return a.f;
}

// C-store helpers: f32 passthrough or bf16 round (split-K partials, R20)
__device__ __forceinline__ void cstore(float* p, float v) { *p = v; }
__device__ __forceinline__ void cstore(u16*   p, float v) { *p = f2bf(v); }

// async global->LDS, 16B per lane; LDS dest is wave-uniform base + lane*16
__device__ __forceinline__ void gld_lds16(const u16* g, u16* l) {
    __builtin_amdgcn_global_load_lds(
        (const __attribute__((address_space(1))) unsigned int*)g,
        (__attribute__((address_space(3))) unsigned int*)l, 16, 0, 0);
}

// --------------------------- block-wide sum --------------------------------
__device__ __forceinline__ float block_sum(float v) {
    #pragma unroll
    for (int off = 32; off > 0; off >>= 1) v += __shfl_xor(v, off, 64);
    __shared__ float red[4];
    int w = threadIdx.x >> 6;
    int nwv = blockDim.x >> 6;
    if ((threadIdx.x & 63) == 0) red[w] = v;
    __syncthreads();
    float tot = red[0];
    for (int i = 1; i < nwv; i++) tot += red[i];
    return tot;
}

// --------------------- f32 -> bf16 convert (all weights + hidden) ----------
#define HID_E      2097152LL   // 4096*512
#define INPROJ_P_E 1179648LL   // 2304*512
#define INPROJ_S_E 1122304LL   // 2192*512
#define OUTPROJ_E   524288LL   // 512*1024
#define GUT_E      5767168LL   // 5632*1024
#define DOWNT_E    2883584LL   // 1024*2816
#define GUM_E      1572864LL   // 3072*512
#define DOWNM_E     786432LL   // 512*1536
#define CONV_TOT_E 14811136LL

__global__ __launch_bounds__(256) void convert_all_kernel(
    const float* __restrict__ s_hid, const float* __restrict__ s_inproj,
    const float* __restrict__ s_outproj, const float* __restrict__ s_gut,
    const float* __restrict__ s_downt, const float* __restrict__ s_gum,
    const float* __restrict__ s_downm, u16* __restrict__ dst)
{
    long long idx = (long long)blockIdx.x * 256 + threadIdx.x;
    long long e = idx * 4;
    if (e >= CONV_TOT_E) return;
    const float* src; long long off, nsrc;
    long long c0 = HID_E;
    long long c1 = c0 + INPROJ_P_E;
    long long c2 = c1 + OUTPROJ_E;
    long long c3 = c2 + GUT_E;
    long long c4 = c3 + DOWNT_E;
    long long c5 = c4 + GUM_E;
    if      (e < c0) { src = s_hid;     off = e;      nsrc = HID_E; }
    else if (e < c1) { src = s_inproj;  off = e - c0; nsrc = INPROJ_S_E; }
    else if (e < c2) { src = s_outproj; off = e - c1; nsrc = OUTPROJ_E; }
    else if (e < c3) { src = s_gut;     off = e - c2; nsrc = GUT_E; }
    else if (e < c4) { src = s_downt;   off = e - c3; nsrc = DOWNT_E; }
    else if (e < c5) { src = s_gum;     off = e - c4; nsrc = GUM_E; }
    else             { src = s_downm;   off = e - c5; nsrc = DOWNM_E; }
    ushort4 r;
    if (off < nsrc) {
        float4 v = *reinterpret_cast<const float4*>(src + off);
        r.x = f2bf(v.x); r.y = f2bf(v.y); r.z = f2bf(v.z); r.w = f2bf(v.w);
    } else {
        r.x = 0; r.y = 0; r.z = 0; r.w = 0;
    }
    *reinterpret_cast<ushort4*>(dst + e) = r;
}

// ----------------------------- bf16 MFMA GEMM (BK=64) ----------------------
// C[M,N] = A[M,K] * W[N,K]^T. 128x128 tile, 4 waves of 64x64 (4x4 MFMAs).
// LDS rows are 64 u16 (128 B); staging: 8 rows x 8 chunks of 16B per inst,
// global chunk = cL ^ rL (3-bit XOR). Frag chunk = (ks*4+kq) ^ (lrow&7).
// R20: CT templates the C dtype — f32 for full GEMMs, bf16 for SK partials.
template<bool SK, typename CT>
__device__ __forceinline__ void gemm_bt_body(
    const u16* __restrict__ A, const u16* __restrict__ W,
    CT* __restrict__ C, int M, int N, int K, int kLen)
{
    __shared__ u16 As[128 * 64];   // 16 KB
    __shared__ u16 Bs[128 * 64];   // 16 KB
    int tid = threadIdx.x;
    int m0 = blockIdx.y * 128, n0 = blockIdx.x * 128;
    int kBase = SK ? blockIdx.z * kLen : 0;
    CT* Cw = SK ? C + (size_t)blockIdx.z * M * N : C;
    int wave = tid >> 6, lane = tid & 63;
    int wm = (wave >> 1) * 64, wn = (wave & 1) * 64;
    int lrow = lane & 15;
    int kq = lane >> 4;
    int kx = lrow & 7;

    int rL = lane >> 3, cL = lane & 7;
    int cG = cL ^ rL;
    const u16* gA[4]; const u16* gB[4];
    u16 *lA[4], *lB[4];
    #pragma unroll
    for (int i = 0; i < 4; i++) {
        int r = wave * 32 + i * 8;
        gA[i] = A + (size_t)(m0 + r + rL) * K + kBase + cG * 8;
        gB[i] = W + (size_t)(n0 + r + rL) * K + kBase + cG * 8;
        lA[i] = &As[r * 64];
        lB[i] = &Bs[r * 64];
    }

    f32x4 acc[4][4];
    #pragma unroll
    for (int i = 0; i < 4; i++)
        #pragma unroll
        for (int j = 0; j < 4; j++) {
            acc[i][j][0] = 0.f; acc[i][j][1] = 0.f;
            acc[i][j][2] = 0.f; acc[i][j][3] = 0.f;
        }

    for (int kt = 0; kt < kLen; kt += 64) {
        __syncthreads();
        #pragma unroll
        for (int i = 0; i < 4; i++) {
            gld_lds16(gA[i] + kt, lA[i]);
            gld_lds16(gB[i] + kt, lB[i]);
        }
        __syncthreads();
        #pragma unroll
        for (int ks = 0; ks < 2; ks++) {
            int ko = (((ks * 4 + kq) ^ kx) * 8);
            bf16x8 af[4], bfr[4];
            #pragma unroll
            for (int i = 0; i < 4; i++) {
                af[i]  = *reinterpret_cast<const bf16x8*>(&As[(wm + i * 16 + lrow) * 64 + ko]);
                bfr[i] = *reinterpret_cast<const bf16x8*>(&Bs[(wn + i * 16 + lrow) * 64 + ko]);
            }
            #pragma unroll
            for (int i = 0; i < 4; i++)
                #pragma unroll
                for (int j = 0; j < 4; j++)
                    acc[i][j] = __builtin_amdgcn_mfma_f32_16x16x32_bf16(af[i], bfr[j], acc[i][j], 0, 0, 0);
        }
    }

    // C/D layout: col = lane&15, row = (lane>>4)*4 + reg
    int rbase = m0 + wm + kq * 4;
    int cbase = n0 + wn + lrow;
    #pragma unroll
    for (int i = 0; i < 4; i++)
        #pragma unroll
        for (int j = 0; j < 4; j++)
            #pragma unroll
            for (int r = 0; r < 4; r++)
                cstore(&Cw[(size_t)(rbase + i * 16 + r) * N + cbase + j * 16], acc[i][j][r]);
}

__global__ __launch_bounds__(256) void gemm_bt(
    const u16* __restrict__ A, const u16* __restrict__ W,
    float* __restrict__ C, int M, int N, int K)
{
    gemm_bt_body<false, float>(A, W, C, M, N, K, K);
}

__global__ __launch_bounds__(256) void gemm_bt_sk(
    const u16* __restrict__ A, const u16* __restrict__ W,
    u16* __restrict__ C, int M, int N, int K, int kLen)
{
    gemm_bt_body<true, u16>(A, W, C, M, N, K, kLen);
}

// --------------- fused gate/up GEMM + SwiGLU (128x64, BK=64) ---------------
// act[M,inter] = silu(A·Wg^T) * (A·Wu^T). Bs rows 0..63 = gate, 64..127 = up.
__global__ __launch_bounds__(256) void gemm_swiglu(
    const u16* __restrict__ A, const u16* __restrict__ W,
    u16* __restrict__ act, int M, int inter, int K)
{
    __shared__ u16 As[128 * 64];   // 16 KB
    __shared__ u16 Bs[128 * 64];   // 16 KB
    int tid = threadIdx.x;
    int m0 = blockIdx.y * 128, n0 = blockIdx.x * 64;
    int wave = tid >> 6, lane = tid & 63;
    int wm = (wave >> 1) * 64, wn = (wave & 1) * 32;
    int lrow = lane & 15;
    int kq = lane >> 4;
    int kx = lrow & 7;

    int rL = lane >> 3, cL = lane & 7;
    int cG = cL ^ rL;
    const u16* gA[4]; const u16* gB[4];
    u16 *lA[4], *lB[4];
    #pragma unroll
    for (int i = 0; i < 4; i++) {
        int r = wave * 32 + i * 8;
        gA[i] = A + (size_t)(m0 + r + rL) * K + cG * 8;
        lA[i] = &As[r * 64];
        int rB = r;   // combined index: 0..63 gate, 64..127 up (per wave 32)
        int grow = (rB < 64) ? (n0 + rB + rL)
                             : (inter + n0 + rB - 64 + rL);
        gB[i] = W + (size_t)grow * K + cG * 8;
        lB[i] = &Bs[rB * 64];
    }

    f32x4 accg[4][2], accu[4][2];
    #pragma unroll
    for (int i = 0; i < 4; i++)
        #pragma unroll
        for (int j = 0; j < 2; j++) {
            accg[i][j][0]=0.f; accg[i][j][1]=0.f; accg[i][j][2]=0.f; accg[i][j][3]=0.f;
            accu[i][j][0]=0.f; accu[i][j][1]=0.f; accu[i][j][2]=0.f; accu[i][j][3]=0.f;
        }

    for (int kt = 0; kt < K; kt += 64) {
        __syncthreads();
        #pragma unroll
        for (int i = 0; i < 4; i++) {
            gld_lds16(gA[i] + kt, lA[i]);
            gld_lds16(gB[i] + kt, lB[i]);
        }
        __syncthreads();
        #pragma unroll
        for (int ks = 0; ks < 2; ks++) {
            int ko = (((ks * 4 + kq) ^ kx) * 8);
            bf16x8 af[4], bg[2], bu[2];
            #pragma unroll
            for (int i = 0; i < 4; i++)
                af[i] = *reinterpret_cast<const bf16x8*>(&As[(wm + i * 16 + lrow) * 64 + ko]);
            #pragma unroll
            for (int j = 0; j < 2; j++) {
                bg[j] = *reinterpret_cast<const bf16x8*>(&Bs[(wn + j * 16 + lrow) * 64 + ko]);
                bu[j] = *reinterpret_cast<const bf16x8*>(&Bs[(64 + wn + j * 16 + lrow) * 64 + ko]);
            }
            #pragma unroll
            for (int i = 0; i < 4; i++)
                #pragma unroll
                for (int j = 0; j < 2; j++) {
                    accg[i][j] = __builtin_amdgcn_mfma_f32_16x16x32_bf16(af[i], bg[j], accg[i][j], 0, 0, 0);
                    accu[i][j] = __builtin_amdgcn_mfma_f32_16x16x32_bf16(af[i], bu[j], accu[i][j], 0, 0, 0);
                }
        }
    }

    int rbase = m0 + wm + kq * 4;
    int cbase = n0 + wn + lrow;
    #pragma unroll
    for (int i = 0; i < 4; i++)
        #pragma unroll
        for (int j = 0; j < 2; j++)
            #pragma unroll
            for (int r = 0; r < 4; r++) {
                float g = accg[i][j][r], u = accu[i][j][r];
                act[(size_t)(rbase + i * 16 + r) * inter + cbase + j * 16] =
                    f2bf(silu_f(g) * u);
            }
}

// ----------------- conv (depthwise, causal, width 4) + dt ------------------
__global__ __launch_bounds__(256) void conv_dt_kernel(
    const float* __restrict__ zx, const float* __restrict__ conv_w,
    const float* __restrict__ conv_b, const float* __restrict__ dt_bias,
    float* __restrict__ convout, float* __restrict__ dtbuf)
{
    int idx = blockIdx.x * 256 + threadIdx.x;   // over 4096*1168
    int bl = idx / 1168;
    int c  = idx - bl * 1168;
    int l  = bl & (LL - 1);
    if (c < CONVDIM) {
        const float* col = zx + (size_t)bl * NPROJ_PAD + DINNER + c;
        float acc = conv_b[c];
        #pragma unroll
        for (int i = 0; i < 4; i++) {
            int lt = l - 3 + i;
            float v = (lt >= 0) ? col[(long long)(lt - l) * NPROJ_PAD] : 0.f;
            acc = fmaf(v, conv_w[c * 4 + i], acc);
        }
        convout[(size_t)bl * CONVDIM + c] = silu_f(acc);
    } else {
        int h = c - CONVDIM;
        float v = zx[(size_t)bl * NPROJ_PAD + 2176 + h] + dt_bias[h];
        float sp = (v > 20.f) ? v : log1pf(__expf(v));
        dtbuf[(size_t)bl * NHEADS + h] = sp;
    }
}

// -------------------- MFMA chunk scan: pass 1 ------------------------------
// R16: 4 heads per block (4 waves), shared B/C staging.
// R19: Sc and yp0 outputs are bf16 (halves the scan-state HBM round-trip).
__global__ __launch_bounds__(256) void scan_mfma1(
    const float* __restrict__ convout, const float* __restrict__ dtbuf,
    const float* __restrict__ A_log, u16* __restrict__ Sc,
    float* __restrict__ Ptot, u16* __restrict__ yp0)
{
    __shared__ u16 Blds[32 * 72];        // raw B bf16 [t][n] (shared)
    __shared__ u16 Clds[32 * 72];        // raw C bf16 [t][n] (shared)
    __shared__ u16 Xt[4][64 * 40];       // x^T bf16 [p][t] (per head)
    __shared__ u16 Bht[4][64 * 40];      // (w_t*dt_t*B)^T bf16 [n][t]
    __shared__ u16 Wlds[4][32 * 40];     // W bf16 [t][t']
    __shared__ float dtl[4][32], cuml[4][32], warr[4][32];

    int blk = blockIdx.x;                // 512 = (b*4 + hq)*32 + c
    int c   = blk & 31;
    int bg  = blk >> 5;
    int b   = bg >> 2;
    int hq  = bg & 3;
    int tid = threadIdx.x;
    int w    = tid >> 6;                 // wave = head within quad
    int lane = tid & 63;
    int h   = hq * 4 + w;
    int bh  = b * 16 + h;
    int lrow = lane & 15, kq = lane >> 4;
    size_t base = ((size_t)b * LL + (size_t)c * CHUNK) * CONVDIM;
    float Ah = -__expf(A_log[h]);

    if (lane < 32)
        dtl[w][lane] = dtbuf[((size_t)b * LL + (size_t)c * CHUNK + lane) * NHEADS + h];
    // shared B/C staging: 256 threads cover 32 t x 32 float4 in 4 iters
    #pragma unroll
    for (int it = 0; it < 4; ++it) {
        int idx = it * 256 + tid;
        int t = idx >> 5, q = idx & 31;
        float4 v = *reinterpret_cast<const float4*>(
            &convout[base + (size_t)t * CONVDIM + DINNER + q * 4]);
        ushort4 r4; r4.x = f2bf(v.x); r4.y = f2bf(v.y); r4.z = f2bf(v.z); r4.w = f2bf(v.w);
        if (q < 16) *reinterpret_cast<ushort4*>(&Blds[t * 72 + q * 4]) = r4;
        else        *reinterpret_cast<ushort4*>(&Clds[t * 72 + (q - 16) * 4]) = r4;
    }
    #pragma unroll
    for (int t = 0; t < 32; ++t) {
        float v = convout[base + (size_t)t * CONVDIM + h * HEADDIM + lane];
        Xt[w][lane * 40 + t] = f2bf(v);
    }
    __syncthreads();

    float s_inc = 0.f, s_all = 0.f;
    #pragma unroll
    for (int j = 0; j < 32; ++j) {
        float v = dtl[w][j];
        s_all += v;
        if (j <= lane) s_inc += v;
    }
    if (lane < 32) {
        cuml[w][lane] = s_inc;
        warr[w][lane] = __expf(Ah * (s_all - s_inc)) * dtl[w][lane];
    }
    float cumTot = s_all;
    __syncthreads();

    #pragma unroll
    for (int t = 0; t < 32; ++t)
        Bht[w][lane * 40 + t] = f2bf(warr[w][t] * bf2f(Blds[t * 72 + lane]));

    f32x4 accG[2][2];
    #pragma unroll
    for (int i = 0; i < 2; i++)
        #pragma unroll
        for (int j = 0; j < 2; j++) {
            accG[i][j][0]=0.f; accG[i][j][1]=0.f; accG[i][j][2]=0.f; accG[i][j][3]=0.f;
        }
    #pragma unroll
    for (int ks = 0; ks < 2; ++ks) {
        bf16x8 af[2], bfr[2];
        #pragma unroll
        for (int i = 0; i < 2; i++) {
            af[i]  = *reinterpret_cast<const bf16x8*>(&Clds[(16*i + lrow) * 72 + ks*32 + kq*8]);
            bfr[i] = *reinterpret_cast<const bf16x8*>(&Blds[(16*i + lrow) * 72 + ks*32 + kq*8]);
        }
        #pragma unroll
        for (int i = 0; i < 2; i++)
            #pragma unroll
            for (int j = 0; j < 2; j++)
                accG[i][j] = __builtin_amdgcn_mfma_f32_16x16x32_bf16(af[i], bfr[j], accG[i][j], 0, 0, 0);
    }

    float ctp0 = cuml[w][lrow],      dtp0 = dtl[w][lrow];
    float ctp1 = cuml[w][16 + lrow], dtp1 = dtl[w][16 + lrow];
    #pragma unroll
    for (int i = 0; i < 2; i++)
        #pragma unroll
        for (int r = 0; r < 4; r++) {
            int t = 16*i + kq*4 + r;
            float ct = cuml[w][t];
            #pragma unroll
            for (int j = 0; j < 2; j++) {
                int tp = 16*j + lrow;
                float ctp = j ? ctp1 : ctp0;
                float dtp = j ? dtp1 : dtp0;
                float g = accG[i][j][r];
                float wv = (tp <= t) ? __expf(Ah * (ct - ctp)) * dtp * g : 0.f;
                Wlds[w][t * 40 + tp] = f2bf(wv);
            }
        }
    __syncthreads();

    bf16x8 xf[4];
    #pragma unroll
    for (int j = 0; j < 4; j++)
        xf[j] = *reinterpret_cast<const bf16x8*>(&Xt[w][(16*j + lrow) * 40 + kq*8]);
    f32x4 accY[2][4];
    #pragma unroll
    for (int i = 0; i < 2; i++) {
        bf16x8 wf = *reinterpret_cast<const bf16x8*>(&Wlds[w][(16*i + lrow) * 40 + kq*8]);
        #pragma unroll
        for (int j = 0; j < 4; j++) {
            accY[i][j][0]=0.f; accY[i][j][1]=0.f; accY[i][j][2]=0.f; accY[i][j][3]=0.f;
            accY[i][j] = __builtin_amdgcn_mfma_f32_16x16x32_bf16(wf, xf[j], accY[i][j], 0, 0, 0);
        }
    }

    f32x4 accS[4][4];
    #pragma unroll
    for (int j = 0; j < 4; j++) {
        bf16x8 bb = *reinterpret_cast<const bf16x8*>(&Bht[w][(16*j + lrow) * 40 + kq*8]);
        #pragma unroll
        for (int i = 0; i < 4; i++) {
            accS[i][j][0]=0.f; accS[i][j][1]=0.f; accS[i][j][2]=0.f; accS[i][j][3]=0.f;
            accS[i][j] = __builtin_amdgcn_mfma_f32_16x16x32_bf16(xf[i], bb, accS[i][j], 0, 0, 0);
        }
    }

    u16* yb = yp0 + ((size_t)b * LL + (size_t)c * CHUNK) * DINNER + h * HEADDIM;
    #pragma unroll
    for (int i = 0; i < 2; i++)
        #pragma unroll
        for (int r = 0; r < 4; r++) {
            int t = 16*i + kq*4 + r;
            #pragma unroll
            for (int j = 0; j < 4; j++)
                yb[(size_t)t * DINNER + 16*j + lrow] = f2bf(accY[i][j][r]);
        }
    #pragma unroll
    for (int i = 0; i < 4; i++)
        #pragma unroll
        for (int r = 0; r < 4; r++) {
            int p = 16*i + kq*4 + r;
            #pragma unroll
            for (int j = 0; j < 4; j++)
                Sc[((size_t)(bh * 4 + j) * NCHUNK + c) * 1024 + p * 16 + lrow] = f2bf(accS[i][j][r]);
        }
    if (lane == 0) Ptot[bh * NCHUNK + c] = __expf(Ah * cumTot);
}

// ----------------------- chunked SSM scan: combine -------------------------
// R16: 4 waves + vectorized. R17: Ptot in regs, full unroll. R19: Sc/Sinit
// bf16 (carry stays f32 in-register; stored Sinit rounding is IDENTICAL to
// the f2bf that scan_mfma2 previously applied at read time).
__global__ __launch_bounds__(256) void scan_combine(
    const u16* __restrict__ Sc, const float* __restrict__ Ptot,
    u16* __restrict__ Sinit)
{
    int blk = blockIdx.x;             // 256 = bh*4 + n-quarter
    int bh = blk >> 2;
    int tid = threadIdx.x;
    int p = tid >> 2;                 // 0..63
    int ncol = (tid & 3) * 4;         // 4 elems of the 16-wide n slice
    float Pv[NCHUNK];
    #pragma unroll
    for (int c = 0; c < NCHUNK; ++c) Pv[c] = Ptot[bh * NCHUNK + c];
    float4 carry; carry.x = 0.f; carry.y = 0.f; carry.z = 0.f; carry.w = 0.f;
    size_t rowbase = (size_t)blk * NCHUNK * 1024 + p * 16 + ncol;
    #pragma unroll
    for (int c = 0; c < NCHUNK; ++c) {
        size_t row = rowbase + (size_t)c * 1024;
        ushort4 o;
        o.x = f2bf(carry.x); o.y = f2bf(carry.y);
        o.z = f2bf(carry.z); o.w = f2bf(carry.w);
        *reinterpret_cast<ushort4*>(Sinit + row) = o;
        ushort4 si = *reinterpret_cast<const ushort4*>(Sc + row);
        carry.x = fmaf(carry.x, Pv[c], bf2f(si.x));
        carry.y = fmaf(carry.y, Pv[c], bf2f(si.y));
        carry.z = fmaf(carry.z, Pv[c], bf2f(si.z));
        carry.w = fmaf(carry.w, Pv[c], bf2f(si.w));
    }
}

// -------------------- MFMA chunk scan: pass 2 ------------------------------
// R17: 4 heads/block, shared raw-C staging, dacl in f32 epilogue.
// R19: Sinit is bf16 -> the B-fragment is ONE b128 load (was 2x float4 +
// 8x f2bf); yp1 stored bf16.
__global__ __launch_bounds__(256) void scan_mfma2(
    const float* __restrict__ convout, const float* __restrict__ dtbuf,
    const float* __restrict__ A_log, const u16* __restrict__ Sinit,
    u16* __restrict__ yp1)
{
    __shared__ u16 Clds2[32 * 72];       // raw C bf16 [t][n] (shared)
    __shared__ float dtl[4][32], dacl[4][32];
    int blk = blockIdx.x;                // 512 = (b*4 + hq)*32 + c
    int c   = blk & 31;
    int bg  = blk >> 5;
    int b   = bg >> 2;
    int hq  = bg & 3;
    int tid = threadIdx.x;
    int w    = tid >> 6;                 // wave = head within quad
    int lane = tid & 63;
    int h   = hq * 4 + w;
    int bh  = b * 16 + h;
    int lrow = lane & 15, kq = lane >> 4;
    size_t base = ((size_t)b * LL + (size_t)c * CHUNK) * CONVDIM;
    float Ah = -__expf(A_log[h]);

    if (lane < 32)
        dtl[w][lane] = dtbuf[((size_t)b * LL + (size_t)c * CHUNK + lane) * NHEADS + h];
    // shared raw-C staging: 32 t x 16 float4 = 512 float4 over 256 thr, 2 it
    #pragma unroll
    for (int it = 0; it < 2; ++it) {
        int idx = it * 256 + tid;
        int t = idx >> 4, q = idx & 15;
        float4 v = *reinterpret_cast<const float4*>(
            &convout[base + (size_t)t * CONVDIM + DINNER + DSTATE + q * 4]);
        ushort4 r4;
        r4.x = f2bf(v.x); r4.y = f2bf(v.y);
        r4.z = f2bf(v.z); r4.w = f2bf(v.w);
        *reinterpret_cast<ushort4*>(&Clds2[t * 72 + q * 4]) = r4;
    }
    __syncthreads();

    float s_inc = 0.f;
    #pragma unroll
    for (int j = 0; j < 32; ++j) {
        float v = dtl[w][j];
        if (j <= lane) s_inc += v;
    }
    if (lane < 32) dacl[w][lane] = __expf(Ah * s_inc);

    f32x4 accI[2][4];
    #pragma unroll
    for (int i = 0; i < 2; i++)
        #pragma unroll
        for (int j = 0; j < 4; j++) {
            accI[i][j][0]=0.f; accI[i][j][1]=0.f; accI[i][j][2]=0.f; accI[i][j][3]=0.f;
        }
    #pragma unroll
    for (int ks = 0; ks < 2; ++ks) {
        bf16x8 ca[2];
        #pragma unroll
        for (int i = 0; i < 2; i++)
            ca[i] = *reinterpret_cast<const bf16x8*>(&Clds2[(16*i + lrow) * 72 + ks*32 + kq*8]);
        int nq = ks * 2 + (kq >> 1);
        int off = (kq & 1) * 8;
        #pragma unroll
        for (int j = 0; j < 4; j++) {
            int p = 16*j + lrow;
            const u16* sp = Sinit + ((size_t)(bh * 4 + nq) * NCHUNK + c) * 1024 + p * 16 + off;
            bf16x8 fr = *reinterpret_cast<const bf16x8*>(sp);
            #pragma unroll
            for (int i = 0; i < 2; i++)
                accI[i][j] = __builtin_amdgcn_mfma_f32_16x16x32_bf16(ca[i], fr, accI[i][j], 0, 0, 0);
        }
    }

    u16* yb = yp1 + ((size_t)b * LL + (size_t)c * CHUNK) * DINNER + h * HEADDIM;
    #pragma unroll
    for (int i = 0; i < 2; i++)
        #pragma unroll
        for (int r = 0; r < 4; r++) {
            int t = 16*i + kq*4 + r;
            float sct = dacl[w][t];
            #pragma unroll
            for (int j = 0; j < 4; j++)
                yb[(size_t)t * DINNER + 16*j + lrow] = f2bf(accI[i][j][r] * sct);
        }
}

// ------------- gated RMSNorm (yp0+yp1+xD)*silu(z), bf16 out ----------------
// R19: yp0/yp1 are bf16 inputs.
__global__ __launch_bounds__(256) void gated_rms_kernel(
    const u16* __restrict__ yp0, const u16* __restrict__ yp1,
    const float* __restrict__ convout, const float* __restrict__ zx,
    const float* __restrict__ Dv, const float* __restrict__ norm_w,
    u16* __restrict__ gout)
{
    int bl = blockIdx.x;
    int c = threadIdx.x * 4;
    ushort4 y0 = *reinterpret_cast<const ushort4*>(yp0 + (size_t)bl * DINNER + c);
    ushort4 y1 = *reinterpret_cast<const ushort4*>(yp1 + (size_t)bl * DINNER + c);
    float4 xv = *reinterpret_cast<const float4*>(convout + (size_t)bl * CONVDIM + c);
    float4 zv = *reinterpret_cast<const float4*>(zx + (size_t)bl * NPROJ_PAD + c);
    float Dh = Dv[c >> 6];
    float g0 = (bf2f(y0.x) + bf2f(y1.x) + xv.x * Dh) * silu_f(zv.x);
    float g1 = (bf2f(y0.y) + bf2f(y1.y) + xv.y * Dh) * silu_f(zv.y);
    float g2 = (bf2f(y0.z) + bf2f(y1.z) + xv.z * Dh) * silu_f(zv.z);
    float g3 = (bf2f(y0.w) + bf2f(y1.w) + xv.w * Dh) * silu_f(zv.w);
    float tot = block_sum(g0 * g0 + g1 * g1 + g2 * g2 + g3 * g3);
    float sc = rsqrtf(tot * (1.f / DINNER) + 1e-5f);
    float4 nw = *reinterpret_cast<const float4*>(norm_w + c);
    ushort4 o;
    o.x = f2bf(g0 * sc * nw.x); o.y = f2bf(g1 * sc * nw.y);
    o.z = f2bf(g2 * sc * nw.z); o.w = f2bf(g3 * sc * nw.w);
    *reinterpret_cast<ushort4*>(gout + (size_t)bl * DINNER + c) = o;
}

// ---- residual + 4 split-K partials + RMSNorm (no weight), f32 out ---------
// R20: partials are bf16 (halves the 201 MB partial round-trip).
__global__ void residual_rms_sk_kernel(
    const float* __restrict__ a, const u16* __restrict__ pbuf,
    float* __restrict__ outf, int ncols, int rows)
{
    int row = blockIdx.x;
    int c = threadIdx.x * 4;
    size_t slice = (size_t)rows * ncols;
    size_t off = (size_t)row * ncols + c;
    float4 va = *reinterpret_cast<const float4*>(a + off);
    ushort4 p0 = *reinterpret_cast<const ushort4*>(pbuf + off);
    ushort4 p1 = *reinterpret_cast<const ushort4*>(pbuf + slice + off);
    ushort4 p2 = *reinterpret_cast<const ushort4*>(pbuf + 2 * slice + off);
    ushort4 p3 = *reinterpret_cast<const ushort4*>(pbuf + 3 * slice + off);
    float v0 = va.x + ((bf2f(p0.x) + bf2f(p1.x)) + (bf2f(p2.x) + bf2f(p3.x)));
    float v1 = va.y + ((bf2f(p0.y) + bf2f(p1.y)) + (bf2f(p2.y) + bf2f(p3.y)));
    float v2 = va.z + ((bf2f(p0.z) + bf2f(p1.z)) + (bf2f(p2.z) + bf2f(p3.z)));
    float v3 = va.w + ((bf2f(p0.w) + bf2f(p1.w)) + (bf2f(p2.w) + bf2f(p3.w)));
    float tot = block_sum(v0 * v0 + v1 * v1 + v2 * v2 + v3 * v3);
    float sc = rsqrtf(tot / (float)ncols + 1e-5f);
    float4 o; o.x = v0 * sc; o.y = v1 * sc; o.z = v2 * sc; o.w = v3 * sc;
    *reinterpret_cast<float4*>(outf + off) = o;
}

// ------------- transpose per batch: in (R,C) -> out (C,R), dual write ------
__global__ __launch_bounds__(256) void transpose_dual_kernel(
    const float* __restrict__ in, u16* __restrict__ outb,
    float* __restrict__ outf, int R, int C)
{
    __shared__ float tile[32][33];
    int b = blockIdx.z;
    int c0 = blockIdx.x * 32, r0 = blockIdx.y * 32;
    const float* ip = in + (size_t)b * R * C;
    for (int i = threadIdx.y; i < 32; i += 8)
        tile[i][threadIdx.x] = ip[(size_t)(r0 + i) * C + c0 + threadIdx.x];
    __syncthreads();
    size_t ob = (size_t)b * R * C;
    for (int i = threadIdx.y; i < 32; i += 8) {
        float v = tile[threadIdx.x][i];
        size_t oi = ob + (size_t)(c0 + i) * R + r0 + threadIdx.x;
        outf[oi] = v;
        outb[oi] = f2bf(v);
    }
}

// ---------------------------------------------------------------------------
extern "C" void kernel_launch(void* const* d_in, const int* in_sizes, int n_in,
                              void* d_out, int out_size, void* d_ws, size_t ws_size,
                              hipStream_t stream)
{
    const float* hid      = (const float*)d_in[0];
    const float* in_proj  = (const float*)d_in[1];
    const float* conv_w   = (const float*)d_in[2];
    const float* conv_b   = (const float*)d_in[3];
    const float* dt_bias  = (const float*)d_in[4];
    const float* A_log    = (const float*)d_in[5];
    const float* Dv       = (const float*)d_in[6];
    const float* norm_w   = (const float*)d_in[7];
    const float* out_proj = (const float*)d_in[8];
    const float* gu_t     = (const float*)d_in[9];
    const float* down_t   = (const float*)d_in[10];
    const float* gu_m     = (const float*)d_in[11];
    const float* down_m   = (const float*)d_in[12];
    float* outp = (float*)d_out;

    char* ws = (char*)d_ws;
    u16* bf        = (u16*)ws;
    u16* hid_bf    = bf;
    u16* w_inproj  = bf + HID_E;
    u16* w_outproj = w_inproj + INPROJ_P_E;
    u16* w_gut     = w_outproj + OUTPROJ_E;
    u16* w_downt   = w_gut + GUT_E;
    u16* w_gum     = w_downt + DOWNT_E;
    u16* w_downm   = w_gum + GUM_E;
    size_t o = (size_t)(CONV_TOT_E * 2);
    auto alloc = [&](size_t bytes) { size_t r = o; o = (o + bytes + 255) & ~(size_t)255; return r; };
    size_t dt_off  = alloc(4096 * 16 * 4);
    size_t g_off   = alloc((size_t)4096 * 1024 * 2);
    size_t h1_off  = alloc((size_t)4096 * 512 * 4);
    size_t Pt_off  = alloc(2048 * 4);
    // ---- MLP region (live step 8+); Sc/Sinit OVERLAY it (live steps 4-5).
    size_t xtb_off = alloc((size_t)2048 * 1024 * 2);
    size_t xtf_off = alloc((size_t)2048 * 1024 * 4);
    size_t act1_off= alloc((size_t)2048 * 2816 * 2);
    size_t x2_off  = alloc((size_t)2048 * 1024 * 4);
    size_t h2b_off = alloc((size_t)4096 * 512 * 2);
    size_t h2f_off = alloc((size_t)4096 * 512 * 4);
    size_t act2_off= alloc((size_t)4096 * 1536 * 2);
    size_t pad_off = alloc((size_t)10 * 1024 * 1024);
    size_t Sc_off  = xtb_off;                          // bf16: 16.78 MB
    size_t Si_off  = xtb_off + (size_t)8192 * 1024 * 4;// bf16: 16.78 MB
    (void)pad_off;
    size_t R_off   = o;
    size_t zx_off  = R_off;
    size_t cv_off  = zx_off + (size_t)4096 * NPROJ_PAD * 4;
    size_t y_off   = cv_off + (size_t)4096 * CONVDIM * 4;
    size_t sk_off  = R_off;

    float* zx      = (float*)(ws + zx_off);
    float* convout = (float*)(ws + cv_off);
    u16*   ybuf    = (u16*)(ws + y_off);             // yp0 (bf16, R19)
    float* dtbuf   = (float*)(ws + dt_off);
    u16*   g_bf    = (u16*)(ws + g_off);
    float* h1      = (float*)(ws + h1_off);
    u16*   xt_bf   = (u16*)(ws + xtb_off);
    float* xt_f    = (float*)(ws + xtf_off);
    u16*   act1    = (u16*)(ws + act1_off);
    float* x2      = (float*)(ws + x2_off);
    u16*   h2_bf   = (u16*)(ws + h2b_off);
    float* h2_f    = (float*)(ws + h2f_off);
    u16*   act2    = (u16*)(ws + act2_off);
    u16*   skbuf   = (u16*)(ws + sk_off);            // bf16 partials (R20)
    u16*   Sc      = (u16*)(ws + Sc_off);            // bf16; yp1 after combine
    u16*   Sinit   = (u16*)(ws + Si_off);            // bf16
    float* Ptot    = (float*)(ws + Pt_off);

    // 1) convert weights + hidden to bf16
    convert_all_kernel<<<14464, 256, 0, stream>>>(
        hid, in_proj, out_proj, gu_t, down_t, gu_m, down_m, bf);

    // 2) zxbcdt = hidden @ in_proj^T
    gemm_bt<<<dim3(NPROJ_PAD / 128, 4096 / 128), 256, 0, stream>>>(
        hid_bf, w_inproj, zx, 4096, NPROJ_PAD, 512);

    // 3) conv + dt
    conv_dt_kernel<<<18688, 256, 0, stream>>>(zx, conv_w, conv_b, dt_bias, convout, dtbuf);

    // 4) MFMA chunk scan (R19: all state bf16)
    scan_mfma1<<<512, 256, 0, stream>>>(convout, dtbuf, A_log, Sc, Ptot, ybuf);
    scan_combine<<<256, 256, 0, stream>>>(Sc, Ptot, Sinit);
    scan_mfma2<<<512, 256, 0, stream>>>(convout, dtbuf, A_log, Sinit, Sc);

    // 5) gated RMSNorm -> bf16
    gated_rms_kernel<<<4096, 256, 0, stream>>>(ybuf, Sc, convout, zx, Dv, norm_w, g_bf);

    // 6) out_proj GEMM, split-K x4 -> bf16 partials in skbuf
    gemm_bt_sk<<<dim3(512 / 128, 4096 / 128, 4), 256, 0, stream>>>(
        g_bf, w_outproj, skbuf, 4096, 512, 1024, 256);

    // 7) h1 = rms(hidden + sum partials)
    residual_rms_sk_kernel<<<4096, 128, 0, stream>>>(hid, skbuf, h1, 512, 4096);

    // 8) transpose (B,1024,512) -> (B,512,1024)
    transpose_dual_kernel<<<dim3(16, 32, 4), dim3(32, 8), 0, stream>>>(h1, xt_bf, xt_f, 1024, 512);

    // 9) token MLP fused: act1 = swiglu(xt @ gu_t^T)  (704 blocks, 128x64)
    gemm_swiglu<<<dim3(INTER_T / 64, 2048 / 128), 256, 0, stream>>>(
        xt_bf, w_gut, act1, 2048, INTER_T, 1024);

    // 10) down_t GEMM, split-K x4 -> bf16 partials in skbuf
    gemm_bt_sk<<<dim3(1024 / 128, 2048 / 128, 4), 256, 0, stream>>>(
        act1, w_downt, skbuf, 2048, 1024, 2816, 704);

    // 11) x2 = rms(xt_f + sum partials)
    residual_rms_sk_kernel<<<2048, 256, 0, stream>>>(xt_f, skbuf, x2, 1024, 2048);

    // 12) transpose back (B,512,1024) -> (B,1024,512)
    transpose_dual_kernel<<<dim3(32, 16, 4), dim3(32, 8), 0, stream>>>(x2, h2_bf, h2_f, 512, 1024);

    // 13) channel MLP fused: act2 = swiglu(h2 @ gu_m^T)  (768 blocks, 128x64)
    gemm_swiglu<<<dim3(INTER_M / 64, 4096 / 128), 256, 0, stream>>>(
        h2_bf, w_gum, act2, 4096, INTER_M, 512);

    // 14) down_m GEMM, split-K x4 -> bf16 partials in skbuf
    gemm_bt_sk<<<dim3(512 / 128, 4096 / 128, 4), 256, 0, stream>>>(
        act2, w_downm, skbuf, 4096, 512, 1536, 384);

    // 15) out = rms(h2_f + sum partials)
    residual_rms_sk_kernel<<<4096, 128, 0, stream>>>(h2_f, skbuf, outp, 512, 4096);
}

// Round 6
// 318.033 us; speedup vs baseline: 1.0866x; 1.0050x over previous
//
#include <hip/hip_runtime.h>

// ---------------------------------------------------------------------------
// Mamba2 hybrid block. GEMMs: bf16 MFMA 16x16x32, f32 accumulate, m97-style
// global_load_lds(16B) staging, BK=64. 3-bit XOR chunk swizzle keeps frag
// reads 2-way/free. Small-N GEMMs use split-K x4 into bf16 partial buffers;
// partials summed in residual_rms. MLP gu-GEMMs fuse SwiGLU (128x64 tile).
// Scan: MFMA chunked.
// R16: scan_mfma1 4 heads/block shared B/C staging (-14.1 us, 355.5->341.4).
// R17/R18: scan_mfma2 4 heads/block + scan_combine unroll: NEUTRAL.
// R19: bf16 scan state (Sc/Sinit/yp0/yp1): -17.4 us (345.6->328.2).
// R20: bf16 split-K partials (-8.6 us, 328.2->319.6, absmax 0.03125 stable).
// R21: bf16 zx + convout. All scan consumers ALREADY f2bf convout at point
// of use -> storing bf16 is numerically identical there; staging loops become
// straight ushort8 copies. New roundings (conv taps, dt, silu(z), gated xv)
// are 2^-9 rel, below the existing MFMA noise floor. ~70 MB HBM removed.
// ---------------------------------------------------------------------------

#define BB 4
#define LL 1024
#define DMODEL 512
#define DINNER 1024
#define NHEADS 16
#define HEADDIM 64
#define DSTATE 64
#define CONVDIM 1152        // DINNER + 2*DSTATE
#define NPROJ 2192          // D_IN_PROJ
#define NPROJ_PAD 2304      // padded to multiple of 128
#define INTER_T 2816
#define INTER_M 1536
#define NCHUNK 32
#define CHUNK 32

typedef __bf16 bf16x8 __attribute__((ext_vector_type(8)));
typedef float  f32x4  __attribute__((ext_vector_type(4)));
typedef unsigned short u16;
typedef unsigned int   u32;
typedef unsigned short u16x8 __attribute__((ext_vector_type(8)));

__device__ __forceinline__ u16 f2bf(float x) {
    union { float f; u32 u; } v; v.f = x;
    u32 u = v.u;
    return (u16)((u + 0x7fffu + ((u >> 16) & 1u)) >> 16);
}
__device__ __forceinline__ float silu_f(float x) {
    return x / (1.f + __expf(-x));
}
__device__ __forceinline__ float bf2f(u16 w) {
    union { u32 u; float f; } a; a.u = ((u32)w) << 16; return a.f;
}

// C-store helpers: f32 passthrough or bf16 round (R20/R21)
__device__ __forceinline__ void cstore(float* p, float v) { *p = v; }
__device__ __forceinline__ void cstore(u16*   p, float v) { *p = f2bf(v); }

// async global->LDS, 16B per lane; LDS dest is wave-uniform base + lane*16
__device__ __forceinline__ void gld_lds16(const u16* g, u16* l) {
    __builtin_amdgcn_global_load_lds(
        (const __attribute__((address_space(1))) unsigned int*)g,
        (__attribute__((address_space(3))) unsigned int*)l, 16, 0, 0);
}

// --------------------------- block-wide sum --------------------------------
__device__ __forceinline__ float block_sum(float v) {
    #pragma unroll
    for (int off = 32; off > 0; off >>= 1) v += __shfl_xor(v, off, 64);
    __shared__ float red[4];
    int w = threadIdx.x >> 6;
    int nwv = blockDim.x >> 6;
    if ((threadIdx.x & 63) == 0) red[w] = v;
    __syncthreads();
    float tot = red[0];
    for (int i = 1; i < nwv; i++) tot += red[i];
    return tot;
}

// --------------------- f32 -> bf16 convert (all weights + hidden) ----------
#define HID_E      2097152LL   // 4096*512
#define INPROJ_P_E 1179648LL   // 2304*512
#define INPROJ_S_E 1122304LL   // 2192*512
#define OUTPROJ_E   524288LL   // 512*1024
#define GUT_E      5767168LL   // 5632*1024
#define DOWNT_E    2883584LL   // 1024*2816
#define GUM_E      1572864LL   // 3072*512
#define DOWNM_E     786432LL   // 512*1536
#define CONV_TOT_E 14811136LL

__global__ __launch_bounds__(256) void convert_all_kernel(
    const float* __restrict__ s_hid, const float* __restrict__ s_inproj,
    const float* __restrict__ s_outproj, const float* __restrict__ s_gut,
    const float* __restrict__ s_downt, const float* __restrict__ s_gum,
    const float* __restrict__ s_downm, u16* __restrict__ dst)
{
    long long idx = (long long)blockIdx.x * 256 + threadIdx.x;
    long long e = idx * 4;
    if (e >= CONV_TOT_E) return;
    const float* src; long long off, nsrc;
    long long c0 = HID_E;
    long long c1 = c0 + INPROJ_P_E;
    long long c2 = c1 + OUTPROJ_E;
    long long c3 = c2 + GUT_E;
    long long c4 = c3 + DOWNT_E;
    long long c5 = c4 + GUM_E;
    if      (e < c0) { src = s_hid;     off = e;      nsrc = HID_E; }
    else if (e < c1) { src = s_inproj;  off = e - c0; nsrc = INPROJ_S_E; }
    else if (e < c2) { src = s_outproj; off = e - c1; nsrc = OUTPROJ_E; }
    else if (e < c3) { src = s_gut;     off = e - c2; nsrc = GUT_E; }
    else if (e < c4) { src = s_downt;   off = e - c3; nsrc = DOWNT_E; }
    else if (e < c5) { src = s_gum;     off = e - c4; nsrc = GUM_E; }
    else             { src = s_downm;   off = e - c5; nsrc = DOWNM_E; }
    ushort4 r;
    if (off < nsrc) {
        float4 v = *reinterpret_cast<const float4*>(src + off);
        r.x = f2bf(v.x); r.y = f2bf(v.y); r.z = f2bf(v.z); r.w = f2bf(v.w);
    } else {
        r.x = 0; r.y = 0; r.z = 0; r.w = 0;
    }
    *reinterpret_cast<ushort4*>(dst + e) = r;
}

// ----------------------------- bf16 MFMA GEMM (BK=64) ----------------------
// C[M,N] = A[M,K] * W[N,K]^T. 128x128 tile, 4 waves of 64x64 (4x4 MFMAs).
// R20/R21: CT templates the C dtype (f32 or bf16).
template<bool SK, typename CT>
__device__ __forceinline__ void gemm_bt_body(
    const u16* __restrict__ A, const u16* __restrict__ W,
    CT* __restrict__ C, int M, int N, int K, int kLen)
{
    __shared__ u16 As[128 * 64];   // 16 KB
    __shared__ u16 Bs[128 * 64];   // 16 KB
    int tid = threadIdx.x;
    int m0 = blockIdx.y * 128, n0 = blockIdx.x * 128;
    int kBase = SK ? blockIdx.z * kLen : 0;
    CT* Cw = SK ? C + (size_t)blockIdx.z * M * N : C;
    int wave = tid >> 6, lane = tid & 63;
    int wm = (wave >> 1) * 64, wn = (wave & 1) * 64;
    int lrow = lane & 15;
    int kq = lane >> 4;
    int kx = lrow & 7;

    int rL = lane >> 3, cL = lane & 7;
    int cG = cL ^ rL;
    const u16* gA[4]; const u16* gB[4];
    u16 *lA[4], *lB[4];
    #pragma unroll
    for (int i = 0; i < 4; i++) {
        int r = wave * 32 + i * 8;
        gA[i] = A + (size_t)(m0 + r + rL) * K + kBase + cG * 8;
        gB[i] = W + (size_t)(n0 + r + rL) * K + kBase + cG * 8;
        lA[i] = &As[r * 64];
        lB[i] = &Bs[r * 64];
    }

    f32x4 acc[4][4];
    #pragma unroll
    for (int i = 0; i < 4; i++)
        #pragma unroll
        for (int j = 0; j < 4; j++) {
            acc[i][j][0] = 0.f; acc[i][j][1] = 0.f;
            acc[i][j][2] = 0.f; acc[i][j][3] = 0.f;
        }

    for (int kt = 0; kt < kLen; kt += 64) {
        __syncthreads();
        #pragma unroll
        for (int i = 0; i < 4; i++) {
            gld_lds16(gA[i] + kt, lA[i]);
            gld_lds16(gB[i] + kt, lB[i]);
        }
        __syncthreads();
        #pragma unroll
        for (int ks = 0; ks < 2; ks++) {
            int ko = (((ks * 4 + kq) ^ kx) * 8);
            bf16x8 af[4], bfr[4];
            #pragma unroll
            for (int i = 0; i < 4; i++) {
                af[i]  = *reinterpret_cast<const bf16x8*>(&As[(wm + i * 16 + lrow) * 64 + ko]);
                bfr[i] = *reinterpret_cast<const bf16x8*>(&Bs[(wn + i * 16 + lrow) * 64 + ko]);
            }
            #pragma unroll
            for (int i = 0; i < 4; i++)
                #pragma unroll
                for (int j = 0; j < 4; j++)
                    acc[i][j] = __builtin_amdgcn_mfma_f32_16x16x32_bf16(af[i], bfr[j], acc[i][j], 0, 0, 0);
        }
    }

    // C/D layout: col = lane&15, row = (lane>>4)*4 + reg
    int rbase = m0 + wm + kq * 4;
    int cbase = n0 + wn + lrow;
    #pragma unroll
    for (int i = 0; i < 4; i++)
        #pragma unroll
        for (int j = 0; j < 4; j++)
            #pragma unroll
            for (int r = 0; r < 4; r++)
                cstore(&Cw[(size_t)(rbase + i * 16 + r) * N + cbase + j * 16], acc[i][j][r]);
}

// R21: in_proj GEMM emits bf16 zx
__global__ __launch_bounds__(256) void gemm_bt(
    const u16* __restrict__ A, const u16* __restrict__ W,
    u16* __restrict__ C, int M, int N, int K)
{
    gemm_bt_body<false, u16>(A, W, C, M, N, K, K);
}

__global__ __launch_bounds__(256) void gemm_bt_sk(
    const u16* __restrict__ A, const u16* __restrict__ W,
    u16* __restrict__ C, int M, int N, int K, int kLen)
{
    gemm_bt_body<true, u16>(A, W, C, M, N, K, kLen);
}

// --------------- fused gate/up GEMM + SwiGLU (128x64, BK=64) ---------------
// act[M,inter] = silu(A·Wg^T) * (A·Wu^T). Bs rows 0..63 = gate, 64..127 = up.
__global__ __launch_bounds__(256) void gemm_swiglu(
    const u16* __restrict__ A, const u16* __restrict__ W,
    u16* __restrict__ act, int M, int inter, int K)
{
    __shared__ u16 As[128 * 64];   // 16 KB
    __shared__ u16 Bs[128 * 64];   // 16 KB
    int tid = threadIdx.x;
    int m0 = blockIdx.y * 128, n0 = blockIdx.x * 64;
    int wave = tid >> 6, lane = tid & 63;
    int wm = (wave >> 1) * 64, wn = (wave & 1) * 32;
    int lrow = lane & 15;
    int kq = lane >> 4;
    int kx = lrow & 7;

    int rL = lane >> 3, cL = lane & 7;
    int cG = cL ^ rL;
    const u16* gA[4]; const u16* gB[4];
    u16 *lA[4], *lB[4];
    #pragma unroll
    for (int i = 0; i < 4; i++) {
        int r = wave * 32 + i * 8;
        gA[i] = A + (size_t)(m0 + r + rL) * K + cG * 8;
        lA[i] = &As[r * 64];
        int rB = r;   // combined index: 0..63 gate, 64..127 up (per wave 32)
        int grow = (rB < 64) ? (n0 + rB + rL)
                             : (inter + n0 + rB - 64 + rL);
        gB[i] = W + (size_t)grow * K + cG * 8;
        lB[i] = &Bs[rB * 64];
    }

    f32x4 accg[4][2], accu[4][2];
    #pragma unroll
    for (int i = 0; i < 4; i++)
        #pragma unroll
        for (int j = 0; j < 2; j++) {
            accg[i][j][0]=0.f; accg[i][j][1]=0.f; accg[i][j][2]=0.f; accg[i][j][3]=0.f;
            accu[i][j][0]=0.f; accu[i][j][1]=0.f; accu[i][j][2]=0.f; accu[i][j][3]=0.f;
        }

    for (int kt = 0; kt < K; kt += 64) {
        __syncthreads();
        #pragma unroll
        for (int i = 0; i < 4; i++) {
            gld_lds16(gA[i] + kt, lA[i]);
            gld_lds16(gB[i] + kt, lB[i]);
        }
        __syncthreads();
        #pragma unroll
        for (int ks = 0; ks < 2; ks++) {
            int ko = (((ks * 4 + kq) ^ kx) * 8);
            bf16x8 af[4], bg[2], bu[2];
            #pragma unroll
            for (int i = 0; i < 4; i++)
                af[i] = *reinterpret_cast<const bf16x8*>(&As[(wm + i * 16 + lrow) * 64 + ko]);
            #pragma unroll
            for (int j = 0; j < 2; j++) {
                bg[j] = *reinterpret_cast<const bf16x8*>(&Bs[(wn + j * 16 + lrow) * 64 + ko]);
                bu[j] = *reinterpret_cast<const bf16x8*>(&Bs[(64 + wn + j * 16 + lrow) * 64 + ko]);
            }
            #pragma unroll
            for (int i = 0; i < 4; i++)
                #pragma unroll
                for (int j = 0; j < 2; j++) {
                    accg[i][j] = __builtin_amdgcn_mfma_f32_16x16x32_bf16(af[i], bg[j], accg[i][j], 0, 0, 0);
                    accu[i][j] = __builtin_amdgcn_mfma_f32_16x16x32_bf16(af[i], bu[j], accu[i][j], 0, 0, 0);
                }
        }
    }

    int rbase = m0 + wm + kq * 4;
    int cbase = n0 + wn + lrow;
    #pragma unroll
    for (int i = 0; i < 4; i++)
        #pragma unroll
        for (int j = 0; j < 2; j++)
            #pragma unroll
            for (int r = 0; r < 4; r++) {
                float g = accg[i][j][r], u = accu[i][j][r];
                act[(size_t)(rbase + i * 16 + r) * inter + cbase + j * 16] =
                    f2bf(silu_f(g) * u);
            }
}

// ----------------- conv (depthwise, causal, width 4) + dt ------------------
// R21: zx and convout are bf16; accumulate in f32.
__global__ __launch_bounds__(256) void conv_dt_kernel(
    const u16* __restrict__ zx, const float* __restrict__ conv_w,
    const float* __restrict__ conv_b, const float* __restrict__ dt_bias,
    u16* __restrict__ convout, float* __restrict__ dtbuf)
{
    int idx = blockIdx.x * 256 + threadIdx.x;   // over 4096*1168
    int bl = idx / 1168;
    int c  = idx - bl * 1168;
    int l  = bl & (LL - 1);
    if (c < CONVDIM) {
        const u16* col = zx + (size_t)bl * NPROJ_PAD + DINNER + c;
        float acc = conv_b[c];
        #pragma unroll
        for (int i = 0; i < 4; i++) {
            int lt = l - 3 + i;
            float v = (lt >= 0) ? bf2f(col[(long long)(lt - l) * NPROJ_PAD]) : 0.f;
            acc = fmaf(v, conv_w[c * 4 + i], acc);
        }
        convout[(size_t)bl * CONVDIM + c] = f2bf(silu_f(acc));
    } else {
        int h = c - CONVDIM;
        float v = bf2f(zx[(size_t)bl * NPROJ_PAD + 2176 + h]) + dt_bias[h];
        float sp = (v > 20.f) ? v : log1pf(__expf(v));
        dtbuf[(size_t)bl * NHEADS + h] = sp;
    }
}

// -------------------- MFMA chunk scan: pass 1 ------------------------------
// R16: 4 heads per block (4 waves), shared B/C staging.
// R19: Sc and yp0 outputs bf16. R21: convout is bf16 -> staging loops are
// straight ushort8 copies (no f2bf), B/C staging 2 iters (was 4).
__global__ __launch_bounds__(256) void scan_mfma1(
    const u16* __restrict__ convout, const float* __restrict__ dtbuf,
    const float* __restrict__ A_log, u16* __restrict__ Sc,
    float* __restrict__ Ptot, u16* __restrict__ yp0)
{
    __shared__ u16 Blds[32 * 72];        // raw B bf16 [t][n] (shared)
    __shared__ u16 Clds[32 * 72];        // raw C bf16 [t][n] (shared)
    __shared__ u16 Xt[4][64 * 40];       // x^T bf16 [p][t] (per head)
    __shared__ u16 Bht[4][64 * 40];      // (w_t*dt_t*B)^T bf16 [n][t]
    __shared__ u16 Wlds[4][32 * 40];     // W bf16 [t][t']
    __shared__ float dtl[4][32], cuml[4][32], warr[4][32];

    int blk = blockIdx.x;                // 512 = (b*4 + hq)*32 + c
    int c   = blk & 31;
    int bg  = blk >> 5;
    int b   = bg >> 2;
    int hq  = bg & 3;
    int tid = threadIdx.x;
    int w    = tid >> 6;                 // wave = head within quad
    int lane = tid & 63;
    int h   = hq * 4 + w;
    int bh  = b * 16 + h;
    int lrow = lane & 15, kq = lane >> 4;
    size_t base = ((size_t)b * LL + (size_t)c * CHUNK) * CONVDIM;
    float Ah = -__expf(A_log[h]);

    if (lane < 32)
        dtl[w][lane] = dtbuf[((size_t)b * LL + (size_t)c * CHUNK + lane) * NHEADS + h];
    // shared B/C staging: 32 t x 16 chunks of 8 bf16; 256 thr -> 2 iters
    #pragma unroll
    for (int it = 0; it < 2; ++it) {
        int idx = it * 256 + tid;
        int t = idx >> 4, q = idx & 15;
        u16x8 v = *reinterpret_cast<const u16x8*>(
            &convout[base + (size_t)t * CONVDIM + DINNER + q * 8]);
        if (q < 8) *reinterpret_cast<u16x8*>(&Blds[t * 72 + q * 8]) = v;
        else       *reinterpret_cast<u16x8*>(&Clds[t * 72 + (q - 8) * 8]) = v;
    }
    #pragma unroll
    for (int t = 0; t < 32; ++t)
        Xt[w][lane * 40 + t] = convout[base + (size_t)t * CONVDIM + h * HEADDIM + lane];
    __syncthreads();

    float s_inc = 0.f, s_all = 0.f;
    #pragma unroll
    for (int j = 0; j < 32; ++j) {
        float v = dtl[w][j];
        s_all += v;
        if (j <= lane) s_inc += v;
    }
    if (lane < 32) {
        cuml[w][lane] = s_inc;
        warr[w][lane] = __expf(Ah * (s_all - s_inc)) * dtl[w][lane];
    }
    float cumTot = s_all;
    __syncthreads();

    #pragma unroll
    for (int t = 0; t < 32; ++t)
        Bht[w][lane * 40 + t] = f2bf(warr[w][t] * bf2f(Blds[t * 72 + lane]));

    f32x4 accG[2][2];
    #pragma unroll
    for (int i = 0; i < 2; i++)
        #pragma unroll
        for (int j = 0; j < 2; j++) {
            accG[i][j][0]=0.f; accG[i][j][1]=0.f; accG[i][j][2]=0.f; accG[i][j][3]=0.f;
        }
    #pragma unroll
    for (int ks = 0; ks < 2; ++ks) {
        bf16x8 af[2], bfr[2];
        #pragma unroll
        for (int i = 0; i < 2; i++) {
            af[i]  = *reinterpret_cast<const bf16x8*>(&Clds[(16*i + lrow) * 72 + ks*32 + kq*8]);
            bfr[i] = *reinterpret_cast<const bf16x8*>(&Blds[(16*i + lrow) * 72 + ks*32 + kq*8]);
        }
        #pragma unroll
        for (int i = 0; i < 2; i++)
            #pragma unroll
            for (int j = 0; j < 2; j++)
                accG[i][j] = __builtin_amdgcn_mfma_f32_16x16x32_bf16(af[i], bfr[j], accG[i][j], 0, 0, 0);
    }

    float ctp0 = cuml[w][lrow],      dtp0 = dtl[w][lrow];
    float ctp1 = cuml[w][16 + lrow], dtp1 = dtl[w][16 + lrow];
    #pragma unroll
    for (int i = 0; i < 2; i++)
        #pragma unroll
        for (int r = 0; r < 4; r++) {
            int t = 16*i + kq*4 + r;
            float ct = cuml[w][t];
            #pragma unroll
            for (int j = 0; j < 2; j++) {
                int tp = 16*j + lrow;
                float ctp = j ? ctp1 : ctp0;
                float dtp = j ? dtp1 : dtp0;
                float g = accG[i][j][r];
                float wv = (tp <= t) ? __expf(Ah * (ct - ctp)) * dtp * g : 0.f;
                Wlds[w][t * 40 + tp] = f2bf(wv);
            }
        }
    __syncthreads();

    bf16x8 xf[4];
    #pragma unroll
    for (int j = 0; j < 4; j++)
        xf[j] = *reinterpret_cast<const bf16x8*>(&Xt[w][(16*j + lrow) * 40 + kq*8]);
    f32x4 accY[2][4];
    #pragma unroll
    for (int i = 0; i < 2; i++) {
        bf16x8 wf = *reinterpret_cast<const bf16x8*>(&Wlds[w][(16*i + lrow) * 40 + kq*8]);
        #pragma unroll
        for (int j = 0; j < 4; j++) {
            accY[i][j][0]=0.f; accY[i][j][1]=0.f; accY[i][j][2]=0.f; accY[i][j][3]=0.f;
            accY[i][j] = __builtin_amdgcn_mfma_f32_16x16x32_bf16(wf, xf[j], accY[i][j], 0, 0, 0);
        }
    }

    f32x4 accS[4][4];
    #pragma unroll
    for (int j = 0; j < 4; j++) {
        bf16x8 bb = *reinterpret_cast<const bf16x8*>(&Bht[w][(16*j + lrow) * 40 + kq*8]);
        #pragma unroll
        for (int i = 0; i < 4; i++) {
            accS[i][j][0]=0.f; accS[i][j][1]=0.f; accS[i][j][2]=0.f; accS[i][j][3]=0.f;
            accS[i][j] = __builtin_amdgcn_mfma_f32_16x16x32_bf16(xf[i], bb, accS[i][j], 0, 0, 0);
        }
    }

    u16* yb = yp0 + ((size_t)b * LL + (size_t)c * CHUNK) * DINNER + h * HEADDIM;
    #pragma unroll
    for (int i = 0; i < 2; i++)
        #pragma unroll
        for (int r = 0; r < 4; r++) {
            int t = 16*i + kq*4 + r;
            #pragma unroll
            for (int j = 0; j < 4; j++)
                yb[(size_t)t * DINNER + 16*j + lrow] = f2bf(accY[i][j][r]);
        }
    #pragma unroll
    for (int i = 0; i < 4; i++)
        #pragma unroll
        for (int r = 0; r < 4; r++) {
            int p = 16*i + kq*4 + r;
            #pragma unroll
            for (int j = 0; j < 4; j++)
                Sc[((size_t)(bh * 4 + j) * NCHUNK + c) * 1024 + p * 16 + lrow] = f2bf(accS[i][j][r]);
        }
    if (lane == 0) Ptot[bh * NCHUNK + c] = __expf(Ah * cumTot);
}

// ----------------------- chunked SSM scan: combine -------------------------
__global__ __launch_bounds__(256) void scan_combine(
    const u16* __restrict__ Sc, const float* __restrict__ Ptot,
    u16* __restrict__ Sinit)
{
    int blk = blockIdx.x;             // 256 = bh*4 + n-quarter
    int bh = blk >> 2;
    int tid = threadIdx.x;
    int p = tid >> 2;                 // 0..63
    int ncol = (tid & 3) * 4;         // 4 elems of the 16-wide n slice
    float Pv[NCHUNK];
    #pragma unroll
    for (int c = 0; c < NCHUNK; ++c) Pv[c] = Ptot[bh * NCHUNK + c];
    float4 carry; carry.x = 0.f; carry.y = 0.f; carry.z = 0.f; carry.w = 0.f;
    size_t rowbase = (size_t)blk * NCHUNK * 1024 + p * 16 + ncol;
    #pragma unroll
    for (int c = 0; c < NCHUNK; ++c) {
        size_t row = rowbase + (size_t)c * 1024;
        ushort4 o;
        o.x = f2bf(carry.x); o.y = f2bf(carry.y);
        o.z = f2bf(carry.z); o.w = f2bf(carry.w);
        *reinterpret_cast<ushort4*>(Sinit + row) = o;
        ushort4 si = *reinterpret_cast<const ushort4*>(Sc + row);
        carry.x = fmaf(carry.x, Pv[c], bf2f(si.x));
        carry.y = fmaf(carry.y, Pv[c], bf2f(si.y));
        carry.z = fmaf(carry.z, Pv[c], bf2f(si.z));
        carry.w = fmaf(carry.w, Pv[c], bf2f(si.w));
    }
}

// -------------------- MFMA chunk scan: pass 2 ------------------------------
// R17: 4 heads/block, shared raw-C staging, dacl in f32 epilogue.
// R21: convout bf16 -> C staging is ONE ushort8-copy iteration.
__global__ __launch_bounds__(256) void scan_mfma2(
    const u16* __restrict__ convout, const float* __restrict__ dtbuf,
    const float* __restrict__ A_log, const u16* __restrict__ Sinit,
    u16* __restrict__ yp1)
{
    __shared__ u16 Clds2[32 * 72];       // raw C bf16 [t][n] (shared)
    __shared__ float dtl[4][32], dacl[4][32];
    int blk = blockIdx.x;                // 512 = (b*4 + hq)*32 + c
    int c   = blk & 31;
    int bg  = blk >> 5;
    int b   = bg >> 2;
    int hq  = bg & 3;
    int tid = threadIdx.x;
    int w    = tid >> 6;                 // wave = head within quad
    int lane = tid & 63;
    int h   = hq * 4 + w;
    int bh  = b * 16 + h;
    int lrow = lane & 15, kq = lane >> 4;
    size_t base = ((size_t)b * LL + (size_t)c * CHUNK) * CONVDIM;
    float Ah = -__expf(A_log[h]);

    if (lane < 32)
        dtl[w][lane] = dtbuf[((size_t)b * LL + (size_t)c * CHUNK + lane) * NHEADS + h];
    // shared raw-C staging: 32 t x 8 chunks of 8 bf16 = 256 thr x 1 iter
    {
        int t = tid >> 3, q = tid & 7;
        u16x8 v = *reinterpret_cast<const u16x8*>(
            &convout[base + (size_t)t * CONVDIM + DINNER + DSTATE + q * 8]);
        *reinterpret_cast<u16x8*>(&Clds2[t * 72 + q * 8]) = v;
    }
    __syncthreads();

    float s_inc = 0.f;
    #pragma unroll
    for (int j = 0; j < 32; ++j) {
        float v = dtl[w][j];
        if (j <= lane) s_inc += v;
    }
    if (lane < 32) dacl[w][lane] = __expf(Ah * s_inc);

    f32x4 accI[2][4];
    #pragma unroll
    for (int i = 0; i < 2; i++)
        #pragma unroll
        for (int j = 0; j < 4; j++) {
            accI[i][j][0]=0.f; accI[i][j][1]=0.f; accI[i][j][2]=0.f; accI[i][j][3]=0.f;
        }
    #pragma unroll
    for (int ks = 0; ks < 2; ++ks) {
        bf16x8 ca[2];
        #pragma unroll
        for (int i = 0; i < 2; i++)
            ca[i] = *reinterpret_cast<const bf16x8*>(&Clds2[(16*i + lrow) * 72 + ks*32 + kq*8]);
        int nq = ks * 2 + (kq >> 1);
        int off = (kq & 1) * 8;
        #pragma unroll
        for (int j = 0; j < 4; j++) {
            int p = 16*j + lrow;
            const u16* sp = Sinit + ((size_t)(bh * 4 + nq) * NCHUNK + c) * 1024 + p * 16 + off;
            bf16x8 fr = *reinterpret_cast<const bf16x8*>(sp);
            #pragma unroll
            for (int i = 0; i < 2; i++)
                accI[i][j] = __builtin_amdgcn_mfma_f32_16x16x32_bf16(ca[i], fr, accI[i][j], 0, 0, 0);
        }
    }

    u16* yb = yp1 + ((size_t)b * LL + (size_t)c * CHUNK) * DINNER + h * HEADDIM;
    #pragma unroll
    for (int i = 0; i < 2; i++)
        #pragma unroll
        for (int r = 0; r < 4; r++) {
            int t = 16*i + kq*4 + r;
            float sct = dacl[w][t];
            #pragma unroll
            for (int j = 0; j < 4; j++)
                yb[(size_t)t * DINNER + 16*j + lrow] = f2bf(accI[i][j][r] * sct);
        }
}

// ------------- gated RMSNorm (yp0+yp1+xD)*silu(z), bf16 out ----------------
// R19: yp0/yp1 bf16. R21: convout and zx bf16.
__global__ __launch_bounds__(256) void gated_rms_kernel(
    const u16* __restrict__ yp0, const u16* __restrict__ yp1,
    const u16* __restrict__ convout, const u16* __restrict__ zx,
    const float* __restrict__ Dv, const float* __restrict__ norm_w,
    u16* __restrict__ gout)
{
    int bl = blockIdx.x;
    int c = threadIdx.x * 4;
    ushort4 y0 = *reinterpret_cast<const ushort4*>(yp0 + (size_t)bl * DINNER + c);
    ushort4 y1 = *reinterpret_cast<const ushort4*>(yp1 + (size_t)bl * DINNER + c);
    ushort4 xv = *reinterpret_cast<const ushort4*>(convout + (size_t)bl * CONVDIM + c);
    ushort4 zv = *reinterpret_cast<const ushort4*>(zx + (size_t)bl * NPROJ_PAD + c);
    float Dh = Dv[c >> 6];
    float g0 = (bf2f(y0.x) + bf2f(y1.x) + bf2f(xv.x) * Dh) * silu_f(bf2f(zv.x));
    float g1 = (bf2f(y0.y) + bf2f(y1.y) + bf2f(xv.y) * Dh) * silu_f(bf2f(zv.y));
    float g2 = (bf2f(y0.z) + bf2f(y1.z) + bf2f(xv.z) * Dh) * silu_f(bf2f(zv.z));
    float g3 = (bf2f(y0.w) + bf2f(y1.w) + bf2f(xv.w) * Dh) * silu_f(bf2f(zv.w));
    float tot = block_sum(g0 * g0 + g1 * g1 + g2 * g2 + g3 * g3);
    float sc = rsqrtf(tot * (1.f / DINNER) + 1e-5f);
    float4 nw = *reinterpret_cast<const float4*>(norm_w + c);
    ushort4 o;
    o.x = f2bf(g0 * sc * nw.x); o.y = f2bf(g1 * sc * nw.y);
    o.z = f2bf(g2 * sc * nw.z); o.w = f2bf(g3 * sc * nw.w);
    *reinterpret_cast<ushort4*>(gout + (size_t)bl * DINNER + c) = o;
}

// ---- residual + 4 split-K partials + RMSNorm (no weight), f32 out ---------
// R20: partials are bf16.
__global__ void residual_rms_sk_kernel(
    const float* __restrict__ a, const u16* __restrict__ pbuf,
    float* __restrict__ outf, int ncols, int rows)
{
    int row = blockIdx.x;
    int c = threadIdx.x * 4;
    size_t slice = (size_t)rows * ncols;
    size_t off = (size_t)row * ncols + c;
    float4 va = *reinterpret_cast<const float4*>(a + off);
    ushort4 p0 = *reinterpret_cast<const ushort4*>(pbuf + off);
    ushort4 p1 = *reinterpret_cast<const ushort4*>(pbuf + slice + off);
    ushort4 p2 = *reinterpret_cast<const ushort4*>(pbuf + 2 * slice + off);
    ushort4 p3 = *reinterpret_cast<const ushort4*>(pbuf + 3 * slice + off);
    float v0 = va.x + ((bf2f(p0.x) + bf2f(p1.x)) + (bf2f(p2.x) + bf2f(p3.x)));
    float v1 = va.y + ((bf2f(p0.y) + bf2f(p1.y)) + (bf2f(p2.y) + bf2f(p3.y)));
    float v2 = va.z + ((bf2f(p0.z) + bf2f(p1.z)) + (bf2f(p2.z) + bf2f(p3.z)));
    float v3 = va.w + ((bf2f(p0.w) + bf2f(p1.w)) + (bf2f(p2.w) + bf2f(p3.w)));
    float tot = block_sum(v0 * v0 + v1 * v1 + v2 * v2 + v3 * v3);
    float sc = rsqrtf(tot / (float)ncols + 1e-5f);
    float4 o; o.x = v0 * sc; o.y = v1 * sc; o.z = v2 * sc; o.w = v3 * sc;
    *reinterpret_cast<float4*>(outf + off) = o;
}

// ------------- transpose per batch: in (R,C) -> out (C,R), dual write ------
__global__ __launch_bounds__(256) void transpose_dual_kernel(
    const float* __restrict__ in, u16* __restrict__ outb,
    float* __restrict__ outf, int R, int C)
{
    __shared__ float tile[32][33];
    int b = blockIdx.z;
    int c0 = blockIdx.x * 32, r0 = blockIdx.y * 32;
    const float* ip = in + (size_t)b * R * C;
    for (int i = threadIdx.y; i < 32; i += 8)
        tile[i][threadIdx.x] = ip[(size_t)(r0 + i) * C + c0 + threadIdx.x];
    __syncthreads();
    size_t ob = (size_t)b * R * C;
    for (int i = threadIdx.y; i < 32; i += 8) {
        float v = tile[threadIdx.x][i];
        size_t oi = ob + (size_t)(c0 + i) * R + r0 + threadIdx.x;
        outf[oi] = v;
        outb[oi] = f2bf(v);
    }
}

// ---------------------------------------------------------------------------
extern "C" void kernel_launch(void* const* d_in, const int* in_sizes, int n_in,
                              void* d_out, int out_size, void* d_ws, size_t ws_size,
                              hipStream_t stream)
{
    const float* hid      = (const float*)d_in[0];
    const float* in_proj  = (const float*)d_in[1];
    const float* conv_w   = (const float*)d_in[2];
    const float* conv_b   = (const float*)d_in[3];
    const float* dt_bias  = (const float*)d_in[4];
    const float* A_log    = (const float*)d_in[5];
    const float* Dv       = (const float*)d_in[6];
    const float* norm_w   = (const float*)d_in[7];
    const float* out_proj = (const float*)d_in[8];
    const float* gu_t     = (const float*)d_in[9];
    const float* down_t   = (const float*)d_in[10];
    const float* gu_m     = (const float*)d_in[11];
    const float* down_m   = (const float*)d_in[12];
    float* outp = (float*)d_out;

    char* ws = (char*)d_ws;
    u16* bf        = (u16*)ws;
    u16* hid_bf    = bf;
    u16* w_inproj  = bf + HID_E;
    u16* w_outproj = w_inproj + INPROJ_P_E;
    u16* w_gut     = w_outproj + OUTPROJ_E;
    u16* w_downt   = w_gut + GUT_E;
    u16* w_gum     = w_downt + DOWNT_E;
    u16* w_downm   = w_gum + GUM_E;
    size_t o = (size_t)(CONV_TOT_E * 2);
    auto alloc = [&](size_t bytes) { size_t r = o; o = (o + bytes + 255) & ~(size_t)255; return r; };
    size_t dt_off  = alloc(4096 * 16 * 4);
    size_t g_off   = alloc((size_t)4096 * 1024 * 2);
    size_t h1_off  = alloc((size_t)4096 * 512 * 4);
    size_t Pt_off  = alloc(2048 * 4);
    // ---- MLP region (live step 8+); Sc/Sinit OVERLAY it (live steps 4-5).
    size_t xtb_off = alloc((size_t)2048 * 1024 * 2);
    size_t xtf_off = alloc((size_t)2048 * 1024 * 4);
    size_t act1_off= alloc((size_t)2048 * 2816 * 2);
    size_t x2_off  = alloc((size_t)2048 * 1024 * 4);
    size_t h2b_off = alloc((size_t)4096 * 512 * 2);
    size_t h2f_off = alloc((size_t)4096 * 512 * 4);
    size_t act2_off= alloc((size_t)4096 * 1536 * 2);
    size_t pad_off = alloc((size_t)10 * 1024 * 1024);
    size_t Sc_off  = xtb_off;                          // bf16: 16.78 MB
    size_t Si_off  = xtb_off + (size_t)8192 * 1024 * 4;// bf16: 16.78 MB
    (void)pad_off;
    size_t R_off   = o;
    size_t zx_off  = R_off;
    size_t cv_off  = zx_off + (size_t)4096 * NPROJ_PAD * 4;
    size_t y_off   = cv_off + (size_t)4096 * CONVDIM * 4;
    size_t sk_off  = R_off;

    u16*   zx      = (u16*)(ws + zx_off);            // bf16 (R21)
    u16*   convout = (u16*)(ws + cv_off);            // bf16 (R21)
    u16*   ybuf    = (u16*)(ws + y_off);             // yp0 (bf16, R19)
    float* dtbuf   = (float*)(ws + dt_off);
    u16*   g_bf    = (u16*)(ws + g_off);
    float* h1      = (float*)(ws + h1_off);
    u16*   xt_bf   = (u16*)(ws + xtb_off);
    float* xt_f    = (float*)(ws + xtf_off);
    u16*   act1    = (u16*)(ws + act1_off);
    float* x2      = (float*)(ws + x2_off);
    u16*   h2_bf   = (u16*)(ws + h2b_off);
    float* h2_f    = (float*)(ws + h2f_off);
    u16*   act2    = (u16*)(ws + act2_off);
    u16*   skbuf   = (u16*)(ws + sk_off);            // bf16 partials (R20)
    u16*   Sc      = (u16*)(ws + Sc_off);            // bf16; yp1 after combine
    u16*   Sinit   = (u16*)(ws + Si_off);            // bf16
    float* Ptot    = (float*)(ws + Pt_off);

    // 1) convert weights + hidden to bf16
    convert_all_kernel<<<14464, 256, 0, stream>>>(
        hid, in_proj, out_proj, gu_t, down_t, gu_m, down_m, bf);

    // 2) zxbcdt = hidden @ in_proj^T  (bf16 out, R21)
    gemm_bt<<<dim3(NPROJ_PAD / 128, 4096 / 128), 256, 0, stream>>>(
        hid_bf, w_inproj, zx, 4096, NPROJ_PAD, 512);

    // 3) conv + dt
    conv_dt_kernel<<<18688, 256, 0, stream>>>(zx, conv_w, conv_b, dt_bias, convout, dtbuf);

    // 4) MFMA chunk scan (all state bf16)
    scan_mfma1<<<512, 256, 0, stream>>>(convout, dtbuf, A_log, Sc, Ptot, ybuf);
    scan_combine<<<256, 256, 0, stream>>>(Sc, Ptot, Sinit);
    scan_mfma2<<<512, 256, 0, stream>>>(convout, dtbuf, A_log, Sinit, Sc);

    // 5) gated RMSNorm -> bf16
    gated_rms_kernel<<<4096, 256, 0, stream>>>(ybuf, Sc, convout, zx, Dv, norm_w, g_bf);

    // 6) out_proj GEMM, split-K x4 -> bf16 partials in skbuf
    gemm_bt_sk<<<dim3(512 / 128, 4096 / 128, 4), 256, 0, stream>>>(
        g_bf, w_outproj, skbuf, 4096, 512, 1024, 256);

    // 7) h1 = rms(hidden + sum partials)
    residual_rms_sk_kernel<<<4096, 128, 0, stream>>>(hid, skbuf, h1, 512, 4096);

    // 8) transpose (B,1024,512) -> (B,512,1024)
    transpose_dual_kernel<<<dim3(16, 32, 4), dim3(32, 8), 0, stream>>>(h1, xt_bf, xt_f, 1024, 512);

    // 9) token MLP fused: act1 = swiglu(xt @ gu_t^T)  (704 blocks, 128x64)
    gemm_swiglu<<<dim3(INTER_T / 64, 2048 / 128), 256, 0, stream>>>(
        xt_bf, w_gut, act1, 2048, INTER_T, 1024);

    // 10) down_t GEMM, split-K x4 -> bf16 partials in skbuf
    gemm_bt_sk<<<dim3(1024 / 128, 2048 / 128, 4), 256, 0, stream>>>(
        act1, w_downt, skbuf, 2048, 1024, 2816, 704);

    // 11) x2 = rms(xt_f + sum partials)
    residual_rms_sk_kernel<<<2048, 256, 0, stream>>>(xt_f, skbuf, x2, 1024, 2048);

    // 12) transpose back (B,512,1024) -> (B,1024,512)
    transpose_dual_kernel<<<dim3(32, 16, 4), dim3(32, 8), 0, stream>>>(x2, h2_bf, h2_f, 512, 1024);

    // 13) channel MLP fused: act2 = swiglu(h2 @ gu_m^T)  (768 blocks, 128x64)
    gemm_swiglu<<<dim3(INTER_M / 64, 4096 / 128), 256, 0, stream>>>(
        h2_bf, w_gum, act2, 4096, INTER_M, 512);

    // 14) down_m GEMM, split-K x4 -> bf16 partials in skbuf
    gemm_bt_sk<<<dim3(512 / 128, 4096 / 128, 4), 256, 0, stream>>>(
        act2, w_downm, skbuf, 4096, 512, 1536, 384);

    // 15) out = rms(h2_f + sum partials)
    residual_rms_sk_kernel<<<4096, 128, 0, stream>>>(h2_f, skbuf, outp, 512, 4096);
}

// Round 7
// 308.765 us; speedup vs baseline: 1.1192x; 1.0300x over previous
//
#include <hip/hip_runtime.h>

// ---------------------------------------------------------------------------
// Mamba2 hybrid block. GEMMs: bf16 MFMA 16x16x32, f32 accumulate, m97-style
// global_load_lds(16B) staging, BK=64. 3-bit XOR chunk swizzle keeps frag
// reads 2-way/free. Small-N GEMMs use split-K x4 into bf16 partial buffers;
// partials summed in residual_rms. MLP gu-GEMMs fuse SwiGLU (128x64 tile).
// Scan: MFMA chunked.
// R16: scan_mfma1 4 heads/block shared B/C staging (-14.1 us, 355.5->341.4).
// R17/R18: scan_mfma2 4 heads/block + scan_combine unroll: NEUTRAL.
// R19: bf16 scan state (Sc/Sinit/yp0/yp1): -17.4 us (345.6->328.2).
// R20: bf16 split-K partials (-8.6 us, 328.2->319.6).
// R21: bf16 zx + convout: only -1.6 us (318.0) — that traffic was L2/L3-
// resident (1-kernel producer->consumer distance). Lesson: bf16-ing pays only
// when the round-trip reaches HBM or a saturated cache level.
// R22: bf16 residual trunk. h1/xt/x2/h2 f32 copies (67 MB round-trip, multi-
// kernel lifetimes) -> bf16; transposes become bf16->bf16 single-write.
// One extra 2^-9 rounding on O(1) post-norm values. Last traffic lever;
// if <3 us, remaining levers are GEMM-structural only.
// ---------------------------------------------------------------------------

#define BB 4
#define LL 1024
#define DMODEL 512
#define DINNER 1024
#define NHEADS 16
#define HEADDIM 64
#define DSTATE 64
#define CONVDIM 1152        // DINNER + 2*DSTATE
#define NPROJ 2192          // D_IN_PROJ
#define NPROJ_PAD 2304      // padded to multiple of 128
#define INTER_T 2816
#define INTER_M 1536
#define NCHUNK 32
#define CHUNK 32

typedef __bf16 bf16x8 __attribute__((ext_vector_type(8)));
typedef float  f32x4  __attribute__((ext_vector_type(4)));
typedef unsigned short u16;
typedef unsigned int   u32;
typedef unsigned short u16x8 __attribute__((ext_vector_type(8)));

__device__ __forceinline__ u16 f2bf(float x) {
    union { float f; u32 u; } v; v.f = x;
    u32 u = v.u;
    return (u16)((u + 0x7fffu + ((u >> 16) & 1u)) >> 16);
}
__device__ __forceinline__ float silu_f(float x) {
    return x / (1.f + __expf(-x));
}
__device__ __forceinline__ float bf2f(u16 w) {
    union { u32 u; float f; } a; a.u = ((u32)w) << 16; return a.f;
}

// C-store helpers: f32 passthrough or bf16 round (R20/R21)
__device__ __forceinline__ void cstore(float* p, float v) { *p = v; }
__device__ __forceinline__ void cstore(u16*   p, float v) { *p = f2bf(v); }

// async global->LDS, 16B per lane; LDS dest is wave-uniform base + lane*16
__device__ __forceinline__ void gld_lds16(const u16* g, u16* l) {
    __builtin_amdgcn_global_load_lds(
        (const __attribute__((address_space(1))) unsigned int*)g,
        (__attribute__((address_space(3))) unsigned int*)l, 16, 0, 0);
}

// --------------------------- block-wide sum --------------------------------
__device__ __forceinline__ float block_sum(float v) {
    #pragma unroll
    for (int off = 32; off > 0; off >>= 1) v += __shfl_xor(v, off, 64);
    __shared__ float red[4];
    int w = threadIdx.x >> 6;
    int nwv = blockDim.x >> 6;
    if ((threadIdx.x & 63) == 0) red[w] = v;
    __syncthreads();
    float tot = red[0];
    for (int i = 1; i < nwv; i++) tot += red[i];
    return tot;
}

// --------------------- f32 -> bf16 convert (all weights + hidden) ----------
#define HID_E      2097152LL   // 4096*512
#define INPROJ_P_E 1179648LL   // 2304*512
#define INPROJ_S_E 1122304LL   // 2192*512
#define OUTPROJ_E   524288LL   // 512*1024
#define GUT_E      5767168LL   // 5632*1024
#define DOWNT_E    2883584LL   // 1024*2816
#define GUM_E      1572864LL   // 3072*512
#define DOWNM_E     786432LL   // 512*1536
#define CONV_TOT_E 14811136LL

__global__ __launch_bounds__(256) void convert_all_kernel(
    const float* __restrict__ s_hid, const float* __restrict__ s_inproj,
    const float* __restrict__ s_outproj, const float* __restrict__ s_gut,
    const float* __restrict__ s_downt, const float* __restrict__ s_gum,
    const float* __restrict__ s_downm, u16* __restrict__ dst)
{
    long long idx = (long long)blockIdx.x * 256 + threadIdx.x;
    long long e = idx * 4;
    if (e >= CONV_TOT_E) return;
    const float* src; long long off, nsrc;
    long long c0 = HID_E;
    long long c1 = c0 + INPROJ_P_E;
    long long c2 = c1 + OUTPROJ_E;
    long long c3 = c2 + GUT_E;
    long long c4 = c3 + DOWNT_E;
    long long c5 = c4 + GUM_E;
    if      (e < c0) { src = s_hid;     off = e;      nsrc = HID_E; }
    else if (e < c1) { src = s_inproj;  off = e - c0; nsrc = INPROJ_S_E; }
    else if (e < c2) { src = s_outproj; off = e - c1; nsrc = OUTPROJ_E; }
    else if (e < c3) { src = s_gut;     off = e - c2; nsrc = GUT_E; }
    else if (e < c4) { src = s_downt;   off = e - c3; nsrc = DOWNT_E; }
    else if (e < c5) { src = s_gum;     off = e - c4; nsrc = GUM_E; }
    else             { src = s_downm;   off = e - c5; nsrc = DOWNM_E; }
    ushort4 r;
    if (off < nsrc) {
        float4 v = *reinterpret_cast<const float4*>(src + off);
        r.x = f2bf(v.x); r.y = f2bf(v.y); r.z = f2bf(v.z); r.w = f2bf(v.w);
    } else {
        r.x = 0; r.y = 0; r.z = 0; r.w = 0;
    }
    *reinterpret_cast<ushort4*>(dst + e) = r;
}

// ----------------------------- bf16 MFMA GEMM (BK=64) ----------------------
// C[M,N] = A[M,K] * W[N,K]^T. 128x128 tile, 4 waves of 64x64 (4x4 MFMAs).
// R20/R21: CT templates the C dtype (f32 or bf16).
template<bool SK, typename CT>
__device__ __forceinline__ void gemm_bt_body(
    const u16* __restrict__ A, const u16* __restrict__ W,
    CT* __restrict__ C, int M, int N, int K, int kLen)
{
    __shared__ u16 As[128 * 64];   // 16 KB
    __shared__ u16 Bs[128 * 64];   // 16 KB
    int tid = threadIdx.x;
    int m0 = blockIdx.y * 128, n0 = blockIdx.x * 128;
    int kBase = SK ? blockIdx.z * kLen : 0;
    CT* Cw = SK ? C + (size_t)blockIdx.z * M * N : C;
    int wave = tid >> 6, lane = tid & 63;
    int wm = (wave >> 1) * 64, wn = (wave & 1) * 64;
    int lrow = lane & 15;
    int kq = lane >> 4;
    int kx = lrow & 7;

    int rL = lane >> 3, cL = lane & 7;
    int cG = cL ^ rL;
    const u16* gA[4]; const u16* gB[4];
    u16 *lA[4], *lB[4];
    #pragma unroll
    for (int i = 0; i < 4; i++) {
        int r = wave * 32 + i * 8;
        gA[i] = A + (size_t)(m0 + r + rL) * K + kBase + cG * 8;
        gB[i] = W + (size_t)(n0 + r + rL) * K + kBase + cG * 8;
        lA[i] = &As[r * 64];
        lB[i] = &Bs[r * 64];
    }

    f32x4 acc[4][4];
    #pragma unroll
    for (int i = 0; i < 4; i++)
        #pragma unroll
        for (int j = 0; j < 4; j++) {
            acc[i][j][0] = 0.f; acc[i][j][1] = 0.f;
            acc[i][j][2] = 0.f; acc[i][j][3] = 0.f;
        }

    for (int kt = 0; kt < kLen; kt += 64) {
        __syncthreads();
        #pragma unroll
        for (int i = 0; i < 4; i++) {
            gld_lds16(gA[i] + kt, lA[i]);
            gld_lds16(gB[i] + kt, lB[i]);
        }
        __syncthreads();
        #pragma unroll
        for (int ks = 0; ks < 2; ks++) {
            int ko = (((ks * 4 + kq) ^ kx) * 8);
            bf16x8 af[4], bfr[4];
            #pragma unroll
            for (int i = 0; i < 4; i++) {
                af[i]  = *reinterpret_cast<const bf16x8*>(&As[(wm + i * 16 + lrow) * 64 + ko]);
                bfr[i] = *reinterpret_cast<const bf16x8*>(&Bs[(wn + i * 16 + lrow) * 64 + ko]);
            }
            #pragma unroll
            for (int i = 0; i < 4; i++)
                #pragma unroll
                for (int j = 0; j < 4; j++)
                    acc[i][j] = __builtin_amdgcn_mfma_f32_16x16x32_bf16(af[i], bfr[j], acc[i][j], 0, 0, 0);
        }
    }

    // C/D layout: col = lane&15, row = (lane>>4)*4 + reg
    int rbase = m0 + wm + kq * 4;
    int cbase = n0 + wn + lrow;
    #pragma unroll
    for (int i = 0; i < 4; i++)
        #pragma unroll
        for (int j = 0; j < 4; j++)
            #pragma unroll
            for (int r = 0; r < 4; r++)
                cstore(&Cw[(size_t)(rbase + i * 16 + r) * N + cbase + j * 16], acc[i][j][r]);
}

// R21: in_proj GEMM emits bf16 zx
__global__ __launch_bounds__(256) void gemm_bt(
    const u16* __restrict__ A, const u16* __restrict__ W,
    u16* __restrict__ C, int M, int N, int K)
{
    gemm_bt_body<false, u16>(A, W, C, M, N, K, K);
}

__global__ __launch_bounds__(256) void gemm_bt_sk(
    const u16* __restrict__ A, const u16* __restrict__ W,
    u16* __restrict__ C, int M, int N, int K, int kLen)
{
    gemm_bt_body<true, u16>(A, W, C, M, N, K, kLen);
}

// --------------- fused gate/up GEMM + SwiGLU (128x64, BK=64) ---------------
// act[M,inter] = silu(A·Wg^T) * (A·Wu^T). Bs rows 0..63 = gate, 64..127 = up.
__global__ __launch_bounds__(256) void gemm_swiglu(
    const u16* __restrict__ A, const u16* __restrict__ W,
    u16* __restrict__ act, int M, int inter, int K)
{
    __shared__ u16 As[128 * 64];   // 16 KB
    __shared__ u16 Bs[128 * 64];   // 16 KB
    int tid = threadIdx.x;
    int m0 = blockIdx.y * 128, n0 = blockIdx.x * 64;
    int wave = tid >> 6, lane = tid & 63;
    int wm = (wave >> 1) * 64, wn = (wave & 1) * 32;
    int lrow = lane & 15;
    int kq = lane >> 4;
    int kx = lrow & 7;

    int rL = lane >> 3, cL = lane & 7;
    int cG = cL ^ rL;
    const u16* gA[4]; const u16* gB[4];
    u16 *lA[4], *lB[4];
    #pragma unroll
    for (int i = 0; i < 4; i++) {
        int r = wave * 32 + i * 8;
        gA[i] = A + (size_t)(m0 + r + rL) * K + cG * 8;
        lA[i] = &As[r * 64];
        int rB = r;   // combined index: 0..63 gate, 64..127 up (per wave 32)
        int grow = (rB < 64) ? (n0 + rB + rL)
                             : (inter + n0 + rB - 64 + rL);
        gB[i] = W + (size_t)grow * K + cG * 8;
        lB[i] = &Bs[rB * 64];
    }

    f32x4 accg[4][2], accu[4][2];
    #pragma unroll
    for (int i = 0; i < 4; i++)
        #pragma unroll
        for (int j = 0; j < 2; j++) {
            accg[i][j][0]=0.f; accg[i][j][1]=0.f; accg[i][j][2]=0.f; accg[i][j][3]=0.f;
            accu[i][j][0]=0.f; accu[i][j][1]=0.f; accu[i][j][2]=0.f; accu[i][j][3]=0.f;
        }

    for (int kt = 0; kt < K; kt += 64) {
        __syncthreads();
        #pragma unroll
        for (int i = 0; i < 4; i++) {
            gld_lds16(gA[i] + kt, lA[i]);
            gld_lds16(gB[i] + kt, lB[i]);
        }
        __syncthreads();
        #pragma unroll
        for (int ks = 0; ks < 2; ks++) {
            int ko = (((ks * 4 + kq) ^ kx) * 8);
            bf16x8 af[4], bg[2], bu[2];
            #pragma unroll
            for (int i = 0; i < 4; i++)
                af[i] = *reinterpret_cast<const bf16x8*>(&As[(wm + i * 16 + lrow) * 64 + ko]);
            #pragma unroll
            for (int j = 0; j < 2; j++) {
                bg[j] = *reinterpret_cast<const bf16x8*>(&Bs[(wn + j * 16 + lrow) * 64 + ko]);
                bu[j] = *reinterpret_cast<const bf16x8*>(&Bs[(64 + wn + j * 16 + lrow) * 64 + ko]);
            }
            #pragma unroll
            for (int i = 0; i < 4; i++)
                #pragma unroll
                for (int j = 0; j < 2; j++) {
                    accg[i][j] = __builtin_amdgcn_mfma_f32_16x16x32_bf16(af[i], bg[j], accg[i][j], 0, 0, 0);
                    accu[i][j] = __builtin_amdgcn_mfma_f32_16x16x32_bf16(af[i], bu[j], accu[i][j], 0, 0, 0);
                }
        }
    }

    int rbase = m0 + wm + kq * 4;
    int cbase = n0 + wn + lrow;
    #pragma unroll
    for (int i = 0; i < 4; i++)
        #pragma unroll
        for (int j = 0; j < 2; j++)
            #pragma unroll
            for (int r = 0; r < 4; r++) {
                float g = accg[i][j][r], u = accu[i][j][r];
                act[(size_t)(rbase + i * 16 + r) * inter + cbase + j * 16] =
                    f2bf(silu_f(g) * u);
            }
}

// ----------------- conv (depthwise, causal, width 4) + dt ------------------
// R21: zx and convout are bf16; accumulate in f32.
__global__ __launch_bounds__(256) void conv_dt_kernel(
    const u16* __restrict__ zx, const float* __restrict__ conv_w,
    const float* __restrict__ conv_b, const float* __restrict__ dt_bias,
    u16* __restrict__ convout, float* __restrict__ dtbuf)
{
    int idx = blockIdx.x * 256 + threadIdx.x;   // over 4096*1168
    int bl = idx / 1168;
    int c  = idx - bl * 1168;
    int l  = bl & (LL - 1);
    if (c < CONVDIM) {
        const u16* col = zx + (size_t)bl * NPROJ_PAD + DINNER + c;
        float acc = conv_b[c];
        #pragma unroll
        for (int i = 0; i < 4; i++) {
            int lt = l - 3 + i;
            float v = (lt >= 0) ? bf2f(col[(long long)(lt - l) * NPROJ_PAD]) : 0.f;
            acc = fmaf(v, conv_w[c * 4 + i], acc);
        }
        convout[(size_t)bl * CONVDIM + c] = f2bf(silu_f(acc));
    } else {
        int h = c - CONVDIM;
        float v = bf2f(zx[(size_t)bl * NPROJ_PAD + 2176 + h]) + dt_bias[h];
        float sp = (v > 20.f) ? v : log1pf(__expf(v));
        dtbuf[(size_t)bl * NHEADS + h] = sp;
    }
}

// -------------------- MFMA chunk scan: pass 1 ------------------------------
__global__ __launch_bounds__(256) void scan_mfma1(
    const u16* __restrict__ convout, const float* __restrict__ dtbuf,
    const float* __restrict__ A_log, u16* __restrict__ Sc,
    float* __restrict__ Ptot, u16* __restrict__ yp0)
{
    __shared__ u16 Blds[32 * 72];        // raw B bf16 [t][n] (shared)
    __shared__ u16 Clds[32 * 72];        // raw C bf16 [t][n] (shared)
    __shared__ u16 Xt[4][64 * 40];       // x^T bf16 [p][t] (per head)
    __shared__ u16 Bht[4][64 * 40];      // (w_t*dt_t*B)^T bf16 [n][t]
    __shared__ u16 Wlds[4][32 * 40];     // W bf16 [t][t']
    __shared__ float dtl[4][32], cuml[4][32], warr[4][32];

    int blk = blockIdx.x;                // 512 = (b*4 + hq)*32 + c
    int c   = blk & 31;
    int bg  = blk >> 5;
    int b   = bg >> 2;
    int hq  = bg & 3;
    int tid = threadIdx.x;
    int w    = tid >> 6;                 // wave = head within quad
    int lane = tid & 63;
    int h   = hq * 4 + w;
    int bh  = b * 16 + h;
    int lrow = lane & 15, kq = lane >> 4;
    size_t base = ((size_t)b * LL + (size_t)c * CHUNK) * CONVDIM;
    float Ah = -__expf(A_log[h]);

    if (lane < 32)
        dtl[w][lane] = dtbuf[((size_t)b * LL + (size_t)c * CHUNK + lane) * NHEADS + h];
    // shared B/C staging: 32 t x 16 chunks of 8 bf16; 256 thr -> 2 iters
    #pragma unroll
    for (int it = 0; it < 2; ++it) {
        int idx = it * 256 + tid;
        int t = idx >> 4, q = idx & 15;
        u16x8 v = *reinterpret_cast<const u16x8*>(
            &convout[base + (size_t)t * CONVDIM + DINNER + q * 8]);
        if (q < 8) *reinterpret_cast<u16x8*>(&Blds[t * 72 + q * 8]) = v;
        else       *reinterpret_cast<u16x8*>(&Clds[t * 72 + (q - 8) * 8]) = v;
    }
    #pragma unroll
    for (int t = 0; t < 32; ++t)
        Xt[w][lane * 40 + t] = convout[base + (size_t)t * CONVDIM + h * HEADDIM + lane];
    __syncthreads();

    float s_inc = 0.f, s_all = 0.f;
    #pragma unroll
    for (int j = 0; j < 32; ++j) {
        float v = dtl[w][j];
        s_all += v;
        if (j <= lane) s_inc += v;
    }
    if (lane < 32) {
        cuml[w][lane] = s_inc;
        warr[w][lane] = __expf(Ah * (s_all - s_inc)) * dtl[w][lane];
    }
    float cumTot = s_all;
    __syncthreads();

    #pragma unroll
    for (int t = 0; t < 32; ++t)
        Bht[w][lane * 40 + t] = f2bf(warr[w][t] * bf2f(Blds[t * 72 + lane]));

    f32x4 accG[2][2];
    #pragma unroll
    for (int i = 0; i < 2; i++)
        #pragma unroll
        for (int j = 0; j < 2; j++) {
            accG[i][j][0]=0.f; accG[i][j][1]=0.f; accG[i][j][2]=0.f; accG[i][j][3]=0.f;
        }
    #pragma unroll
    for (int ks = 0; ks < 2; ++ks) {
        bf16x8 af[2], bfr[2];
        #pragma unroll
        for (int i = 0; i < 2; i++) {
            af[i]  = *reinterpret_cast<const bf16x8*>(&Clds[(16*i + lrow) * 72 + ks*32 + kq*8]);
            bfr[i] = *reinterpret_cast<const bf16x8*>(&Blds[(16*i + lrow) * 72 + ks*32 + kq*8]);
        }
        #pragma unroll
        for (int i = 0; i < 2; i++)
            #pragma unroll
            for (int j = 0; j < 2; j++)
                accG[i][j] = __builtin_amdgcn_mfma_f32_16x16x32_bf16(af[i], bfr[j], accG[i][j], 0, 0, 0);
    }

    float ctp0 = cuml[w][lrow],      dtp0 = dtl[w][lrow];
    float ctp1 = cuml[w][16 + lrow], dtp1 = dtl[w][16 + lrow];
    #pragma unroll
    for (int i = 0; i < 2; i++)
        #pragma unroll
        for (int r = 0; r < 4; r++) {
            int t = 16*i + kq*4 + r;
            float ct = cuml[w][t];
            #pragma unroll
            for (int j = 0; j < 2; j++) {
                int tp = 16*j + lrow;
                float ctp = j ? ctp1 : ctp0;
                float dtp = j ? dtp1 : dtp0;
                float g = accG[i][j][r];
                float wv = (tp <= t) ? __expf(Ah * (ct - ctp)) * dtp * g : 0.f;
                Wlds[w][t * 40 + tp] = f2bf(wv);
            }
        }
    __syncthreads();

    bf16x8 xf[4];
    #pragma unroll
    for (int j = 0; j < 4; j++)
        xf[j] = *reinterpret_cast<const bf16x8*>(&Xt[w][(16*j + lrow) * 40 + kq*8]);
    f32x4 accY[2][4];
    #pragma unroll
    for (int i = 0; i < 2; i++) {
        bf16x8 wf = *reinterpret_cast<const bf16x8*>(&Wlds[w][(16*i + lrow) * 40 + kq*8]);
        #pragma unroll
        for (int j = 0; j < 4; j++) {
            accY[i][j][0]=0.f; accY[i][j][1]=0.f; accY[i][j][2]=0.f; accY[i][j][3]=0.f;
            accY[i][j] = __builtin_amdgcn_mfma_f32_16x16x32_bf16(wf, xf[j], accY[i][j], 0, 0, 0);
        }
    }

    f32x4 accS[4][4];
    #pragma unroll
    for (int j = 0; j < 4; j++) {
        bf16x8 bb = *reinterpret_cast<const bf16x8*>(&Bht[w][(16*j + lrow) * 40 + kq*8]);
        #pragma unroll
        for (int i = 0; i < 4; i++) {
            accS[i][j][0]=0.f; accS[i][j][1]=0.f; accS[i][j][2]=0.f; accS[i][j][3]=0.f;
            accS[i][j] = __builtin_amdgcn_mfma_f32_16x16x32_bf16(xf[i], bb, accS[i][j], 0, 0, 0);
        }
    }

    u16* yb = yp0 + ((size_t)b * LL + (size_t)c * CHUNK) * DINNER + h * HEADDIM;
    #pragma unroll
    for (int i = 0; i < 2; i++)
        #pragma unroll
        for (int r = 0; r < 4; r++) {
            int t = 16*i + kq*4 + r;
            #pragma unroll
            for (int j = 0; j < 4; j++)
                yb[(size_t)t * DINNER + 16*j + lrow] = f2bf(accY[i][j][r]);
        }
    #pragma unroll
    for (int i = 0; i < 4; i++)
        #pragma unroll
        for (int r = 0; r < 4; r++) {
            int p = 16*i + kq*4 + r;
            #pragma unroll
            for (int j = 0; j < 4; j++)
                Sc[((size_t)(bh * 4 + j) * NCHUNK + c) * 1024 + p * 16 + lrow] = f2bf(accS[i][j][r]);
        }
    if (lane == 0) Ptot[bh * NCHUNK + c] = __expf(Ah * cumTot);
}

// ----------------------- chunked SSM scan: combine -------------------------
__global__ __launch_bounds__(256) void scan_combine(
    const u16* __restrict__ Sc, const float* __restrict__ Ptot,
    u16* __restrict__ Sinit)
{
    int blk = blockIdx.x;             // 256 = bh*4 + n-quarter
    int bh = blk >> 2;
    int tid = threadIdx.x;
    int p = tid >> 2;                 // 0..63
    int ncol = (tid & 3) * 4;         // 4 elems of the 16-wide n slice
    float Pv[NCHUNK];
    #pragma unroll
    for (int c = 0; c < NCHUNK; ++c) Pv[c] = Ptot[bh * NCHUNK + c];
    float4 carry; carry.x = 0.f; carry.y = 0.f; carry.z = 0.f; carry.w = 0.f;
    size_t rowbase = (size_t)blk * NCHUNK * 1024 + p * 16 + ncol;
    #pragma unroll
    for (int c = 0; c < NCHUNK; ++c) {
        size_t row = rowbase + (size_t)c * 1024;
        ushort4 o;
        o.x = f2bf(carry.x); o.y = f2bf(carry.y);
        o.z = f2bf(carry.z); o.w = f2bf(carry.w);
        *reinterpret_cast<ushort4*>(Sinit + row) = o;
        ushort4 si = *reinterpret_cast<const ushort4*>(Sc + row);
        carry.x = fmaf(carry.x, Pv[c], bf2f(si.x));
        carry.y = fmaf(carry.y, Pv[c], bf2f(si.y));
        carry.z = fmaf(carry.z, Pv[c], bf2f(si.z));
        carry.w = fmaf(carry.w, Pv[c], bf2f(si.w));
    }
}

// -------------------- MFMA chunk scan: pass 2 ------------------------------
__global__ __launch_bounds__(256) void scan_mfma2(
    const u16* __restrict__ convout, const float* __restrict__ dtbuf,
    const float* __restrict__ A_log, const u16* __restrict__ Sinit,
    u16* __restrict__ yp1)
{
    __shared__ u16 Clds2[32 * 72];       // raw C bf16 [t][n] (shared)
    __shared__ float dtl[4][32], dacl[4][32];
    int blk = blockIdx.x;                // 512 = (b*4 + hq)*32 + c
    int c   = blk & 31;
    int bg  = blk >> 5;
    int b   = bg >> 2;
    int hq  = bg & 3;
    int tid = threadIdx.x;
    int w    = tid >> 6;                 // wave = head within quad
    int lane = tid & 63;
    int h   = hq * 4 + w;
    int bh  = b * 16 + h;
    int lrow = lane & 15, kq = lane >> 4;
    size_t base = ((size_t)b * LL + (size_t)c * CHUNK) * CONVDIM;
    float Ah = -__expf(A_log[h]);

    if (lane < 32)
        dtl[w][lane] = dtbuf[((size_t)b * LL + (size_t)c * CHUNK + lane) * NHEADS + h];
    // shared raw-C staging: 32 t x 8 chunks of 8 bf16 = 256 thr x 1 iter
    {
        int t = tid >> 3, q = tid & 7;
        u16x8 v = *reinterpret_cast<const u16x8*>(
            &convout[base + (size_t)t * CONVDIM + DINNER + DSTATE + q * 8]);
        *reinterpret_cast<u16x8*>(&Clds2[t * 72 + q * 8]) = v;
    }
    __syncthreads();

    float s_inc = 0.f;
    #pragma unroll
    for (int j = 0; j < 32; ++j) {
        float v = dtl[w][j];
        if (j <= lane) s_inc += v;
    }
    if (lane < 32) dacl[w][lane] = __expf(Ah * s_inc);

    f32x4 accI[2][4];
    #pragma unroll
    for (int i = 0; i < 2; i++)
        #pragma unroll
        for (int j = 0; j < 4; j++) {
            accI[i][j][0]=0.f; accI[i][j][1]=0.f; accI[i][j][2]=0.f; accI[i][j][3]=0.f;
        }
    #pragma unroll
    for (int ks = 0; ks < 2; ++ks) {
        bf16x8 ca[2];
        #pragma unroll
        for (int i = 0; i < 2; i++)
            ca[i] = *reinterpret_cast<const bf16x8*>(&Clds2[(16*i + lrow) * 72 + ks*32 + kq*8]);
        int nq = ks * 2 + (kq >> 1);
        int off = (kq & 1) * 8;
        #pragma unroll
        for (int j = 0; j < 4; j++) {
            int p = 16*j + lrow;
            const u16* sp = Sinit + ((size_t)(bh * 4 + nq) * NCHUNK + c) * 1024 + p * 16 + off;
            bf16x8 fr = *reinterpret_cast<const bf16x8*>(sp);
            #pragma unroll
            for (int i = 0; i < 2; i++)
                accI[i][j] = __builtin_amdgcn_mfma_f32_16x16x32_bf16(ca[i], fr, accI[i][j], 0, 0, 0);
        }
    }

    u16* yb = yp1 + ((size_t)b * LL + (size_t)c * CHUNK) * DINNER + h * HEADDIM;
    #pragma unroll
    for (int i = 0; i < 2; i++)
        #pragma unroll
        for (int r = 0; r < 4; r++) {
            int t = 16*i + kq*4 + r;
            float sct = dacl[w][t];
            #pragma unroll
            for (int j = 0; j < 4; j++)
                yb[(size_t)t * DINNER + 16*j + lrow] = f2bf(accI[i][j][r] * sct);
        }
}

// ------------- gated RMSNorm (yp0+yp1+xD)*silu(z), bf16 out ----------------
__global__ __launch_bounds__(256) void gated_rms_kernel(
    const u16* __restrict__ yp0, const u16* __restrict__ yp1,
    const u16* __restrict__ convout, const u16* __restrict__ zx,
    const float* __restrict__ Dv, const float* __restrict__ norm_w,
    u16* __restrict__ gout)
{
    int bl = blockIdx.x;
    int c = threadIdx.x * 4;
    ushort4 y0 = *reinterpret_cast<const ushort4*>(yp0 + (size_t)bl * DINNER + c);
    ushort4 y1 = *reinterpret_cast<const ushort4*>(yp1 + (size_t)bl * DINNER + c);
    ushort4 xv = *reinterpret_cast<const ushort4*>(convout + (size_t)bl * CONVDIM + c);
    ushort4 zv = *reinterpret_cast<const ushort4*>(zx + (size_t)bl * NPROJ_PAD + c);
    float Dh = Dv[c >> 6];
    float g0 = (bf2f(y0.x) + bf2f(y1.x) + bf2f(xv.x) * Dh) * silu_f(bf2f(zv.x));
    float g1 = (bf2f(y0.y) + bf2f(y1.y) + bf2f(xv.y) * Dh) * silu_f(bf2f(zv.y));
    float g2 = (bf2f(y0.z) + bf2f(y1.z) + bf2f(xv.z) * Dh) * silu_f(bf2f(zv.z));
    float g3 = (bf2f(y0.w) + bf2f(y1.w) + bf2f(xv.w) * Dh) * silu_f(bf2f(zv.w));
    float tot = block_sum(g0 * g0 + g1 * g1 + g2 * g2 + g3 * g3);
    float sc = rsqrtf(tot * (1.f / DINNER) + 1e-5f);
    float4 nw = *reinterpret_cast<const float4*>(norm_w + c);
    ushort4 o;
    o.x = f2bf(g0 * sc * nw.x); o.y = f2bf(g1 * sc * nw.y);
    o.z = f2bf(g2 * sc * nw.z); o.w = f2bf(g3 * sc * nw.w);
    *reinterpret_cast<ushort4*>(gout + (size_t)bl * DINNER + c) = o;
}

// ---- residual + 4 split-K partials + RMSNorm (no weight) ------------------
// R20: partials bf16. R22: residual base and output templated (f32 or bf16).
template<typename AT, typename OT>
__device__ __forceinline__ void residual_rms_body(
    const AT* __restrict__ a, const u16* __restrict__ pbuf,
    OT* __restrict__ outf, int ncols, int rows)
{
    int row = blockIdx.x;
    int c = threadIdx.x * 4;
    size_t slice = (size_t)rows * ncols;
    size_t off = (size_t)row * ncols + c;
    float va0, va1, va2, va3;
    if constexpr (sizeof(AT) == 4) {
        float4 t = *reinterpret_cast<const float4*>((const float*)a + off);
        va0 = t.x; va1 = t.y; va2 = t.z; va3 = t.w;
    } else {
        ushort4 t = *reinterpret_cast<const ushort4*>((const u16*)a + off);
        va0 = bf2f(t.x); va1 = bf2f(t.y); va2 = bf2f(t.z); va3 = bf2f(t.w);
    }
    ushort4 p0 = *reinterpret_cast<const ushort4*>(pbuf + off);
    ushort4 p1 = *reinterpret_cast<const ushort4*>(pbuf + slice + off);
    ushort4 p2 = *reinterpret_cast<const ushort4*>(pbuf + 2 * slice + off);
    ushort4 p3 = *reinterpret_cast<const ushort4*>(pbuf + 3 * slice + off);
    float v0 = va0 + ((bf2f(p0.x) + bf2f(p1.x)) + (bf2f(p2.x) + bf2f(p3.x)));
    float v1 = va1 + ((bf2f(p0.y) + bf2f(p1.y)) + (bf2f(p2.y) + bf2f(p3.y)));
    float v2 = va2 + ((bf2f(p0.z) + bf2f(p1.z)) + (bf2f(p2.z) + bf2f(p3.z)));
    float v3 = va3 + ((bf2f(p0.w) + bf2f(p1.w)) + (bf2f(p2.w) + bf2f(p3.w)));
    float tot = block_sum(v0 * v0 + v1 * v1 + v2 * v2 + v3 * v3);
    float sc = rsqrtf(tot / (float)ncols + 1e-5f);
    if constexpr (sizeof(OT) == 4) {
        float4 o; o.x = v0 * sc; o.y = v1 * sc; o.z = v2 * sc; o.w = v3 * sc;
        *reinterpret_cast<float4*>((float*)outf + off) = o;
    } else {
        ushort4 o;
        o.x = f2bf(v0 * sc); o.y = f2bf(v1 * sc);
        o.z = f2bf(v2 * sc); o.w = f2bf(v3 * sc);
        *reinterpret_cast<ushort4*>((u16*)outf + off) = o;
    }
}

__global__ void residual_rms_f2b(const float* __restrict__ a,
    const u16* __restrict__ pbuf, u16* __restrict__ o, int ncols, int rows)
{ residual_rms_body<float, u16>(a, pbuf, o, ncols, rows); }

__global__ void residual_rms_b2b(const u16* __restrict__ a,
    const u16* __restrict__ pbuf, u16* __restrict__ o, int ncols, int rows)
{ residual_rms_body<u16, u16>(a, pbuf, o, ncols, rows); }

__global__ void residual_rms_b2f(const u16* __restrict__ a,
    const u16* __restrict__ pbuf, float* __restrict__ o, int ncols, int rows)
{ residual_rms_body<u16, float>(a, pbuf, o, ncols, rows); }

// ------------- transpose per batch: bf16 in (R,C) -> bf16 out (C,R) --------
// R22: single bf16 write (was dual f32+bf16). [32][34] u16 tile: 68 B row
// stride = 17 dwords, gcd(17,32)=1 -> conflict-free column walks.
__global__ __launch_bounds__(256) void transpose_bf16_kernel(
    const u16* __restrict__ in, u16* __restrict__ outb, int R, int C)
{
    __shared__ u16 tile[32][34];
    int b = blockIdx.z;
    int c0 = blockIdx.x * 32, r0 = blockIdx.y * 32;
    const u16* ip = in + (size_t)b * R * C;
    for (int i = threadIdx.y; i < 32; i += 8)
        tile[i][threadIdx.x] = ip[(size_t)(r0 + i) * C + c0 + threadIdx.x];
    __syncthreads();
    size_t ob = (size_t)b * R * C;
    for (int i = threadIdx.y; i < 32; i += 8)
        outb[ob + (size_t)(c0 + i) * R + r0 + threadIdx.x] = tile[threadIdx.x][i];
}

// ---------------------------------------------------------------------------
extern "C" void kernel_launch(void* const* d_in, const int* in_sizes, int n_in,
                              void* d_out, int out_size, void* d_ws, size_t ws_size,
                              hipStream_t stream)
{
    const float* hid      = (const float*)d_in[0];
    const float* in_proj  = (const float*)d_in[1];
    const float* conv_w   = (const float*)d_in[2];
    const float* conv_b   = (const float*)d_in[3];
    const float* dt_bias  = (const float*)d_in[4];
    const float* A_log    = (const float*)d_in[5];
    const float* Dv       = (const float*)d_in[6];
    const float* norm_w   = (const float*)d_in[7];
    const float* out_proj = (const float*)d_in[8];
    const float* gu_t     = (const float*)d_in[9];
    const float* down_t   = (const float*)d_in[10];
    const float* gu_m     = (const float*)d_in[11];
    const float* down_m   = (const float*)d_in[12];
    float* outp = (float*)d_out;

    char* ws = (char*)d_ws;
    u16* bf        = (u16*)ws;
    u16* hid_bf    = bf;
    u16* w_inproj  = bf + HID_E;
    u16* w_outproj = w_inproj + INPROJ_P_E;
    u16* w_gut     = w_outproj + OUTPROJ_E;
    u16* w_downt   = w_gut + GUT_E;
    u16* w_gum     = w_downt + DOWNT_E;
    u16* w_downm   = w_gum + GUM_E;
    size_t o = (size_t)(CONV_TOT_E * 2);
    auto alloc = [&](size_t bytes) { size_t r = o; o = (o + bytes + 255) & ~(size_t)255; return r; };
    size_t dt_off  = alloc(4096 * 16 * 4);
    size_t g_off   = alloc((size_t)4096 * 1024 * 2);
    size_t h1_off  = alloc((size_t)4096 * 512 * 4);
    size_t Pt_off  = alloc(2048 * 4);
    // ---- MLP region (live step 8+); Sc/Sinit OVERLAY it (live steps 4-5).
    size_t xtb_off = alloc((size_t)2048 * 1024 * 2);
    size_t xtf_off = alloc((size_t)2048 * 1024 * 4);
    size_t act1_off= alloc((size_t)2048 * 2816 * 2);
    size_t x2_off  = alloc((size_t)2048 * 1024 * 4);
    size_t h2b_off = alloc((size_t)4096 * 512 * 2);
    size_t h2f_off = alloc((size_t)4096 * 512 * 4);
    size_t act2_off= alloc((size_t)4096 * 1536 * 2);
    size_t pad_off = alloc((size_t)10 * 1024 * 1024);
    size_t Sc_off  = xtb_off;                          // bf16: 16.78 MB
    size_t Si_off  = xtb_off + (size_t)8192 * 1024 * 4;// bf16: 16.78 MB
    (void)pad_off; (void)xtf_off; (void)h2f_off;
    size_t R_off   = o;
    size_t zx_off  = R_off;
    size_t cv_off  = zx_off + (size_t)4096 * NPROJ_PAD * 4;
    size_t y_off   = cv_off + (size_t)4096 * CONVDIM * 4;
    size_t sk_off  = R_off;

    u16*   zx      = (u16*)(ws + zx_off);            // bf16 (R21)
    u16*   convout = (u16*)(ws + cv_off);            // bf16 (R21)
    u16*   ybuf    = (u16*)(ws + y_off);             // yp0 (bf16, R19)
    float* dtbuf   = (float*)(ws + dt_off);
    u16*   g_bf    = (u16*)(ws + g_off);
    u16*   h1_bf   = (u16*)(ws + h1_off);            // bf16 (R22)
    u16*   xt_bf   = (u16*)(ws + xtb_off);
    u16*   act1    = (u16*)(ws + act1_off);
    u16*   x2_bf   = (u16*)(ws + x2_off);            // bf16 (R22)
    u16*   h2_bf   = (u16*)(ws + h2b_off);
    u16*   act2    = (u16*)(ws + act2_off);
    u16*   skbuf   = (u16*)(ws + sk_off);            // bf16 partials (R20)
    u16*   Sc      = (u16*)(ws + Sc_off);            // bf16; yp1 after combine
    u16*   Sinit   = (u16*)(ws + Si_off);            // bf16
    float* Ptot    = (float*)(ws + Pt_off);

    // 1) convert weights + hidden to bf16
    convert_all_kernel<<<14464, 256, 0, stream>>>(
        hid, in_proj, out_proj, gu_t, down_t, gu_m, down_m, bf);

    // 2) zxbcdt = hidden @ in_proj^T  (bf16 out)
    gemm_bt<<<dim3(NPROJ_PAD / 128, 4096 / 128), 256, 0, stream>>>(
        hid_bf, w_inproj, zx, 4096, NPROJ_PAD, 512);

    // 3) conv + dt
    conv_dt_kernel<<<18688, 256, 0, stream>>>(zx, conv_w, conv_b, dt_bias, convout, dtbuf);

    // 4) MFMA chunk scan (all state bf16)
    scan_mfma1<<<512, 256, 0, stream>>>(convout, dtbuf, A_log, Sc, Ptot, ybuf);
    scan_combine<<<256, 256, 0, stream>>>(Sc, Ptot, Sinit);
    scan_mfma2<<<512, 256, 0, stream>>>(convout, dtbuf, A_log, Sinit, Sc);

    // 5) gated RMSNorm -> bf16
    gated_rms_kernel<<<4096, 256, 0, stream>>>(ybuf, Sc, convout, zx, Dv, norm_w, g_bf);

    // 6) out_proj GEMM, split-K x4 -> bf16 partials in skbuf
    gemm_bt_sk<<<dim3(512 / 128, 4096 / 128, 4), 256, 0, stream>>>(
        g_bf, w_outproj, skbuf, 4096, 512, 1024, 256);

    // 7) h1 = rms(hidden + sum partials)  (bf16 out, R22)
    residual_rms_f2b<<<4096, 128, 0, stream>>>(hid, skbuf, h1_bf, 512, 4096);

    // 8) transpose (B,1024,512) -> (B,512,1024)  (bf16->bf16, R22)
    transpose_bf16_kernel<<<dim3(16, 32, 4), dim3(32, 8), 0, stream>>>(h1_bf, xt_bf, 1024, 512);

    // 9) token MLP fused: act1 = swiglu(xt @ gu_t^T)
    gemm_swiglu<<<dim3(INTER_T / 64, 2048 / 128), 256, 0, stream>>>(
        xt_bf, w_gut, act1, 2048, INTER_T, 1024);

    // 10) down_t GEMM, split-K x4 -> bf16 partials in skbuf
    gemm_bt_sk<<<dim3(1024 / 128, 2048 / 128, 4), 256, 0, stream>>>(
        act1, w_downt, skbuf, 2048, 1024, 2816, 704);

    // 11) x2 = rms(xt + sum partials)  (bf16 in/out, R22)
    residual_rms_b2b<<<2048, 256, 0, stream>>>(xt_bf, skbuf, x2_bf, 1024, 2048);

    // 12) transpose back (B,512,1024) -> (B,1024,512)
    transpose_bf16_kernel<<<dim3(32, 16, 4), dim3(32, 8), 0, stream>>>(x2_bf, h2_bf, 512, 1024);

    // 13) channel MLP fused: act2 = swiglu(h2 @ gu_m^T)
    gemm_swiglu<<<dim3(INTER_M / 64, 4096 / 128), 256, 0, stream>>>(
        h2_bf, w_gum, act2, 4096, INTER_M, 512);

    // 14) down_m GEMM, split-K x4 -> bf16 partials in skbuf
    gemm_bt_sk<<<dim3(512 / 128, 4096 / 128, 4), 256, 0, stream>>>(
        act2, w_downm, skbuf, 4096, 512, 1536, 384);

    // 15) out = rms(h2 + sum partials)  (f32 out)
    residual_rms_b2f<<<4096, 128, 0, stream>>>(h2_bf, skbuf, outp, 512, 4096);
}

// Round 8
// 305.217 us; speedup vs baseline: 1.1322x; 1.0116x over previous
//
#include <hip/hip_runtime.h>

// ---------------------------------------------------------------------------
// Mamba2 hybrid block. GEMMs: bf16 MFMA 16x16x32, f32 accumulate, m97-style
// global_load_lds(16B) staging, BK=64. 3-bit XOR chunk swizzle keeps frag
// reads 2-way/free. Small-N GEMMs use split-K x4 into bf16 partial buffers;
// partials summed in residual_rms. MLP gu-GEMMs fuse SwiGLU (128x64 tile).
// Scan: MFMA chunked.
// R16: scan_mfma1 4 heads/block shared B/C staging (-14.1 us, 355.5->341.4).
// R17/R18: scan_mfma2 4 heads/block + scan_combine unroll: NEUTRAL.
// R19: bf16 scan state (Sc/Sinit/yp0/yp1): -17.4 us (345.6->328.2).
// R20: bf16 split-K partials (-8.6 us, 328.2->319.6).
// R21: bf16 zx + convout: -1.6 us (L2-resident; lesson learned).
// R22: bf16 residual trunk + single-write bf16 transposes (-9.2, 308.8).
// R23: bijective XCD swizzle (m204) on all GEMM block maps — aggregate
// operand re-reads ~1 GB at cache level; contiguous per-XCD tile chunks make
// the per-XCD working set L2-fit (mechanism: T1). scan_combine regrid
// 256->512 blocks (2/CU) for carry-chain latency hiding. Both changes are
// BITWISE-neutral (block remap + same arith order): absmax must stay 0.03125.
// NOTE: 8-phase 256^2 rewrite is contraindicated at these shapes: 256^2
// tiles give only 88-176 blocks on 256 CUs (half the chip idle).
// ---------------------------------------------------------------------------

#define BB 4
#define LL 1024
#define DMODEL 512
#define DINNER 1024
#define NHEADS 16
#define HEADDIM 64
#define DSTATE 64
#define CONVDIM 1152        // DINNER + 2*DSTATE
#define NPROJ 2192          // D_IN_PROJ
#define NPROJ_PAD 2304      // padded to multiple of 128
#define INTER_T 2816
#define INTER_M 1536
#define NCHUNK 32
#define CHUNK 32

typedef __bf16 bf16x8 __attribute__((ext_vector_type(8)));
typedef float  f32x4  __attribute__((ext_vector_type(4)));
typedef unsigned short u16;
typedef unsigned int   u32;
typedef unsigned short u16x8 __attribute__((ext_vector_type(8)));

__device__ __forceinline__ u16 f2bf(float x) {
    union { float f; u32 u; } v; v.f = x;
    u32 u = v.u;
    return (u16)((u + 0x7fffu + ((u >> 16) & 1u)) >> 16);
}
__device__ __forceinline__ float silu_f(float x) {
    return x / (1.f + __expf(-x));
}
__device__ __forceinline__ float bf2f(u16 w) {
    union { u32 u; float f; } a; a.u = ((u32)w) << 16; return a.f;
}

// C-store helpers: f32 passthrough or bf16 round (R20/R21)
__device__ __forceinline__ void cstore(float* p, float v) { *p = v; }
__device__ __forceinline__ void cstore(u16*   p, float v) { *p = f2bf(v); }

// R23: bijective XCD-aware block remap (m204). Consecutive remapped indices
// land on the SAME XCD as a contiguous chunk -> per-XCD L2 keeps the A/W
// panels of that chunk resident across re-reads.
__device__ __forceinline__ void xcd_swizzle(int& bx, int& by) {
    int gx = gridDim.x;
    int nwg = gx * gridDim.y;
    int orig = by * gx + bx;
    int q = nwg >> 3, rr = nwg & 7;
    int xcd = orig & 7, lid = orig >> 3;
    int swz = (xcd < rr ? xcd * (q + 1) : rr * (q + 1) + (xcd - rr) * q) + lid;
    bx = swz % gx;
    by = swz / gx;
}

// async global->LDS, 16B per lane; LDS dest is wave-uniform base + lane*16
__device__ __forceinline__ void gld_lds16(const u16* g, u16* l) {
    __builtin_amdgcn_global_load_lds(
        (const __attribute__((address_space(1))) unsigned int*)g,
        (__attribute__((address_space(3))) unsigned int*)l, 16, 0, 0);
}

// --------------------------- block-wide sum --------------------------------
__device__ __forceinline__ float block_sum(float v) {
    #pragma unroll
    for (int off = 32; off > 0; off >>= 1) v += __shfl_xor(v, off, 64);
    __shared__ float red[4];
    int w = threadIdx.x >> 6;
    int nwv = blockDim.x >> 6;
    if ((threadIdx.x & 63) == 0) red[w] = v;
    __syncthreads();
    float tot = red[0];
    for (int i = 1; i < nwv; i++) tot += red[i];
    return tot;
}

// --------------------- f32 -> bf16 convert (all weights + hidden) ----------
#define HID_E      2097152LL   // 4096*512
#define INPROJ_P_E 1179648LL   // 2304*512
#define INPROJ_S_E 1122304LL   // 2192*512
#define OUTPROJ_E   524288LL   // 512*1024
#define GUT_E      5767168LL   // 5632*1024
#define DOWNT_E    2883584LL   // 1024*2816
#define GUM_E      1572864LL   // 3072*512
#define DOWNM_E     786432LL   // 512*1536
#define CONV_TOT_E 14811136LL

__global__ __launch_bounds__(256) void convert_all_kernel(
    const float* __restrict__ s_hid, const float* __restrict__ s_inproj,
    const float* __restrict__ s_outproj, const float* __restrict__ s_gut,
    const float* __restrict__ s_downt, const float* __restrict__ s_gum,
    const float* __restrict__ s_downm, u16* __restrict__ dst)
{
    long long idx = (long long)blockIdx.x * 256 + threadIdx.x;
    long long e = idx * 4;
    if (e >= CONV_TOT_E) return;
    const float* src; long long off, nsrc;
    long long c0 = HID_E;
    long long c1 = c0 + INPROJ_P_E;
    long long c2 = c1 + OUTPROJ_E;
    long long c3 = c2 + GUT_E;
    long long c4 = c3 + DOWNT_E;
    long long c5 = c4 + GUM_E;
    if      (e < c0) { src = s_hid;     off = e;      nsrc = HID_E; }
    else if (e < c1) { src = s_inproj;  off = e - c0; nsrc = INPROJ_S_E; }
    else if (e < c2) { src = s_outproj; off = e - c1; nsrc = OUTPROJ_E; }
    else if (e < c3) { src = s_gut;     off = e - c2; nsrc = GUT_E; }
    else if (e < c4) { src = s_downt;   off = e - c3; nsrc = DOWNT_E; }
    else if (e < c5) { src = s_gum;     off = e - c4; nsrc = GUM_E; }
    else             { src = s_downm;   off = e - c5; nsrc = DOWNM_E; }
    ushort4 r;
    if (off < nsrc) {
        float4 v = *reinterpret_cast<const float4*>(src + off);
        r.x = f2bf(v.x); r.y = f2bf(v.y); r.z = f2bf(v.z); r.w = f2bf(v.w);
    } else {
        r.x = 0; r.y = 0; r.z = 0; r.w = 0;
    }
    *reinterpret_cast<ushort4*>(dst + e) = r;
}

// ----------------------------- bf16 MFMA GEMM (BK=64) ----------------------
// C[M,N] = A[M,K] * W[N,K]^T. 128x128 tile, 4 waves of 64x64 (4x4 MFMAs).
// R20/R21: CT templates the C dtype (f32 or bf16). R23: XCD swizzle.
template<bool SK, typename CT>
__device__ __forceinline__ void gemm_bt_body(
    const u16* __restrict__ A, const u16* __restrict__ W,
    CT* __restrict__ C, int M, int N, int K, int kLen)
{
    __shared__ u16 As[128 * 64];   // 16 KB
    __shared__ u16 Bs[128 * 64];   // 16 KB
    int tid = threadIdx.x;
    int bx = blockIdx.x, by = blockIdx.y;
    xcd_swizzle(bx, by);
    int m0 = by * 128, n0 = bx * 128;
    int kBase = SK ? blockIdx.z * kLen : 0;
    CT* Cw = SK ? C + (size_t)blockIdx.z * M * N : C;
    int wave = tid >> 6, lane = tid & 63;
    int wm = (wave >> 1) * 64, wn = (wave & 1) * 64;
    int lrow = lane & 15;
    int kq = lane >> 4;
    int kx = lrow & 7;

    int rL = lane >> 3, cL = lane & 7;
    int cG = cL ^ rL;
    const u16* gA[4]; const u16* gB[4];
    u16 *lA[4], *lB[4];
    #pragma unroll
    for (int i = 0; i < 4; i++) {
        int r = wave * 32 + i * 8;
        gA[i] = A + (size_t)(m0 + r + rL) * K + kBase + cG * 8;
        gB[i] = W + (size_t)(n0 + r + rL) * K + kBase + cG * 8;
        lA[i] = &As[r * 64];
        lB[i] = &Bs[r * 64];
    }

    f32x4 acc[4][4];
    #pragma unroll
    for (int i = 0; i < 4; i++)
        #pragma unroll
        for (int j = 0; j < 4; j++) {
            acc[i][j][0] = 0.f; acc[i][j][1] = 0.f;
            acc[i][j][2] = 0.f; acc[i][j][3] = 0.f;
        }

    for (int kt = 0; kt < kLen; kt += 64) {
        __syncthreads();
        #pragma unroll
        for (int i = 0; i < 4; i++) {
            gld_lds16(gA[i] + kt, lA[i]);
            gld_lds16(gB[i] + kt, lB[i]);
        }
        __syncthreads();
        #pragma unroll
        for (int ks = 0; ks < 2; ks++) {
            int ko = (((ks * 4 + kq) ^ kx) * 8);
            bf16x8 af[4], bfr[4];
            #pragma unroll
            for (int i = 0; i < 4; i++) {
                af[i]  = *reinterpret_cast<const bf16x8*>(&As[(wm + i * 16 + lrow) * 64 + ko]);
                bfr[i] = *reinterpret_cast<const bf16x8*>(&Bs[(wn + i * 16 + lrow) * 64 + ko]);
            }
            #pragma unroll
            for (int i = 0; i < 4; i++)
                #pragma unroll
                for (int j = 0; j < 4; j++)
                    acc[i][j] = __builtin_amdgcn_mfma_f32_16x16x32_bf16(af[i], bfr[j], acc[i][j], 0, 0, 0);
        }
    }

    // C/D layout: col = lane&15, row = (lane>>4)*4 + reg
    int rbase = m0 + wm + kq * 4;
    int cbase = n0 + wn + lrow;
    #pragma unroll
    for (int i = 0; i < 4; i++)
        #pragma unroll
        for (int j = 0; j < 4; j++)
            #pragma unroll
            for (int r = 0; r < 4; r++)
                cstore(&Cw[(size_t)(rbase + i * 16 + r) * N + cbase + j * 16], acc[i][j][r]);
}

// R21: in_proj GEMM emits bf16 zx
__global__ __launch_bounds__(256) void gemm_bt(
    const u16* __restrict__ A, const u16* __restrict__ W,
    u16* __restrict__ C, int M, int N, int K)
{
    gemm_bt_body<false, u16>(A, W, C, M, N, K, K);
}

__global__ __launch_bounds__(256) void gemm_bt_sk(
    const u16* __restrict__ A, const u16* __restrict__ W,
    u16* __restrict__ C, int M, int N, int K, int kLen)
{
    gemm_bt_body<true, u16>(A, W, C, M, N, K, kLen);
}

// --------------- fused gate/up GEMM + SwiGLU (128x64, BK=64) ---------------
// act[M,inter] = silu(A·Wg^T) * (A·Wu^T). Bs rows 0..63 = gate, 64..127 = up.
// R23: XCD swizzle.
__global__ __launch_bounds__(256) void gemm_swiglu(
    const u16* __restrict__ A, const u16* __restrict__ W,
    u16* __restrict__ act, int M, int inter, int K)
{
    __shared__ u16 As[128 * 64];   // 16 KB
    __shared__ u16 Bs[128 * 64];   // 16 KB
    int tid = threadIdx.x;
    int bx = blockIdx.x, by = blockIdx.y;
    xcd_swizzle(bx, by);
    int m0 = by * 128, n0 = bx * 64;
    int wave = tid >> 6, lane = tid & 63;
    int wm = (wave >> 1) * 64, wn = (wave & 1) * 32;
    int lrow = lane & 15;
    int kq = lane >> 4;
    int kx = lrow & 7;

    int rL = lane >> 3, cL = lane & 7;
    int cG = cL ^ rL;
    const u16* gA[4]; const u16* gB[4];
    u16 *lA[4], *lB[4];
    #pragma unroll
    for (int i = 0; i < 4; i++) {
        int r = wave * 32 + i * 8;
        gA[i] = A + (size_t)(m0 + r + rL) * K + cG * 8;
        lA[i] = &As[r * 64];
        int rB = r;   // combined index: 0..63 gate, 64..127 up (per wave 32)
        int grow = (rB < 64) ? (n0 + rB + rL)
                             : (inter + n0 + rB - 64 + rL);
        gB[i] = W + (size_t)grow * K + cG * 8;
        lB[i] = &Bs[rB * 64];
    }

    f32x4 accg[4][2], accu[4][2];
    #pragma unroll
    for (int i = 0; i < 4; i++)
        #pragma unroll
        for (int j = 0; j < 2; j++) {
            accg[i][j][0]=0.f; accg[i][j][1]=0.f; accg[i][j][2]=0.f; accg[i][j][3]=0.f;
            accu[i][j][0]=0.f; accu[i][j][1]=0.f; accu[i][j][2]=0.f; accu[i][j][3]=0.f;
        }

    for (int kt = 0; kt < K; kt += 64) {
        __syncthreads();
        #pragma unroll
        for (int i = 0; i < 4; i++) {
            gld_lds16(gA[i] + kt, lA[i]);
            gld_lds16(gB[i] + kt, lB[i]);
        }
        __syncthreads();
        #pragma unroll
        for (int ks = 0; ks < 2; ks++) {
            int ko = (((ks * 4 + kq) ^ kx) * 8);
            bf16x8 af[4], bg[2], bu[2];
            #pragma unroll
            for (int i = 0; i < 4; i++)
                af[i] = *reinterpret_cast<const bf16x8*>(&As[(wm + i * 16 + lrow) * 64 + ko]);
            #pragma unroll
            for (int j = 0; j < 2; j++) {
                bg[j] = *reinterpret_cast<const bf16x8*>(&Bs[(wn + j * 16 + lrow) * 64 + ko]);
                bu[j] = *reinterpret_cast<const bf16x8*>(&Bs[(64 + wn + j * 16 + lrow) * 64 + ko]);
            }
            #pragma unroll
            for (int i = 0; i < 4; i++)
                #pragma unroll
                for (int j = 0; j < 2; j++) {
                    accg[i][j] = __builtin_amdgcn_mfma_f32_16x16x32_bf16(af[i], bg[j], accg[i][j], 0, 0, 0);
                    accu[i][j] = __builtin_amdgcn_mfma_f32_16x16x32_bf16(af[i], bu[j], accu[i][j], 0, 0, 0);
                }
        }
    }

    int rbase = m0 + wm + kq * 4;
    int cbase = n0 + wn + lrow;
    #pragma unroll
    for (int i = 0; i < 4; i++)
        #pragma unroll
        for (int j = 0; j < 2; j++)
            #pragma unroll
            for (int r = 0; r < 4; r++) {
                float g = accg[i][j][r], u = accu[i][j][r];
                act[(size_t)(rbase + i * 16 + r) * inter + cbase + j * 16] =
                    f2bf(silu_f(g) * u);
            }
}

// ----------------- conv (depthwise, causal, width 4) + dt ------------------
__global__ __launch_bounds__(256) void conv_dt_kernel(
    const u16* __restrict__ zx, const float* __restrict__ conv_w,
    const float* __restrict__ conv_b, const float* __restrict__ dt_bias,
    u16* __restrict__ convout, float* __restrict__ dtbuf)
{
    int idx = blockIdx.x * 256 + threadIdx.x;   // over 4096*1168
    int bl = idx / 1168;
    int c  = idx - bl * 1168;
    int l  = bl & (LL - 1);
    if (c < CONVDIM) {
        const u16* col = zx + (size_t)bl * NPROJ_PAD + DINNER + c;
        float acc = conv_b[c];
        #pragma unroll
        for (int i = 0; i < 4; i++) {
            int lt = l - 3 + i;
            float v = (lt >= 0) ? bf2f(col[(long long)(lt - l) * NPROJ_PAD]) : 0.f;
            acc = fmaf(v, conv_w[c * 4 + i], acc);
        }
        convout[(size_t)bl * CONVDIM + c] = f2bf(silu_f(acc));
    } else {
        int h = c - CONVDIM;
        float v = bf2f(zx[(size_t)bl * NPROJ_PAD + 2176 + h]) + dt_bias[h];
        float sp = (v > 20.f) ? v : log1pf(__expf(v));
        dtbuf[(size_t)bl * NHEADS + h] = sp;
    }
}

// -------------------- MFMA chunk scan: pass 1 ------------------------------
__global__ __launch_bounds__(256) void scan_mfma1(
    const u16* __restrict__ convout, const float* __restrict__ dtbuf,
    const float* __restrict__ A_log, u16* __restrict__ Sc,
    float* __restrict__ Ptot, u16* __restrict__ yp0)
{
    __shared__ u16 Blds[32 * 72];        // raw B bf16 [t][n] (shared)
    __shared__ u16 Clds[32 * 72];        // raw C bf16 [t][n] (shared)
    __shared__ u16 Xt[4][64 * 40];       // x^T bf16 [p][t] (per head)
    __shared__ u16 Bht[4][64 * 40];      // (w_t*dt_t*B)^T bf16 [n][t]
    __shared__ u16 Wlds[4][32 * 40];     // W bf16 [t][t']
    __shared__ float dtl[4][32], cuml[4][32], warr[4][32];

    int blk = blockIdx.x;                // 512 = (b*4 + hq)*32 + c
    int c   = blk & 31;
    int bg  = blk >> 5;
    int b   = bg >> 2;
    int hq  = bg & 3;
    int tid = threadIdx.x;
    int w    = tid >> 6;                 // wave = head within quad
    int lane = tid & 63;
    int h   = hq * 4 + w;
    int bh  = b * 16 + h;
    int lrow = lane & 15, kq = lane >> 4;
    size_t base = ((size_t)b * LL + (size_t)c * CHUNK) * CONVDIM;
    float Ah = -__expf(A_log[h]);

    if (lane < 32)
        dtl[w][lane] = dtbuf[((size_t)b * LL + (size_t)c * CHUNK + lane) * NHEADS + h];
    // shared B/C staging: 32 t x 16 chunks of 8 bf16; 256 thr -> 2 iters
    #pragma unroll
    for (int it = 0; it < 2; ++it) {
        int idx = it * 256 + tid;
        int t = idx >> 4, q = idx & 15;
        u16x8 v = *reinterpret_cast<const u16x8*>(
            &convout[base + (size_t)t * CONVDIM + DINNER + q * 8]);
        if (q < 8) *reinterpret_cast<u16x8*>(&Blds[t * 72 + q * 8]) = v;
        else       *reinterpret_cast<u16x8*>(&Clds[t * 72 + (q - 8) * 8]) = v;
    }
    #pragma unroll
    for (int t = 0; t < 32; ++t)
        Xt[w][lane * 40 + t] = convout[base + (size_t)t * CONVDIM + h * HEADDIM + lane];
    __syncthreads();

    float s_inc = 0.f, s_all = 0.f;
    #pragma unroll
    for (int j = 0; j < 32; ++j) {
        float v = dtl[w][j];
        s_all += v;
        if (j <= lane) s_inc += v;
    }
    if (lane < 32) {
        cuml[w][lane] = s_inc;
        warr[w][lane] = __expf(Ah * (s_all - s_inc)) * dtl[w][lane];
    }
    float cumTot = s_all;
    __syncthreads();

    #pragma unroll
    for (int t = 0; t < 32; ++t)
        Bht[w][lane * 40 + t] = f2bf(warr[w][t] * bf2f(Blds[t * 72 + lane]));

    f32x4 accG[2][2];
    #pragma unroll
    for (int i = 0; i < 2; i++)
        #pragma unroll
        for (int j = 0; j < 2; j++) {
            accG[i][j][0]=0.f; accG[i][j][1]=0.f; accG[i][j][2]=0.f; accG[i][j][3]=0.f;
        }
    #pragma unroll
    for (int ks = 0; ks < 2; ++ks) {
        bf16x8 af[2], bfr[2];
        #pragma unroll
        for (int i = 0; i < 2; i++) {
            af[i]  = *reinterpret_cast<const bf16x8*>(&Clds[(16*i + lrow) * 72 + ks*32 + kq*8]);
            bfr[i] = *reinterpret_cast<const bf16x8*>(&Blds[(16*i + lrow) * 72 + ks*32 + kq*8]);
        }
        #pragma unroll
        for (int i = 0; i < 2; i++)
            #pragma unroll
            for (int j = 0; j < 2; j++)
                accG[i][j] = __builtin_amdgcn_mfma_f32_16x16x32_bf16(af[i], bfr[j], accG[i][j], 0, 0, 0);
    }

    float ctp0 = cuml[w][lrow],      dtp0 = dtl[w][lrow];
    float ctp1 = cuml[w][16 + lrow], dtp1 = dtl[w][16 + lrow];
    #pragma unroll
    for (int i = 0; i < 2; i++)
        #pragma unroll
        for (int r = 0; r < 4; r++) {
            int t = 16*i + kq*4 + r;
            float ct = cuml[w][t];
            #pragma unroll
            for (int j = 0; j < 2; j++) {
                int tp = 16*j + lrow;
                float ctp = j ? ctp1 : ctp0;
                float dtp = j ? dtp1 : dtp0;
                float g = accG[i][j][r];
                float wv = (tp <= t) ? __expf(Ah * (ct - ctp)) * dtp * g : 0.f;
                Wlds[w][t * 40 + tp] = f2bf(wv);
            }
        }
    __syncthreads();

    bf16x8 xf[4];
    #pragma unroll
    for (int j = 0; j < 4; j++)
        xf[j] = *reinterpret_cast<const bf16x8*>(&Xt[w][(16*j + lrow) * 40 + kq*8]);
    f32x4 accY[2][4];
    #pragma unroll
    for (int i = 0; i < 2; i++) {
        bf16x8 wf = *reinterpret_cast<const bf16x8*>(&Wlds[w][(16*i + lrow) * 40 + kq*8]);
        #pragma unroll
        for (int j = 0; j < 4; j++) {
            accY[i][j][0]=0.f; accY[i][j][1]=0.f; accY[i][j][2]=0.f; accY[i][j][3]=0.f;
            accY[i][j] = __builtin_amdgcn_mfma_f32_16x16x32_bf16(wf, xf[j], accY[i][j], 0, 0, 0);
        }
    }

    f32x4 accS[4][4];
    #pragma unroll
    for (int j = 0; j < 4; j++) {
        bf16x8 bb = *reinterpret_cast<const bf16x8*>(&Bht[w][(16*j + lrow) * 40 + kq*8]);
        #pragma unroll
        for (int i = 0; i < 4; i++) {
            accS[i][j][0]=0.f; accS[i][j][1]=0.f; accS[i][j][2]=0.f; accS[i][j][3]=0.f;
            accS[i][j] = __builtin_amdgcn_mfma_f32_16x16x32_bf16(xf[i], bb, accS[i][j], 0, 0, 0);
        }
    }

    u16* yb = yp0 + ((size_t)b * LL + (size_t)c * CHUNK) * DINNER + h * HEADDIM;
    #pragma unroll
    for (int i = 0; i < 2; i++)
        #pragma unroll
        for (int r = 0; r < 4; r++) {
            int t = 16*i + kq*4 + r;
            #pragma unroll
            for (int j = 0; j < 4; j++)
                yb[(size_t)t * DINNER + 16*j + lrow] = f2bf(accY[i][j][r]);
        }
    #pragma unroll
    for (int i = 0; i < 4; i++)
        #pragma unroll
        for (int r = 0; r < 4; r++) {
            int p = 16*i + kq*4 + r;
            #pragma unroll
            for (int j = 0; j < 4; j++)
                Sc[((size_t)(bh * 4 + j) * NCHUNK + c) * 1024 + p * 16 + lrow] = f2bf(accS[i][j][r]);
        }
    if (lane == 0) Ptot[bh * NCHUNK + c] = __expf(Ah * cumTot);
}

// ----------------------- chunked SSM scan: combine -------------------------
// R23: 512 blocks (2/CU) x 256 thr x 2 elems — same arithmetic order as R17
// (bitwise identical), finer grid for carry-chain latency hiding.
__global__ __launch_bounds__(256) void scan_combine(
    const u16* __restrict__ Sc, const float* __restrict__ Ptot,
    u16* __restrict__ Sinit)
{
    int blk = blockIdx.x;             // 512 = (bh*4 + nq)*2 + half
    int rowid = blk >> 1;             // bh*4 + nq
    int bh = rowid >> 2;
    int half = blk & 1;
    int tid = threadIdx.x;
    int e = half * 512 + tid * 2;     // elem offset within the 1024-wide row
    float Pv[NCHUNK];
    #pragma unroll
    for (int c = 0; c < NCHUNK; ++c) Pv[c] = Ptot[bh * NCHUNK + c];
    float c0v = 0.f, c1v = 0.f;
    size_t rowbase = (size_t)rowid * NCHUNK * 1024 + e;
    #pragma unroll
    for (int c = 0; c < NCHUNK; ++c) {
        size_t row = rowbase + (size_t)c * 1024;
        ushort2 o; o.x = f2bf(c0v); o.y = f2bf(c1v);
        *reinterpret_cast<ushort2*>(Sinit + row) = o;
        ushort2 si = *reinterpret_cast<const ushort2*>(Sc + row);
        c0v = fmaf(c0v, Pv[c], bf2f(si.x));
        c1v = fmaf(c1v, Pv[c], bf2f(si.y));
    }
}

// -------------------- MFMA chunk scan: pass 2 ------------------------------
__global__ __launch_bounds__(256) void scan_mfma2(
    const u16* __restrict__ convout, const float* __restrict__ dtbuf,
    const float* __restrict__ A_log, const u16* __restrict__ Sinit,
    u16* __restrict__ yp1)
{
    __shared__ u16 Clds2[32 * 72];       // raw C bf16 [t][n] (shared)
    __shared__ float dtl[4][32], dacl[4][32];
    int blk = blockIdx.x;                // 512 = (b*4 + hq)*32 + c
    int c   = blk & 31;
    int bg  = blk >> 5;
    int b   = bg >> 2;
    int hq  = bg & 3;
    int tid = threadIdx.x;
    int w    = tid >> 6;                 // wave = head within quad
    int lane = tid & 63;
    int h   = hq * 4 + w;
    int bh  = b * 16 + h;
    int lrow = lane & 15, kq = lane >> 4;
    size_t base = ((size_t)b * LL + (size_t)c * CHUNK) * CONVDIM;
    float Ah = -__expf(A_log[h]);

    if (lane < 32)
        dtl[w][lane] = dtbuf[((size_t)b * LL + (size_t)c * CHUNK + lane) * NHEADS + h];
    // shared raw-C staging: 32 t x 8 chunks of 8 bf16 = 256 thr x 1 iter
    {
        int t = tid >> 3, q = tid & 7;
        u16x8 v = *reinterpret_cast<const u16x8*>(
            &convout[base + (size_t)t * CONVDIM + DINNER + DSTATE + q * 8]);
        *reinterpret_cast<u16x8*>(&Clds2[t * 72 + q * 8]) = v;
    }
    __syncthreads();

    float s_inc = 0.f;
    #pragma unroll
    for (int j = 0; j < 32; ++j) {
        float v = dtl[w][j];
        if (j <= lane) s_inc += v;
    }
    if (lane < 32) dacl[w][lane] = __expf(Ah * s_inc);

    f32x4 accI[2][4];
    #pragma unroll
    for (int i = 0; i < 2; i++)
        #pragma unroll
        for (int j = 0; j < 4; j++) {
            accI[i][j][0]=0.f; accI[i][j][1]=0.f; accI[i][j][2]=0.f; accI[i][j][3]=0.f;
        }
    #pragma unroll
    for (int ks = 0; ks < 2; ++ks) {
        bf16x8 ca[2];
        #pragma unroll
        for (int i = 0; i < 2; i++)
            ca[i] = *reinterpret_cast<const bf16x8*>(&Clds2[(16*i + lrow) * 72 + ks*32 + kq*8]);
        int nq = ks * 2 + (kq >> 1);
        int off = (kq & 1) * 8;
        #pragma unroll
        for (int j = 0; j < 4; j++) {
            int p = 16*j + lrow;
            const u16* sp = Sinit + ((size_t)(bh * 4 + nq) * NCHUNK + c) * 1024 + p * 16 + off;
            bf16x8 fr = *reinterpret_cast<const bf16x8*>(sp);
            #pragma unroll
            for (int i = 0; i < 2; i++)
                accI[i][j] = __builtin_amdgcn_mfma_f32_16x16x32_bf16(ca[i], fr, accI[i][j], 0, 0, 0);
        }
    }

    u16* yb = yp1 + ((size_t)b * LL + (size_t)c * CHUNK) * DINNER + h * HEADDIM;
    #pragma unroll
    for (int i = 0; i < 2; i++)
        #pragma unroll
        for (int r = 0; r < 4; r++) {
            int t = 16*i + kq*4 + r;
            float sct = dacl[w][t];
            #pragma unroll
            for (int j = 0; j < 4; j++)
                yb[(size_t)t * DINNER + 16*j + lrow] = f2bf(accI[i][j][r] * sct);
        }
}

// ------------- gated RMSNorm (yp0+yp1+xD)*silu(z), bf16 out ----------------
__global__ __launch_bounds__(256) void gated_rms_kernel(
    const u16* __restrict__ yp0, const u16* __restrict__ yp1,
    const u16* __restrict__ convout, const u16* __restrict__ zx,
    const float* __restrict__ Dv, const float* __restrict__ norm_w,
    u16* __restrict__ gout)
{
    int bl = blockIdx.x;
    int c = threadIdx.x * 4;
    ushort4 y0 = *reinterpret_cast<const ushort4*>(yp0 + (size_t)bl * DINNER + c);
    ushort4 y1 = *reinterpret_cast<const ushort4*>(yp1 + (size_t)bl * DINNER + c);
    ushort4 xv = *reinterpret_cast<const ushort4*>(convout + (size_t)bl * CONVDIM + c);
    ushort4 zv = *reinterpret_cast<const ushort4*>(zx + (size_t)bl * NPROJ_PAD + c);
    float Dh = Dv[c >> 6];
    float g0 = (bf2f(y0.x) + bf2f(y1.x) + bf2f(xv.x) * Dh) * silu_f(bf2f(zv.x));
    float g1 = (bf2f(y0.y) + bf2f(y1.y) + bf2f(xv.y) * Dh) * silu_f(bf2f(zv.y));
    float g2 = (bf2f(y0.z) + bf2f(y1.z) + bf2f(xv.z) * Dh) * silu_f(bf2f(zv.z));
    float g3 = (bf2f(y0.w) + bf2f(y1.w) + bf2f(xv.w) * Dh) * silu_f(bf2f(zv.w));
    float tot = block_sum(g0 * g0 + g1 * g1 + g2 * g2 + g3 * g3);
    float sc = rsqrtf(tot * (1.f / DINNER) + 1e-5f);
    float4 nw = *reinterpret_cast<const float4*>(norm_w + c);
    ushort4 o;
    o.x = f2bf(g0 * sc * nw.x); o.y = f2bf(g1 * sc * nw.y);
    o.z = f2bf(g2 * sc * nw.z); o.w = f2bf(g3 * sc * nw.w);
    *reinterpret_cast<ushort4*>(gout + (size_t)bl * DINNER + c) = o;
}

// ---- residual + 4 split-K partials + RMSNorm (no weight) ------------------
template<typename AT, typename OT>
__device__ __forceinline__ void residual_rms_body(
    const AT* __restrict__ a, const u16* __restrict__ pbuf,
    OT* __restrict__ outf, int ncols, int rows)
{
    int row = blockIdx.x;
    int c = threadIdx.x * 4;
    size_t slice = (size_t)rows * ncols;
    size_t off = (size_t)row * ncols + c;
    float va0, va1, va2, va3;
    if constexpr (sizeof(AT) == 4) {
        float4 t = *reinterpret_cast<const float4*>((const float*)a + off);
        va0 = t.x; va1 = t.y; va2 = t.z; va3 = t.w;
    } else {
        ushort4 t = *reinterpret_cast<const ushort4*>((const u16*)a + off);
        va0 = bf2f(t.x); va1 = bf2f(t.y); va2 = bf2f(t.z); va3 = bf2f(t.w);
    }
    ushort4 p0 = *reinterpret_cast<const ushort4*>(pbuf + off);
    ushort4 p1 = *reinterpret_cast<const ushort4*>(pbuf + slice + off);
    ushort4 p2 = *reinterpret_cast<const ushort4*>(pbuf + 2 * slice + off);
    ushort4 p3 = *reinterpret_cast<const ushort4*>(pbuf + 3 * slice + off);
    float v0 = va0 + ((bf2f(p0.x) + bf2f(p1.x)) + (bf2f(p2.x) + bf2f(p3.x)));
    float v1 = va1 + ((bf2f(p0.y) + bf2f(p1.y)) + (bf2f(p2.y) + bf2f(p3.y)));
    float v2 = va2 + ((bf2f(p0.z) + bf2f(p1.z)) + (bf2f(p2.z) + bf2f(p3.z)));
    float v3 = va3 + ((bf2f(p0.w) + bf2f(p1.w)) + (bf2f(p2.w) + bf2f(p3.w)));
    float tot = block_sum(v0 * v0 + v1 * v1 + v2 * v2 + v3 * v3);
    float sc = rsqrtf(tot / (float)ncols + 1e-5f);
    if constexpr (sizeof(OT) == 4) {
        float4 o; o.x = v0 * sc; o.y = v1 * sc; o.z = v2 * sc; o.w = v3 * sc;
        *reinterpret_cast<float4*>((float*)outf + off) = o;
    } else {
        ushort4 o;
        o.x = f2bf(v0 * sc); o.y = f2bf(v1 * sc);
        o.z = f2bf(v2 * sc); o.w = f2bf(v3 * sc);
        *reinterpret_cast<ushort4*>((u16*)outf + off) = o;
    }
}

__global__ void residual_rms_f2b(const float* __restrict__ a,
    const u16* __restrict__ pbuf, u16* __restrict__ o, int ncols, int rows)
{ residual_rms_body<float, u16>(a, pbuf, o, ncols, rows); }

__global__ void residual_rms_b2b(const u16* __restrict__ a,
    const u16* __restrict__ pbuf, u16* __restrict__ o, int ncols, int rows)
{ residual_rms_body<u16, u16>(a, pbuf, o, ncols, rows); }

__global__ void residual_rms_b2f(const u16* __restrict__ a,
    const u16* __restrict__ pbuf, float* __restrict__ o, int ncols, int rows)
{ residual_rms_body<u16, float>(a, pbuf, o, ncols, rows); }

// ------------- transpose per batch: bf16 in (R,C) -> bf16 out (C,R) --------
__global__ __launch_bounds__(256) void transpose_bf16_kernel(
    const u16* __restrict__ in, u16* __restrict__ outb, int R, int C)
{
    __shared__ u16 tile[32][34];
    int b = blockIdx.z;
    int c0 = blockIdx.x * 32, r0 = blockIdx.y * 32;
    const u16* ip = in + (size_t)b * R * C;
    for (int i = threadIdx.y; i < 32; i += 8)
        tile[i][threadIdx.x] = ip[(size_t)(r0 + i) * C + c0 + threadIdx.x];
    __syncthreads();
    size_t ob = (size_t)b * R * C;
    for (int i = threadIdx.y; i < 32; i += 8)
        outb[ob + (size_t)(c0 + i) * R + r0 + threadIdx.x] = tile[threadIdx.x][i];
}

// ---------------------------------------------------------------------------
extern "C" void kernel_launch(void* const* d_in, const int* in_sizes, int n_in,
                              void* d_out, int out_size, void* d_ws, size_t ws_size,
                              hipStream_t stream)
{
    const float* hid      = (const float*)d_in[0];
    const float* in_proj  = (const float*)d_in[1];
    const float* conv_w   = (const float*)d_in[2];
    const float* conv_b   = (const float*)d_in[3];
    const float* dt_bias  = (const float*)d_in[4];
    const float* A_log    = (const float*)d_in[5];
    const float* Dv       = (const float*)d_in[6];
    const float* norm_w   = (const float*)d_in[7];
    const float* out_proj = (const float*)d_in[8];
    const float* gu_t     = (const float*)d_in[9];
    const float* down_t   = (const float*)d_in[10];
    const float* gu_m     = (const float*)d_in[11];
    const float* down_m   = (const float*)d_in[12];
    float* outp = (float*)d_out;

    char* ws = (char*)d_ws;
    u16* bf        = (u16*)ws;
    u16* hid_bf    = bf;
    u16* w_inproj  = bf + HID_E;
    u16* w_outproj = w_inproj + INPROJ_P_E;
    u16* w_gut     = w_outproj + OUTPROJ_E;
    u16* w_downt   = w_gut + GUT_E;
    u16* w_gum     = w_downt + DOWNT_E;
    u16* w_downm   = w_gum + GUM_E;
    size_t o = (size_t)(CONV_TOT_E * 2);
    auto alloc = [&](size_t bytes) { size_t r = o; o = (o + bytes + 255) & ~(size_t)255; return r; };
    size_t dt_off  = alloc(4096 * 16 * 4);
    size_t g_off   = alloc((size_t)4096 * 1024 * 2);
    size_t h1_off  = alloc((size_t)4096 * 512 * 4);
    size_t Pt_off  = alloc(2048 * 4);
    // ---- MLP region (live step 8+); Sc/Sinit OVERLAY it (live steps 4-5).
    size_t xtb_off = alloc((size_t)2048 * 1024 * 2);
    size_t xtf_off = alloc((size_t)2048 * 1024 * 4);
    size_t act1_off= alloc((size_t)2048 * 2816 * 2);
    size_t x2_off  = alloc((size_t)2048 * 1024 * 4);
    size_t h2b_off = alloc((size_t)4096 * 512 * 2);
    size_t h2f_off = alloc((size_t)4096 * 512 * 4);
    size_t act2_off= alloc((size_t)4096 * 1536 * 2);
    size_t pad_off = alloc((size_t)10 * 1024 * 1024);
    size_t Sc_off  = xtb_off;                          // bf16: 16.78 MB
    size_t Si_off  = xtb_off + (size_t)8192 * 1024 * 4;// bf16: 16.78 MB
    (void)pad_off; (void)xtf_off; (void)h2f_off;
    size_t R_off   = o;
    size_t zx_off  = R_off;
    size_t cv_off  = zx_off + (size_t)4096 * NPROJ_PAD * 4;
    size_t y_off   = cv_off + (size_t)4096 * CONVDIM * 4;
    size_t sk_off  = R_off;

    u16*   zx      = (u16*)(ws + zx_off);            // bf16 (R21)
    u16*   convout = (u16*)(ws + cv_off);            // bf16 (R21)
    u16*   ybuf    = (u16*)(ws + y_off);             // yp0 (bf16, R19)
    float* dtbuf   = (float*)(ws + dt_off);
    u16*   g_bf    = (u16*)(ws + g_off);
    u16*   h1_bf   = (u16*)(ws + h1_off);            // bf16 (R22)
    u16*   xt_bf   = (u16*)(ws + xtb_off);
    u16*   act1    = (u16*)(ws + act1_off);
    u16*   x2_bf   = (u16*)(ws + x2_off);            // bf16 (R22)
    u16*   h2_bf   = (u16*)(ws + h2b_off);
    u16*   act2    = (u16*)(ws + act2_off);
    u16*   skbuf   = (u16*)(ws + sk_off);            // bf16 partials (R20)
    u16*   Sc      = (u16*)(ws + Sc_off);            // bf16; yp1 after combine
    u16*   Sinit   = (u16*)(ws + Si_off);            // bf16
    float* Ptot    = (float*)(ws + Pt_off);

    // 1) convert weights + hidden to bf16
    convert_all_kernel<<<14464, 256, 0, stream>>>(
        hid, in_proj, out_proj, gu_t, down_t, gu_m, down_m, bf);

    // 2) zxbcdt = hidden @ in_proj^T  (bf16 out)
    gemm_bt<<<dim3(NPROJ_PAD / 128, 4096 / 128), 256, 0, stream>>>(
        hid_bf, w_inproj, zx, 4096, NPROJ_PAD, 512);

    // 3) conv + dt
    conv_dt_kernel<<<18688, 256, 0, stream>>>(zx, conv_w, conv_b, dt_bias, convout, dtbuf);

    // 4) MFMA chunk scan (all state bf16; R23 combine regrid)
    scan_mfma1<<<512, 256, 0, stream>>>(convout, dtbuf, A_log, Sc, Ptot, ybuf);
    scan_combine<<<512, 256, 0, stream>>>(Sc, Ptot, Sinit);
    scan_mfma2<<<512, 256, 0, stream>>>(convout, dtbuf, A_log, Sinit, Sc);

    // 5) gated RMSNorm -> bf16
    gated_rms_kernel<<<4096, 256, 0, stream>>>(ybuf, Sc, convout, zx, Dv, norm_w, g_bf);

    // 6) out_proj GEMM, split-K x4 -> bf16 partials in skbuf
    gemm_bt_sk<<<dim3(512 / 128, 4096 / 128, 4), 256, 0, stream>>>(
        g_bf, w_outproj, skbuf, 4096, 512, 1024, 256);

    // 7) h1 = rms(hidden + sum partials)  (bf16 out)
    residual_rms_f2b<<<4096, 128, 0, stream>>>(hid, skbuf, h1_bf, 512, 4096);

    // 8) transpose (B,1024,512) -> (B,512,1024)
    transpose_bf16_kernel<<<dim3(16, 32, 4), dim3(32, 8), 0, stream>>>(h1_bf, xt_bf, 1024, 512);

    // 9) token MLP fused: act1 = swiglu(xt @ gu_t^T)
    gemm_swiglu<<<dim3(INTER_T / 64, 2048 / 128), 256, 0, stream>>>(
        xt_bf, w_gut, act1, 2048, INTER_T, 1024);

    // 10) down_t GEMM, split-K x4 -> bf16 partials in skbuf
    gemm_bt_sk<<<dim3(1024 / 128, 2048 / 128, 4), 256, 0, stream>>>(
        act1, w_downt, skbuf, 2048, 1024, 2816, 704);

    // 11) x2 = rms(xt + sum partials)  (bf16 in/out)
    residual_rms_b2b<<<2048, 256, 0, stream>>>(xt_bf, skbuf, x2_bf, 1024, 2048);

    // 12) transpose back (B,512,1024) -> (B,1024,512)
    transpose_bf16_kernel<<<dim3(32, 16, 4), dim3(32, 8), 0, stream>>>(x2_bf, h2_bf, 512, 1024);

    // 13) channel MLP fused: act2 = swiglu(h2 @ gu_m^T)
    gemm_swiglu<<<dim3(INTER_M / 64, 4096 / 128), 256, 0, stream>>>(
        h2_bf, w_gum, act2, 4096, INTER_M, 512);

    // 14) down_m GEMM, split-K x4 -> bf16 partials in skbuf
    gemm_bt_sk<<<dim3(512 / 128, 4096 / 128, 4), 256, 0, stream>>>(
        act2, w_downm, skbuf, 4096, 512, 1536, 384);

    // 15) out = rms(h2 + sum partials)  (f32 out)
    residual_rms_b2f<<<4096, 128, 0, stream>>>(h2_bf, skbuf, outp, 512, 4096);
}

// Round 9
// 303.736 us; speedup vs baseline: 1.1377x; 1.0049x over previous
//
#include <hip/hip_runtime.h>

// ---------------------------------------------------------------------------
// Mamba2 hybrid block. GEMMs: bf16 MFMA 16x16x32, f32 accumulate, m97-style
// global_load_lds(16B) staging, BK=64. 3-bit XOR chunk swizzle keeps frag
// reads 2-way/free. Small-N GEMMs use split-K x4 into bf16 partial buffers;
// partials summed in residual_rms. MLP gu-GEMMs fuse SwiGLU (128x64 tile).
// Scan: MFMA chunked.
// R16: scan_mfma1 4 heads/block shared B/C staging (-14.1 us, 355.5->341.4).
// R17/R18: scan_mfma2 4 heads/block + scan_combine unroll: NEUTRAL.
// R19: bf16 scan state (Sc/Sinit/yp0/yp1): -17.4 us (345.6->328.2).
// R20: bf16 split-K partials (-8.6 us, 328.2->319.6).
// R21: bf16 zx + convout: -1.6 us (L2-resident; lesson learned).
// R22: bf16 residual trunk + single-write bf16 transposes (-9.2, 308.8).
// R23: bijective XCD swizzle on GEMMs + scan_combine regrid (-3.6, 305.2;
// absmax bitwise-stable as predicted).
// R24: fuse residual_rms + transpose (steps 7+8, 11+12). h1/x2 buffers had
// exactly ONE consumer (the transpose) — write the transposed bf16 output
// directly from the RMS kernel via a padded LDS tile. Saves 2 launches +
// ~17 MB round-trip. One wave per row (wave-local reduce, per-element sum
// order preserved); transposed write in 16-row x 16 B segments.
// ---------------------------------------------------------------------------

#define BB 4
#define LL 1024
#define DMODEL 512
#define DINNER 1024
#define NHEADS 16
#define HEADDIM 64
#define DSTATE 64
#define CONVDIM 1152        // DINNER + 2*DSTATE
#define NPROJ 2192          // D_IN_PROJ
#define NPROJ_PAD 2304      // padded to multiple of 128
#define INTER_T 2816
#define INTER_M 1536
#define NCHUNK 32
#define CHUNK 32

typedef __bf16 bf16x8 __attribute__((ext_vector_type(8)));
typedef float  f32x4  __attribute__((ext_vector_type(4)));
typedef unsigned short u16;
typedef unsigned int   u32;
typedef unsigned short u16x8 __attribute__((ext_vector_type(8)));

__device__ __forceinline__ u16 f2bf(float x) {
    union { float f; u32 u; } v; v.f = x;
    u32 u = v.u;
    return (u16)((u + 0x7fffu + ((u >> 16) & 1u)) >> 16);
}
__device__ __forceinline__ float silu_f(float x) {
    return x / (1.f + __expf(-x));
}
__device__ __forceinline__ float bf2f(u16 w) {
    union { u32 u; float f; } a; a.u = ((u32)w) << 16; return a.f;
}

// C-store helpers: f32 passthrough or bf16 round (R20/R21)
__device__ __forceinline__ void cstore(float* p, float v) { *p = v; }
__device__ __forceinline__ void cstore(u16*   p, float v) { *p = f2bf(v); }

// R23: bijective XCD-aware block remap (m204). Consecutive remapped indices
// land on the SAME XCD as a contiguous chunk -> per-XCD L2 keeps the A/W
// panels of that chunk resident across re-reads.
__device__ __forceinline__ void xcd_swizzle(int& bx, int& by) {
    int gx = gridDim.x;
    int nwg = gx * gridDim.y;
    int orig = by * gx + bx;
    int q = nwg >> 3, rr = nwg & 7;
    int xcd = orig & 7, lid = orig >> 3;
    int swz = (xcd < rr ? xcd * (q + 1) : rr * (q + 1) + (xcd - rr) * q) + lid;
    bx = swz % gx;
    by = swz / gx;
}

// async global->LDS, 16B per lane; LDS dest is wave-uniform base + lane*16
__device__ __forceinline__ void gld_lds16(const u16* g, u16* l) {
    __builtin_amdgcn_global_load_lds(
        (const __attribute__((address_space(1))) unsigned int*)g,
        (__attribute__((address_space(3))) unsigned int*)l, 16, 0, 0);
}

// --------------------------- block-wide sum --------------------------------
__device__ __forceinline__ float block_sum(float v) {
    #pragma unroll
    for (int off = 32; off > 0; off >>= 1) v += __shfl_xor(v, off, 64);
    __shared__ float red[4];
    int w = threadIdx.x >> 6;
    int nwv = blockDim.x >> 6;
    if ((threadIdx.x & 63) == 0) red[w] = v;
    __syncthreads();
    float tot = red[0];
    for (int i = 1; i < nwv; i++) tot += red[i];
    return tot;
}

// --------------------- f32 -> bf16 convert (all weights + hidden) ----------
#define HID_E      2097152LL   // 4096*512
#define INPROJ_P_E 1179648LL   // 2304*512
#define INPROJ_S_E 1122304LL   // 2192*512
#define OUTPROJ_E   524288LL   // 512*1024
#define GUT_E      5767168LL   // 5632*1024
#define DOWNT_E    2883584LL   // 1024*2816
#define GUM_E      1572864LL   // 3072*512
#define DOWNM_E     786432LL   // 512*1536
#define CONV_TOT_E 14811136LL

__global__ __launch_bounds__(256) void convert_all_kernel(
    const float* __restrict__ s_hid, const float* __restrict__ s_inproj,
    const float* __restrict__ s_outproj, const float* __restrict__ s_gut,
    const float* __restrict__ s_downt, const float* __restrict__ s_gum,
    const float* __restrict__ s_downm, u16* __restrict__ dst)
{
    long long idx = (long long)blockIdx.x * 256 + threadIdx.x;
    long long e = idx * 4;
    if (e >= CONV_TOT_E) return;
    const float* src; long long off, nsrc;
    long long c0 = HID_E;
    long long c1 = c0 + INPROJ_P_E;
    long long c2 = c1 + OUTPROJ_E;
    long long c3 = c2 + GUT_E;
    long long c4 = c3 + DOWNT_E;
    long long c5 = c4 + GUM_E;
    if      (e < c0) { src = s_hid;     off = e;      nsrc = HID_E; }
    else if (e < c1) { src = s_inproj;  off = e - c0; nsrc = INPROJ_S_E; }
    else if (e < c2) { src = s_outproj; off = e - c1; nsrc = OUTPROJ_E; }
    else if (e < c3) { src = s_gut;     off = e - c2; nsrc = GUT_E; }
    else if (e < c4) { src = s_downt;   off = e - c3; nsrc = DOWNT_E; }
    else if (e < c5) { src = s_gum;     off = e - c4; nsrc = GUM_E; }
    else             { src = s_downm;   off = e - c5; nsrc = DOWNM_E; }
    ushort4 r;
    if (off < nsrc) {
        float4 v = *reinterpret_cast<const float4*>(src + off);
        r.x = f2bf(v.x); r.y = f2bf(v.y); r.z = f2bf(v.z); r.w = f2bf(v.w);
    } else {
        r.x = 0; r.y = 0; r.z = 0; r.w = 0;
    }
    *reinterpret_cast<ushort4*>(dst + e) = r;
}

// ----------------------------- bf16 MFMA GEMM (BK=64) ----------------------
// C[M,N] = A[M,K] * W[N,K]^T. 128x128 tile, 4 waves of 64x64 (4x4 MFMAs).
// R20/R21: CT templates the C dtype (f32 or bf16). R23: XCD swizzle.
template<bool SK, typename CT>
__device__ __forceinline__ void gemm_bt_body(
    const u16* __restrict__ A, const u16* __restrict__ W,
    CT* __restrict__ C, int M, int N, int K, int kLen)
{
    __shared__ u16 As[128 * 64];   // 16 KB
    __shared__ u16 Bs[128 * 64];   // 16 KB
    int tid = threadIdx.x;
    int bx = blockIdx.x, by = blockIdx.y;
    xcd_swizzle(bx, by);
    int m0 = by * 128, n0 = bx * 128;
    int kBase = SK ? blockIdx.z * kLen : 0;
    CT* Cw = SK ? C + (size_t)blockIdx.z * M * N : C;
    int wave = tid >> 6, lane = tid & 63;
    int wm = (wave >> 1) * 64, wn = (wave & 1) * 64;
    int lrow = lane & 15;
    int kq = lane >> 4;
    int kx = lrow & 7;

    int rL = lane >> 3, cL = lane & 7;
    int cG = cL ^ rL;
    const u16* gA[4]; const u16* gB[4];
    u16 *lA[4], *lB[4];
    #pragma unroll
    for (int i = 0; i < 4; i++) {
        int r = wave * 32 + i * 8;
        gA[i] = A + (size_t)(m0 + r + rL) * K + kBase + cG * 8;
        gB[i] = W + (size_t)(n0 + r + rL) * K + kBase + cG * 8;
        lA[i] = &As[r * 64];
        lB[i] = &Bs[r * 64];
    }

    f32x4 acc[4][4];
    #pragma unroll
    for (int i = 0; i < 4; i++)
        #pragma unroll
        for (int j = 0; j < 4; j++) {
            acc[i][j][0] = 0.f; acc[i][j][1] = 0.f;
            acc[i][j][2] = 0.f; acc[i][j][3] = 0.f;
        }

    for (int kt = 0; kt < kLen; kt += 64) {
        __syncthreads();
        #pragma unroll
        for (int i = 0; i < 4; i++) {
            gld_lds16(gA[i] + kt, lA[i]);
            gld_lds16(gB[i] + kt, lB[i]);
        }
        __syncthreads();
        #pragma unroll
        for (int ks = 0; ks < 2; ks++) {
            int ko = (((ks * 4 + kq) ^ kx) * 8);
            bf16x8 af[4], bfr[4];
            #pragma unroll
            for (int i = 0; i < 4; i++) {
                af[i]  = *reinterpret_cast<const bf16x8*>(&As[(wm + i * 16 + lrow) * 64 + ko]);
                bfr[i] = *reinterpret_cast<const bf16x8*>(&Bs[(wn + i * 16 + lrow) * 64 + ko]);
            }
            #pragma unroll
            for (int i = 0; i < 4; i++)
                #pragma unroll
                for (int j = 0; j < 4; j++)
                    acc[i][j] = __builtin_amdgcn_mfma_f32_16x16x32_bf16(af[i], bfr[j], acc[i][j], 0, 0, 0);
        }
    }

    // C/D layout: col = lane&15, row = (lane>>4)*4 + reg
    int rbase = m0 + wm + kq * 4;
    int cbase = n0 + wn + lrow;
    #pragma unroll
    for (int i = 0; i < 4; i++)
        #pragma unroll
        for (int j = 0; j < 4; j++)
            #pragma unroll
            for (int r = 0; r < 4; r++)
                cstore(&Cw[(size_t)(rbase + i * 16 + r) * N + cbase + j * 16], acc[i][j][r]);
}

// R21: in_proj GEMM emits bf16 zx
__global__ __launch_bounds__(256) void gemm_bt(
    const u16* __restrict__ A, const u16* __restrict__ W,
    u16* __restrict__ C, int M, int N, int K)
{
    gemm_bt_body<false, u16>(A, W, C, M, N, K, K);
}

__global__ __launch_bounds__(256) void gemm_bt_sk(
    const u16* __restrict__ A, const u16* __restrict__ W,
    u16* __restrict__ C, int M, int N, int K, int kLen)
{
    gemm_bt_body<true, u16>(A, W, C, M, N, K, kLen);
}

// --------------- fused gate/up GEMM + SwiGLU (128x64, BK=64) ---------------
// act[M,inter] = silu(A·Wg^T) * (A·Wu^T). Bs rows 0..63 = gate, 64..127 = up.
// R23: XCD swizzle.
__global__ __launch_bounds__(256) void gemm_swiglu(
    const u16* __restrict__ A, const u16* __restrict__ W,
    u16* __restrict__ act, int M, int inter, int K)
{
    __shared__ u16 As[128 * 64];   // 16 KB
    __shared__ u16 Bs[128 * 64];   // 16 KB
    int tid = threadIdx.x;
    int bx = blockIdx.x, by = blockIdx.y;
    xcd_swizzle(bx, by);
    int m0 = by * 128, n0 = bx * 64;
    int wave = tid >> 6, lane = tid & 63;
    int wm = (wave >> 1) * 64, wn = (wave & 1) * 32;
    int lrow = lane & 15;
    int kq = lane >> 4;
    int kx = lrow & 7;

    int rL = lane >> 3, cL = lane & 7;
    int cG = cL ^ rL;
    const u16* gA[4]; const u16* gB[4];
    u16 *lA[4], *lB[4];
    #pragma unroll
    for (int i = 0; i < 4; i++) {
        int r = wave * 32 + i * 8;
        gA[i] = A + (size_t)(m0 + r + rL) * K + cG * 8;
        lA[i] = &As[r * 64];
        int rB = r;   // combined index: 0..63 gate, 64..127 up (per wave 32)
        int grow = (rB < 64) ? (n0 + rB + rL)
                             : (inter + n0 + rB - 64 + rL);
        gB[i] = W + (size_t)grow * K + cG * 8;
        lB[i] = &Bs[rB * 64];
    }

    f32x4 accg[4][2], accu[4][2];
    #pragma unroll
    for (int i = 0; i < 4; i++)
        #pragma unroll
        for (int j = 0; j < 2; j++) {
            accg[i][j][0]=0.f; accg[i][j][1]=0.f; accg[i][j][2]=0.f; accg[i][j][3]=0.f;
            accu[i][j][0]=0.f; accu[i][j][1]=0.f; accu[i][j][2]=0.f; accu[i][j][3]=0.f;
        }

    for (int kt = 0; kt < K; kt += 64) {
        __syncthreads();
        #pragma unroll
        for (int i = 0; i < 4; i++) {
            gld_lds16(gA[i] + kt, lA[i]);
            gld_lds16(gB[i] + kt, lB[i]);
        }
        __syncthreads();
        #pragma unroll
        for (int ks = 0; ks < 2; ks++) {
            int ko = (((ks * 4 + kq) ^ kx) * 8);
            bf16x8 af[4], bg[2], bu[2];
            #pragma unroll
            for (int i = 0; i < 4; i++)
                af[i] = *reinterpret_cast<const bf16x8*>(&As[(wm + i * 16 + lrow) * 64 + ko]);
            #pragma unroll
            for (int j = 0; j < 2; j++) {
                bg[j] = *reinterpret_cast<const bf16x8*>(&Bs[(wn + j * 16 + lrow) * 64 + ko]);
                bu[j] = *reinterpret_cast<const bf16x8*>(&Bs[(64 + wn + j * 16 + lrow) * 64 + ko]);
            }
            #pragma unroll
            for (int i = 0; i < 4; i++)
                #pragma unroll
                for (int j = 0; j < 2; j++) {
                    accg[i][j] = __builtin_amdgcn_mfma_f32_16x16x32_bf16(af[i], bg[j], accg[i][j], 0, 0, 0);
                    accu[i][j] = __builtin_amdgcn_mfma_f32_16x16x32_bf16(af[i], bu[j], accu[i][j], 0, 0, 0);
                }
        }
    }

    int rbase = m0 + wm + kq * 4;
    int cbase = n0 + wn + lrow;
    #pragma unroll
    for (int i = 0; i < 4; i++)
        #pragma unroll
        for (int j = 0; j < 2; j++)
            #pragma unroll
            for (int r = 0; r < 4; r++) {
                float g = accg[i][j][r], u = accu[i][j][r];
                act[(size_t)(rbase + i * 16 + r) * inter + cbase + j * 16] =
                    f2bf(silu_f(g) * u);
            }
}

// ----------------- conv (depthwise, causal, width 4) + dt ------------------
__global__ __launch_bounds__(256) void conv_dt_kernel(
    const u16* __restrict__ zx, const float* __restrict__ conv_w,
    const float* __restrict__ conv_b, const float* __restrict__ dt_bias,
    u16* __restrict__ convout, float* __restrict__ dtbuf)
{
    int idx = blockIdx.x * 256 + threadIdx.x;   // over 4096*1168
    int bl = idx / 1168;
    int c  = idx - bl * 1168;
    int l  = bl & (LL - 1);
    if (c < CONVDIM) {
        const u16* col = zx + (size_t)bl * NPROJ_PAD + DINNER + c;
        float acc = conv_b[c];
        #pragma unroll
        for (int i = 0; i < 4; i++) {
            int lt = l - 3 + i;
            float v = (lt >= 0) ? bf2f(col[(long long)(lt - l) * NPROJ_PAD]) : 0.f;
            acc = fmaf(v, conv_w[c * 4 + i], acc);
        }
        convout[(size_t)bl * CONVDIM + c] = f2bf(silu_f(acc));
    } else {
        int h = c - CONVDIM;
        float v = bf2f(zx[(size_t)bl * NPROJ_PAD + 2176 + h]) + dt_bias[h];
        float sp = (v > 20.f) ? v : log1pf(__expf(v));
        dtbuf[(size_t)bl * NHEADS + h] = sp;
    }
}

// -------------------- MFMA chunk scan: pass 1 ------------------------------
__global__ __launch_bounds__(256) void scan_mfma1(
    const u16* __restrict__ convout, const float* __restrict__ dtbuf,
    const float* __restrict__ A_log, u16* __restrict__ Sc,
    float* __restrict__ Ptot, u16* __restrict__ yp0)
{
    __shared__ u16 Blds[32 * 72];        // raw B bf16 [t][n] (shared)
    __shared__ u16 Clds[32 * 72];        // raw C bf16 [t][n] (shared)
    __shared__ u16 Xt[4][64 * 40];       // x^T bf16 [p][t] (per head)
    __shared__ u16 Bht[4][64 * 40];      // (w_t*dt_t*B)^T bf16 [n][t]
    __shared__ u16 Wlds[4][32 * 40];     // W bf16 [t][t']
    __shared__ float dtl[4][32], cuml[4][32], warr[4][32];

    int blk = blockIdx.x;                // 512 = (b*4 + hq)*32 + c
    int c   = blk & 31;
    int bg  = blk >> 5;
    int b   = bg >> 2;
    int hq  = bg & 3;
    int tid = threadIdx.x;
    int w    = tid >> 6;                 // wave = head within quad
    int lane = tid & 63;
    int h   = hq * 4 + w;
    int bh  = b * 16 + h;
    int lrow = lane & 15, kq = lane >> 4;
    size_t base = ((size_t)b * LL + (size_t)c * CHUNK) * CONVDIM;
    float Ah = -__expf(A_log[h]);

    if (lane < 32)
        dtl[w][lane] = dtbuf[((size_t)b * LL + (size_t)c * CHUNK + lane) * NHEADS + h];
    // shared B/C staging: 32 t x 16 chunks of 8 bf16; 256 thr -> 2 iters
    #pragma unroll
    for (int it = 0; it < 2; ++it) {
        int idx = it * 256 + tid;
        int t = idx >> 4, q = idx & 15;
        u16x8 v = *reinterpret_cast<const u16x8*>(
            &convout[base + (size_t)t * CONVDIM + DINNER + q * 8]);
        if (q < 8) *reinterpret_cast<u16x8*>(&Blds[t * 72 + q * 8]) = v;
        else       *reinterpret_cast<u16x8*>(&Clds[t * 72 + (q - 8) * 8]) = v;
    }
    #pragma unroll
    for (int t = 0; t < 32; ++t)
        Xt[w][lane * 40 + t] = convout[base + (size_t)t * CONVDIM + h * HEADDIM + lane];
    __syncthreads();

    float s_inc = 0.f, s_all = 0.f;
    #pragma unroll
    for (int j = 0; j < 32; ++j) {
        float v = dtl[w][j];
        s_all += v;
        if (j <= lane) s_inc += v;
    }
    if (lane < 32) {
        cuml[w][lane] = s_inc;
        warr[w][lane] = __expf(Ah * (s_all - s_inc)) * dtl[w][lane];
    }
    float cumTot = s_all;
    __syncthreads();

    #pragma unroll
    for (int t = 0; t < 32; ++t)
        Bht[w][lane * 40 + t] = f2bf(warr[w][t] * bf2f(Blds[t * 72 + lane]));

    f32x4 accG[2][2];
    #pragma unroll
    for (int i = 0; i < 2; i++)
        #pragma unroll
        for (int j = 0; j < 2; j++) {
            accG[i][j][0]=0.f; accG[i][j][1]=0.f; accG[i][j][2]=0.f; accG[i][j][3]=0.f;
        }
    #pragma unroll
    for (int ks = 0; ks < 2; ++ks) {
        bf16x8 af[2], bfr[2];
        #pragma unroll
        for (int i = 0; i < 2; i++) {
            af[i]  = *reinterpret_cast<const bf16x8*>(&Clds[(16*i + lrow) * 72 + ks*32 + kq*8]);
            bfr[i] = *reinterpret_cast<const bf16x8*>(&Blds[(16*i + lrow) * 72 + ks*32 + kq*8]);
        }
        #pragma unroll
        for (int i = 0; i < 2; i++)
            #pragma unroll
            for (int j = 0; j < 2; j++)
                accG[i][j] = __builtin_amdgcn_mfma_f32_16x16x32_bf16(af[i], bfr[j], accG[i][j], 0, 0, 0);
    }

    float ctp0 = cuml[w][lrow],      dtp0 = dtl[w][lrow];
    float ctp1 = cuml[w][16 + lrow], dtp1 = dtl[w][16 + lrow];
    #pragma unroll
    for (int i = 0; i < 2; i++)
        #pragma unroll
        for (int r = 0; r < 4; r++) {
            int t = 16*i + kq*4 + r;
            float ct = cuml[w][t];
            #pragma unroll
            for (int j = 0; j < 2; j++) {
                int tp = 16*j + lrow;
                float ctp = j ? ctp1 : ctp0;
                float dtp = j ? dtp1 : dtp0;
                float g = accG[i][j][r];
                float wv = (tp <= t) ? __expf(Ah * (ct - ctp)) * dtp * g : 0.f;
                Wlds[w][t * 40 + tp] = f2bf(wv);
            }
        }
    __syncthreads();

    bf16x8 xf[4];
    #pragma unroll
    for (int j = 0; j < 4; j++)
        xf[j] = *reinterpret_cast<const bf16x8*>(&Xt[w][(16*j + lrow) * 40 + kq*8]);
    f32x4 accY[2][4];
    #pragma unroll
    for (int i = 0; i < 2; i++) {
        bf16x8 wf = *reinterpret_cast<const bf16x8*>(&Wlds[w][(16*i + lrow) * 40 + kq*8]);
        #pragma unroll
        for (int j = 0; j < 4; j++) {
            accY[i][j][0]=0.f; accY[i][j][1]=0.f; accY[i][j][2]=0.f; accY[i][j][3]=0.f;
            accY[i][j] = __builtin_amdgcn_mfma_f32_16x16x32_bf16(wf, xf[j], accY[i][j], 0, 0, 0);
        }
    }

    f32x4 accS[4][4];
    #pragma unroll
    for (int j = 0; j < 4; j++) {
        bf16x8 bb = *reinterpret_cast<const bf16x8*>(&Bht[w][(16*j + lrow) * 40 + kq*8]);
        #pragma unroll
        for (int i = 0; i < 4; i++) {
            accS[i][j][0]=0.f; accS[i][j][1]=0.f; accS[i][j][2]=0.f; accS[i][j][3]=0.f;
            accS[i][j] = __builtin_amdgcn_mfma_f32_16x16x32_bf16(xf[i], bb, accS[i][j], 0, 0, 0);
        }
    }

    u16* yb = yp0 + ((size_t)b * LL + (size_t)c * CHUNK) * DINNER + h * HEADDIM;
    #pragma unroll
    for (int i = 0; i < 2; i++)
        #pragma unroll
        for (int r = 0; r < 4; r++) {
            int t = 16*i + kq*4 + r;
            #pragma unroll
            for (int j = 0; j < 4; j++)
                yb[(size_t)t * DINNER + 16*j + lrow] = f2bf(accY[i][j][r]);
        }
    #pragma unroll
    for (int i = 0; i < 4; i++)
        #pragma unroll
        for (int r = 0; r < 4; r++) {
            int p = 16*i + kq*4 + r;
            #pragma unroll
            for (int j = 0; j < 4; j++)
                Sc[((size_t)(bh * 4 + j) * NCHUNK + c) * 1024 + p * 16 + lrow] = f2bf(accS[i][j][r]);
        }
    if (lane == 0) Ptot[bh * NCHUNK + c] = __expf(Ah * cumTot);
}

// ----------------------- chunked SSM scan: combine -------------------------
// R23: 512 blocks (2/CU) x 256 thr x 2 elems — bitwise identical to R17.
__global__ __launch_bounds__(256) void scan_combine(
    const u16* __restrict__ Sc, const float* __restrict__ Ptot,
    u16* __restrict__ Sinit)
{
    int blk = blockIdx.x;             // 512 = (bh*4 + nq)*2 + half
    int rowid = blk >> 1;             // bh*4 + nq
    int bh = rowid >> 2;
    int half = blk & 1;
    int tid = threadIdx.x;
    int e = half * 512 + tid * 2;     // elem offset within the 1024-wide row
    float Pv[NCHUNK];
    #pragma unroll
    for (int c = 0; c < NCHUNK; ++c) Pv[c] = Ptot[bh * NCHUNK + c];
    float c0v = 0.f, c1v = 0.f;
    size_t rowbase = (size_t)rowid * NCHUNK * 1024 + e;
    #pragma unroll
    for (int c = 0; c < NCHUNK; ++c) {
        size_t row = rowbase + (size_t)c * 1024;
        ushort2 o; o.x = f2bf(c0v); o.y = f2bf(c1v);
        *reinterpret_cast<ushort2*>(Sinit + row) = o;
        ushort2 si = *reinterpret_cast<const ushort2*>(Sc + row);
        c0v = fmaf(c0v, Pv[c], bf2f(si.x));
        c1v = fmaf(c1v, Pv[c], bf2f(si.y));
    }
}

// -------------------- MFMA chunk scan: pass 2 ------------------------------
__global__ __launch_bounds__(256) void scan_mfma2(
    const u16* __restrict__ convout, const float* __restrict__ dtbuf,
    const float* __restrict__ A_log, const u16* __restrict__ Sinit,
    u16* __restrict__ yp1)
{
    __shared__ u16 Clds2[32 * 72];       // raw C bf16 [t][n] (shared)
    __shared__ float dtl[4][32], dacl[4][32];
    int blk = blockIdx.x;                // 512 = (b*4 + hq)*32 + c
    int c   = blk & 31;
    int bg  = blk >> 5;
    int b   = bg >> 2;
    int hq  = bg & 3;
    int tid = threadIdx.x;
    int w    = tid >> 6;                 // wave = head within quad
    int lane = tid & 63;
    int h   = hq * 4 + w;
    int bh  = b * 16 + h;
    int lrow = lane & 15, kq = lane >> 4;
    size_t base = ((size_t)b * LL + (size_t)c * CHUNK) * CONVDIM;
    float Ah = -__expf(A_log[h]);

    if (lane < 32)
        dtl[w][lane] = dtbuf[((size_t)b * LL + (size_t)c * CHUNK + lane) * NHEADS + h];
    // shared raw-C staging: 32 t x 8 chunks of 8 bf16 = 256 thr x 1 iter
    {
        int t = tid >> 3, q = tid & 7;
        u16x8 v = *reinterpret_cast<const u16x8*>(
            &convout[base + (size_t)t * CONVDIM + DINNER + DSTATE + q * 8]);
        *reinterpret_cast<u16x8*>(&Clds2[t * 72 + q * 8]) = v;
    }
    __syncthreads();

    float s_inc = 0.f;
    #pragma unroll
    for (int j = 0; j < 32; ++j) {
        float v = dtl[w][j];
        if (j <= lane) s_inc += v;
    }
    if (lane < 32) dacl[w][lane] = __expf(Ah * s_inc);

    f32x4 accI[2][4];
    #pragma unroll
    for (int i = 0; i < 2; i++)
        #pragma unroll
        for (int j = 0; j < 4; j++) {
            accI[i][j][0]=0.f; accI[i][j][1]=0.f; accI[i][j][2]=0.f; accI[i][j][3]=0.f;
        }
    #pragma unroll
    for (int ks = 0; ks < 2; ++ks) {
        bf16x8 ca[2];
        #pragma unroll
        for (int i = 0; i < 2; i++)
            ca[i] = *reinterpret_cast<const bf16x8*>(&Clds2[(16*i + lrow) * 72 + ks*32 + kq*8]);
        int nq = ks * 2 + (kq >> 1);
        int off = (kq & 1) * 8;
        #pragma unroll
        for (int j = 0; j < 4; j++) {
            int p = 16*j + lrow;
            const u16* sp = Sinit + ((size_t)(bh * 4 + nq) * NCHUNK + c) * 1024 + p * 16 + off;
            bf16x8 fr = *reinterpret_cast<const bf16x8*>(sp);
            #pragma unroll
            for (int i = 0; i < 2; i++)
                accI[i][j] = __builtin_amdgcn_mfma_f32_16x16x32_bf16(ca[i], fr, accI[i][j], 0, 0, 0);
        }
    }

    u16* yb = yp1 + ((size_t)b * LL + (size_t)c * CHUNK) * DINNER + h * HEADDIM;
    #pragma unroll
    for (int i = 0; i < 2; i++)
        #pragma unroll
        for (int r = 0; r < 4; r++) {
            int t = 16*i + kq*4 + r;
            float sct = dacl[w][t];
            #pragma unroll
            for (int j = 0; j < 4; j++)
                yb[(size_t)t * DINNER + 16*j + lrow] = f2bf(accI[i][j][r] * sct);
        }
}

// ------------- gated RMSNorm (yp0+yp1+xD)*silu(z), bf16 out ----------------
__global__ __launch_bounds__(256) void gated_rms_kernel(
    const u16* __restrict__ yp0, const u16* __restrict__ yp1,
    const u16* __restrict__ convout, const u16* __restrict__ zx,
    const float* __restrict__ Dv, const float* __restrict__ norm_w,
    u16* __restrict__ gout)
{
    int bl = blockIdx.x;
    int c = threadIdx.x * 4;
    ushort4 y0 = *reinterpret_cast<const ushort4*>(yp0 + (size_t)bl * DINNER + c);
    ushort4 y1 = *reinterpret_cast<const ushort4*>(yp1 + (size_t)bl * DINNER + c);
    ushort4 xv = *reinterpret_cast<const ushort4*>(convout + (size_t)bl * CONVDIM + c);
    ushort4 zv = *reinterpret_cast<const ushort4*>(zx + (size_t)bl * NPROJ_PAD + c);
    float Dh = Dv[c >> 6];
    float g0 = (bf2f(y0.x) + bf2f(y1.x) + bf2f(xv.x) * Dh) * silu_f(bf2f(zv.x));
    float g1 = (bf2f(y0.y) + bf2f(y1.y) + bf2f(xv.y) * Dh) * silu_f(bf2f(zv.y));
    float g2 = (bf2f(y0.z) + bf2f(y1.z) + bf2f(xv.z) * Dh) * silu_f(bf2f(zv.z));
    float g3 = (bf2f(y0.w) + bf2f(y1.w) + bf2f(xv.w) * Dh) * silu_f(bf2f(zv.w));
    float tot = block_sum(g0 * g0 + g1 * g1 + g2 * g2 + g3 * g3);
    float sc = rsqrtf(tot * (1.f / DINNER) + 1e-5f);
    float4 nw = *reinterpret_cast<const float4*>(norm_w + c);
    ushort4 o;
    o.x = f2bf(g0 * sc * nw.x); o.y = f2bf(g1 * sc * nw.y);
    o.z = f2bf(g2 * sc * nw.z); o.w = f2bf(g3 * sc * nw.w);
    *reinterpret_cast<ushort4*>(gout + (size_t)bl * DINNER + c) = o;
}

// ---- R24: fused residual + split-K sum + RMS + TRANSPOSED bf16 write ------
// One wave per row (4 rows/wave, 16 rows/block). Per-element sum order
// matches the old kernel: a + ((p0+p1)+(p2+p3)). Wave-local shuffle reduce.
// Normalized values staged in padded LDS tile [C][20] (8B-aligned column
// strides), then written transposed: out[b][c][r], 16-r x 16 B segments.
template<typename AT, int C>
__global__ __launch_bounds__(256) void residual_rms_tr(
    const AT* __restrict__ a, const u16* __restrict__ pbuf,
    u16* __restrict__ outT, int Rb, int rowsTot)
{
    constexpr int EPL = C / 64;          // elems per lane (8 or 16)
    constexpr int PAD = 20;
    __shared__ u16 tile[C * PAD];        // C=512: 20 KB; C=1024: 40 KB
    int tid = threadIdx.x;
    int w = tid >> 6, lane = tid & 63;
    int gr0 = blockIdx.x * 16;           // global row base (tiles never span batches)
    int b  = gr0 / Rb;
    int r0 = gr0 - b * Rb;
    size_t slice = (size_t)rowsTot * C;

    #pragma unroll
    for (int i = 0; i < 4; ++i) {
        int rr = w * 4 + i;
        size_t off = (size_t)(gr0 + rr) * C + lane * EPL;
        float v[EPL];
        #pragma unroll
        for (int k = 0; k < EPL; k += 8) {
            float av[8];
            if constexpr (sizeof(AT) == 4) {
                const float* ap = (const float*)a + off + k;
                float4 t0 = *reinterpret_cast<const float4*>(ap);
                float4 t1 = *reinterpret_cast<const float4*>(ap + 4);
                av[0]=t0.x; av[1]=t0.y; av[2]=t0.z; av[3]=t0.w;
                av[4]=t1.x; av[5]=t1.y; av[6]=t1.z; av[7]=t1.w;
            } else {
                u16x8 t = *reinterpret_cast<const u16x8*>((const u16*)a + off + k);
                #pragma unroll
                for (int j = 0; j < 8; j++) av[j] = bf2f(t[j]);
            }
            u16x8 q0 = *reinterpret_cast<const u16x8*>(pbuf + off + k);
            u16x8 q1 = *reinterpret_cast<const u16x8*>(pbuf + slice + off + k);
            u16x8 q2 = *reinterpret_cast<const u16x8*>(pbuf + 2 * slice + off + k);
            u16x8 q3 = *reinterpret_cast<const u16x8*>(pbuf + 3 * slice + off + k);
            #pragma unroll
            for (int j = 0; j < 8; j++)
                v[k + j] = av[j] + ((bf2f(q0[j]) + bf2f(q1[j])) +
                                    (bf2f(q2[j]) + bf2f(q3[j])));
        }
        float ss = 0.f;
        #pragma unroll
        for (int k = 0; k < EPL; ++k) ss += v[k] * v[k];
        #pragma unroll
        for (int o2 = 32; o2 > 0; o2 >>= 1) ss += __shfl_xor(ss, o2, 64);
        float sc = rsqrtf(ss / (float)C + 1e-5f);
        #pragma unroll
        for (int k = 0; k < EPL; ++k)
            tile[(lane * EPL + k) * PAD + rr] = f2bf(v[k] * sc);
    }
    __syncthreads();

    // transposed write: thread pair (c, half) -> 16 B contiguous segment
    u16* ob = outT + (size_t)b * Rb * C;
    int h = tid & 1;
    #pragma unroll
    for (int p = 0; p < C / 128; ++p) {
        int c = p * 128 + (tid >> 1);
        ushort4 lo = *reinterpret_cast<const ushort4*>(&tile[c * PAD + h * 8]);
        ushort4 hi = *reinterpret_cast<const ushort4*>(&tile[c * PAD + h * 8 + 4]);
        u16x8 ov;
        ov[0]=lo.x; ov[1]=lo.y; ov[2]=lo.z; ov[3]=lo.w;
        ov[4]=hi.x; ov[5]=hi.y; ov[6]=hi.z; ov[7]=hi.w;
        *reinterpret_cast<u16x8*>(ob + (size_t)c * Rb + r0 + h * 8) = ov;
    }
}

// ---- residual + 4 split-K partials + RMSNorm, f32 out (final step) --------
__global__ void residual_rms_b2f(
    const u16* __restrict__ a, const u16* __restrict__ pbuf,
    float* __restrict__ outf, int ncols, int rows)
{
    int row = blockIdx.x;
    int c = threadIdx.x * 4;
    size_t slice = (size_t)rows * ncols;
    size_t off = (size_t)row * ncols + c;
    ushort4 t = *reinterpret_cast<const ushort4*>(a + off);
    float va0 = bf2f(t.x), va1 = bf2f(t.y), va2 = bf2f(t.z), va3 = bf2f(t.w);
    ushort4 p0 = *reinterpret_cast<const ushort4*>(pbuf + off);
    ushort4 p1 = *reinterpret_cast<const ushort4*>(pbuf + slice + off);
    ushort4 p2 = *reinterpret_cast<const ushort4*>(pbuf + 2 * slice + off);
    ushort4 p3 = *reinterpret_cast<const ushort4*>(pbuf + 3 * slice + off);
    float v0 = va0 + ((bf2f(p0.x) + bf2f(p1.x)) + (bf2f(p2.x) + bf2f(p3.x)));
    float v1 = va1 + ((bf2f(p0.y) + bf2f(p1.y)) + (bf2f(p2.y) + bf2f(p3.y)));
    float v2 = va2 + ((bf2f(p0.z) + bf2f(p1.z)) + (bf2f(p2.z) + bf2f(p3.z)));
    float v3 = va3 + ((bf2f(p0.w) + bf2f(p1.w)) + (bf2f(p2.w) + bf2f(p3.w)));
    float tot = block_sum(v0 * v0 + v1 * v1 + v2 * v2 + v3 * v3);
    float sc = rsqrtf(tot / (float)ncols + 1e-5f);
    float4 o; o.x = v0 * sc; o.y = v1 * sc; o.z = v2 * sc; o.w = v3 * sc;
    *reinterpret_cast<float4*>(outf + off) = o;
}

// ---------------------------------------------------------------------------
extern "C" void kernel_launch(void* const* d_in, const int* in_sizes, int n_in,
                              void* d_out, int out_size, void* d_ws, size_t ws_size,
                              hipStream_t stream)
{
    const float* hid      = (const float*)d_in[0];
    const float* in_proj  = (const float*)d_in[1];
    const float* conv_w   = (const float*)d_in[2];
    const float* conv_b   = (const float*)d_in[3];
    const float* dt_bias  = (const float*)d_in[4];
    const float* A_log    = (const float*)d_in[5];
    const float* Dv       = (const float*)d_in[6];
    const float* norm_w   = (const float*)d_in[7];
    const float* out_proj = (const float*)d_in[8];
    const float* gu_t     = (const float*)d_in[9];
    const float* down_t   = (const float*)d_in[10];
    const float* gu_m     = (const float*)d_in[11];
    const float* down_m   = (const float*)d_in[12];
    float* outp = (float*)d_out;

    char* ws = (char*)d_ws;
    u16* bf        = (u16*)ws;
    u16* hid_bf    = bf;
    u16* w_inproj  = bf + HID_E;
    u16* w_outproj = w_inproj + INPROJ_P_E;
    u16* w_gut     = w_outproj + OUTPROJ_E;
    u16* w_downt   = w_gut + GUT_E;
    u16* w_gum     = w_downt + DOWNT_E;
    u16* w_downm   = w_gum + GUM_E;
    size_t o = (size_t)(CONV_TOT_E * 2);
    auto alloc = [&](size_t bytes) { size_t r = o; o = (o + bytes + 255) & ~(size_t)255; return r; };
    size_t dt_off  = alloc(4096 * 16 * 4);
    size_t g_off   = alloc((size_t)4096 * 1024 * 2);
    size_t h1_off  = alloc((size_t)4096 * 512 * 4);
    size_t Pt_off  = alloc(2048 * 4);
    // ---- MLP region (live step 8+); Sc/Sinit OVERLAY it (live steps 4-5).
    size_t xtb_off = alloc((size_t)2048 * 1024 * 2);
    size_t xtf_off = alloc((size_t)2048 * 1024 * 4);
    size_t act1_off= alloc((size_t)2048 * 2816 * 2);
    size_t x2_off  = alloc((size_t)2048 * 1024 * 4);
    size_t h2b_off = alloc((size_t)4096 * 512 * 2);
    size_t h2f_off = alloc((size_t)4096 * 512 * 4);
    size_t act2_off= alloc((size_t)4096 * 1536 * 2);
    size_t pad_off = alloc((size_t)10 * 1024 * 1024);
    size_t Sc_off  = xtb_off;                          // bf16: 16.78 MB
    size_t Si_off  = xtb_off + (size_t)8192 * 1024 * 4;// bf16: 16.78 MB
    (void)pad_off; (void)xtf_off; (void)h2f_off; (void)h1_off; (void)x2_off;
    size_t R_off   = o;
    size_t zx_off  = R_off;
    size_t cv_off  = zx_off + (size_t)4096 * NPROJ_PAD * 4;
    size_t y_off   = cv_off + (size_t)4096 * CONVDIM * 4;
    size_t sk_off  = R_off;

    u16*   zx      = (u16*)(ws + zx_off);            // bf16 (R21)
    u16*   convout = (u16*)(ws + cv_off);            // bf16 (R21)
    u16*   ybuf    = (u16*)(ws + y_off);             // yp0 (bf16, R19)
    float* dtbuf   = (float*)(ws + dt_off);
    u16*   g_bf    = (u16*)(ws + g_off);
    u16*   xt_bf   = (u16*)(ws + xtb_off);
    u16*   act1    = (u16*)(ws + act1_off);
    u16*   h2_bf   = (u16*)(ws + h2b_off);
    u16*   act2    = (u16*)(ws + act2_off);
    u16*   skbuf   = (u16*)(ws + sk_off);            // bf16 partials (R20)
    u16*   Sc      = (u16*)(ws + Sc_off);            // bf16; yp1 after combine
    u16*   Sinit   = (u16*)(ws + Si_off);            // bf16
    float* Ptot    = (float*)(ws + Pt_off);

    // 1) convert weights + hidden to bf16
    convert_all_kernel<<<14464, 256, 0, stream>>>(
        hid, in_proj, out_proj, gu_t, down_t, gu_m, down_m, bf);

    // 2) zxbcdt = hidden @ in_proj^T  (bf16 out)
    gemm_bt<<<dim3(NPROJ_PAD / 128, 4096 / 128), 256, 0, stream>>>(
        hid_bf, w_inproj, zx, 4096, NPROJ_PAD, 512);

    // 3) conv + dt
    conv_dt_kernel<<<18688, 256, 0, stream>>>(zx, conv_w, conv_b, dt_bias, convout, dtbuf);

    // 4) MFMA chunk scan (all state bf16)
    scan_mfma1<<<512, 256, 0, stream>>>(convout, dtbuf, A_log, Sc, Ptot, ybuf);
    scan_combine<<<512, 256, 0, stream>>>(Sc, Ptot, Sinit);
    scan_mfma2<<<512, 256, 0, stream>>>(convout, dtbuf, A_log, Sinit, Sc);

    // 5) gated RMSNorm -> bf16
    gated_rms_kernel<<<4096, 256, 0, stream>>>(ybuf, Sc, convout, zx, Dv, norm_w, g_bf);

    // 6) out_proj GEMM, split-K x4 -> bf16 partials in skbuf
    gemm_bt_sk<<<dim3(512 / 128, 4096 / 128, 4), 256, 0, stream>>>(
        g_bf, w_outproj, skbuf, 4096, 512, 1024, 256);

    // 7+8) fused: xt = transpose(rms(hidden + sum partials))  (R24)
    residual_rms_tr<float, 512><<<256, 256, 0, stream>>>(
        hid, skbuf, xt_bf, 1024, 4096);

    // 9) token MLP fused: act1 = swiglu(xt @ gu_t^T)
    gemm_swiglu<<<dim3(INTER_T / 64, 2048 / 128), 256, 0, stream>>>(
        xt_bf, w_gut, act1, 2048, INTER_T, 1024);

    // 10) down_t GEMM, split-K x4 -> bf16 partials in skbuf
    gemm_bt_sk<<<dim3(1024 / 128, 2048 / 128, 4), 256, 0, stream>>>(
        act1, w_downt, skbuf, 2048, 1024, 2816, 704);

    // 11+12) fused: h2 = transpose(rms(xt + sum partials))  (R24)
    residual_rms_tr<u16, 1024><<<128, 256, 0, stream>>>(
        xt_bf, skbuf, h2_bf, 512, 2048);

    // 13) channel MLP fused: act2 = swiglu(h2 @ gu_m^T)
    gemm_swiglu<<<dim3(INTER_M / 64, 4096 / 128), 256, 0, stream>>>(
        h2_bf, w_gum, act2, 4096, INTER_M, 512);

    // 14) down_m GEMM, split-K x4 -> bf16 partials in skbuf
    gemm_bt_sk<<<dim3(512 / 128, 4096 / 128, 4), 256, 0, stream>>>(
        act2, w_downm, skbuf, 4096, 512, 1536, 384);

    // 15) out = rms(h2 + sum partials)  (f32 out)
    residual_rms_b2f<<<4096, 128, 0, stream>>>(h2_bf, skbuf, outp, 512, 4096);
}